// Round 4
// baseline (418.602 us; speedup 1.0000x reference)
//
#include <hip/hip_runtime.h>

// GCN 2-layer forward, round 4:
//   CSR-by-dst gathers with sub-wave-group float4 rows for MLP:
//     layer1: 4 edges in flight per wave-instr (16-lane groups x float4), unroll x2
//     layer2: 8 edges in flight per wave-instr ( 8-lane groups x float4), unroll x2
//   layer1 fused: gather(xs) -> relu(@W1+b1) -> @W2 -> h2s (dinv-prescaled)
//   out[v] = dinv[v]*(sum_{s in N(v)} h2s[s] + h2s[v]) + b2

#define F_IN 64
#define HDIM 128
#define CDIM 32
#define SCAN_B 256

// ---------- CSR build ----------
__global__ void k_hist(const int* __restrict__ dst, int e, int* __restrict__ cnt) {
    int i = blockIdx.x * blockDim.x + threadIdx.x;
    if (i < e) atomicAdd(&cnt[dst[i]], 1);
}

__global__ void k_scan_block(const int* __restrict__ cnt, int* __restrict__ rowptr,
                             int* __restrict__ bsum, int n) {
    __shared__ int sh[SCAN_B];
    int tid = threadIdx.x;
    int i = blockIdx.x * SCAN_B + tid;
    int v = (i < n) ? cnt[i] : 0;
    sh[tid] = v;
    __syncthreads();
    for (int off = 1; off < SCAN_B; off <<= 1) {
        int t = (tid >= off) ? sh[tid - off] : 0;
        __syncthreads();
        sh[tid] += t;
        __syncthreads();
    }
    if (i < n) rowptr[i] = sh[tid] - v;  // exclusive
    if (tid == SCAN_B - 1) bsum[blockIdx.x] = sh[tid];
}

__global__ void k_scan_bsums(int* __restrict__ bsum, int nb) {
    __shared__ int sh[512];
    int tid = threadIdx.x;
    if (nb <= 512) {
        int v = (tid < nb) ? bsum[tid] : 0;
        sh[tid] = v;
        __syncthreads();
        for (int off = 1; off < 512; off <<= 1) {
            int t = (tid >= off) ? sh[tid - off] : 0;
            __syncthreads();
            sh[tid] += t;
            __syncthreads();
        }
        if (tid < nb) bsum[tid] = sh[tid] - v;
    } else if (tid == 0) {
        int run = 0;
        for (int i = 0; i < nb; ++i) { int t = bsum[i]; bsum[i] = run; run += t; }
    }
}

__global__ void k_scan_add_prep(int* __restrict__ rowptr, const int* __restrict__ bsum,
                                const int* __restrict__ cnt, int* __restrict__ cursor,
                                float* __restrict__ dinv, int n) {
    int i = blockIdx.x * blockDim.x + threadIdx.x;
    if (i >= n) return;
    int rp = rowptr[i] + bsum[i / SCAN_B];
    rowptr[i] = rp;
    cursor[i] = rp;
    dinv[i] = rsqrtf((float)(cnt[i] + 1));
}

__global__ void k_fill(const int* __restrict__ src, const int* __restrict__ dst, int e,
                       int* __restrict__ cursor, int* __restrict__ col) {
    int i = blockIdx.x * blockDim.x + threadIdx.x;
    if (i >= e) return;
    int pos = atomicAdd(&cursor[dst[i]], 1);
    col[pos] = src[i];
}

// xs = dinv .* x  (float4 over n*16)
__global__ void k_prescale(const float* __restrict__ x, const float* __restrict__ dinv,
                           float* __restrict__ xs, int n) {
    int i = blockIdx.x * blockDim.x + threadIdx.x;
    if (i >= n * (F_IN / 4)) return;
    int v = i >> 4;
    float s = dinv[v];
    float4 val = ((const float4*)x)[i];
    val.x *= s; val.y *= s; val.z *= s; val.w *= s;
    ((float4*)xs)[i] = val;
}

// ---------- fused layer 1 + transform 2 ----------
// block = 256 threads = 4 waves, wave = 1 node.
// gather: quarter-waves (16 lanes) x float4 -> 4 edges per wave-instr, unroll x2.
__global__ void k_layer1_fused(const float* __restrict__ xs, const int* __restrict__ rowptr,
                               const int* __restrict__ cnt, const int* __restrict__ col,
                               const float* __restrict__ dinv, const float* __restrict__ W1,
                               const float* __restrict__ b1, const float* __restrict__ W2,
                               float* __restrict__ h2s, int n) {
    __shared__ float axs[4][F_IN];
    __shared__ float hs[4][HDIM];
    int tid = threadIdx.x;
    int w = tid >> 6, lane = tid & 63;
    int v = blockIdx.x * 4 + w;
    int q = lane >> 4, l = lane & 15;

    // ---- phase 1: gather (wave-uniform branch: all lanes share v) ----
    float4 r4 = make_float4(0.f, 0.f, 0.f, 0.f);
    if (v < n) {
        int beg = rowptr[v], deg = cnt[v];
        float4 a0 = make_float4(0.f, 0.f, 0.f, 0.f);
        float4 a1 = make_float4(0.f, 0.f, 0.f, 0.f);
        int j = q;
        for (; j + 4 < deg; j += 8) {
            int s0 = col[beg + j];
            int s1 = col[beg + j + 4];
            float4 v0 = ((const float4*)(xs + (size_t)s0 * F_IN))[l];
            float4 v1 = ((const float4*)(xs + (size_t)s1 * F_IN))[l];
            a0.x += v0.x; a0.y += v0.y; a0.z += v0.z; a0.w += v0.w;
            a1.x += v1.x; a1.y += v1.y; a1.z += v1.z; a1.w += v1.w;
        }
        if (j < deg) {
            int s0 = col[beg + j];
            float4 v0 = ((const float4*)(xs + (size_t)s0 * F_IN))[l];
            a0.x += v0.x; a0.y += v0.y; a0.z += v0.z; a0.w += v0.w;
        }
        a0.x += a1.x; a0.y += a1.y; a0.z += a1.z; a0.w += a1.w;
        // reduce across quarters (xor 16, 32)
        a0.x += __shfl_xor(a0.x, 16); a0.y += __shfl_xor(a0.y, 16);
        a0.z += __shfl_xor(a0.z, 16); a0.w += __shfl_xor(a0.w, 16);
        a0.x += __shfl_xor(a0.x, 32); a0.y += __shfl_xor(a0.y, 32);
        a0.z += __shfl_xor(a0.z, 32); a0.w += __shfl_xor(a0.w, 32);
        float dv = dinv[v];
        float4 self = ((const float4*)(xs + (size_t)v * F_IN))[l];
        r4.x = dv * (a0.x + self.x);
        r4.y = dv * (a0.y + self.y);
        r4.z = dv * (a0.z + self.z);
        r4.w = dv * (a0.w + self.w);
    }
    if (q == 0) ((float4*)axs[w])[l] = r4;   // zeros for out-of-range rows
    __syncthreads();

    // ---- phase 2: h[w][lane], h[w][lane+64] = relu(ax @ W1 + b1) ----
    float acc_a = b1[lane], acc_b = b1[lane + 64];
#pragma unroll
    for (int k = 0; k < F_IN; ++k) {
        float a = axs[w][k];  // LDS broadcast
        acc_a = fmaf(a, W1[k * HDIM + lane], acc_a);
        acc_b = fmaf(a, W1[k * HDIM + lane + 64], acc_b);
    }
    hs[w][lane]      = acc_a > 0.f ? acc_a : 0.f;
    hs[w][lane + 64] = acc_b > 0.f ? acc_b : 0.f;
    __syncthreads();

    // ---- phase 3: h2s[v][c] = dinv[v] * (h @ W2)[c], split-k over 2 halves ----
    {
        int half = lane >> 5;
        int c = lane & 31;
        const float* hrow = hs[w] + half * 64;
        const float* w2p = W2 + (half * 64) * CDIM + c;
        float acc = 0.f;
#pragma unroll
        for (int k = 0; k < 64; ++k) acc = fmaf(hrow[k], w2p[k * CDIM], acc);
        acc += __shfl_down(acc, 32);
        if (half == 0 && v < n) h2s[(size_t)v * CDIM + c] = dinv[v] * acc;
    }
}

// ---------- layer 2 aggregation ----------
// block = 256 = 4 waves, wave = 1 node; 8-lane groups x float4 -> 8 edges per instr.
__global__ void k_gather2(const float* __restrict__ h2s, const int* __restrict__ rowptr,
                          const int* __restrict__ cnt, const int* __restrict__ col,
                          const float* __restrict__ dinv, const float* __restrict__ b2,
                          float* __restrict__ out, int n) {
    int tid = threadIdx.x;
    int w = tid >> 6, lane = tid & 63;
    int v = blockIdx.x * 4 + w;
    if (v >= n) return;  // wave-uniform
    int g = lane >> 3, l = lane & 7;
    int beg = rowptr[v], deg = cnt[v];
    float4 a0 = make_float4(0.f, 0.f, 0.f, 0.f);
    float4 a1 = make_float4(0.f, 0.f, 0.f, 0.f);
    int j = g;
    for (; j + 8 < deg; j += 16) {
        int s0 = col[beg + j];
        int s1 = col[beg + j + 8];
        float4 v0 = ((const float4*)(h2s + (size_t)s0 * CDIM))[l];
        float4 v1 = ((const float4*)(h2s + (size_t)s1 * CDIM))[l];
        a0.x += v0.x; a0.y += v0.y; a0.z += v0.z; a0.w += v0.w;
        a1.x += v1.x; a1.y += v1.y; a1.z += v1.z; a1.w += v1.w;
    }
    if (j < deg) {
        int s0 = col[beg + j];
        float4 v0 = ((const float4*)(h2s + (size_t)s0 * CDIM))[l];
        a0.x += v0.x; a0.y += v0.y; a0.z += v0.z; a0.w += v0.w;
    }
    a0.x += a1.x; a0.y += a1.y; a0.z += a1.z; a0.w += a1.w;
    // reduce across 8 groups (xor 8, 16, 32)
    a0.x += __shfl_xor(a0.x, 8);  a0.y += __shfl_xor(a0.y, 8);
    a0.z += __shfl_xor(a0.z, 8);  a0.w += __shfl_xor(a0.w, 8);
    a0.x += __shfl_xor(a0.x, 16); a0.y += __shfl_xor(a0.y, 16);
    a0.z += __shfl_xor(a0.z, 16); a0.w += __shfl_xor(a0.w, 16);
    a0.x += __shfl_xor(a0.x, 32); a0.y += __shfl_xor(a0.y, 32);
    a0.z += __shfl_xor(a0.z, 32); a0.w += __shfl_xor(a0.w, 32);
    if (g == 0) {
        float dv = dinv[v];
        float4 self = ((const float4*)(h2s + (size_t)v * CDIM))[l];
        float4 bb = ((const float4*)b2)[l];
        float4 o;
        o.x = dv * (a0.x + self.x) + bb.x;
        o.y = dv * (a0.y + self.y) + bb.y;
        o.z = dv * (a0.z + self.z) + bb.z;
        o.w = dv * (a0.w + self.w) + bb.w;
        ((float4*)(out + (size_t)v * CDIM))[l] = o;
    }
}

extern "C" void kernel_launch(void* const* d_in, const int* in_sizes, int n_in,
                              void* d_out, int out_size, void* d_ws, size_t ws_size,
                              hipStream_t stream) {
    const float* x  = (const float*)d_in[0];
    const int*   ei = (const int*)d_in[1];
    const float* W1 = (const float*)d_in[2];
    const float* b1 = (const float*)d_in[3];
    const float* W2 = (const float*)d_in[4];
    const float* b2 = (const float*)d_in[5];
    float* out = (float*)d_out;

    int n = in_sizes[0] / F_IN;
    int e = in_sizes[1] / 2;
    const int* srcIdx = ei;
    const int* dstIdx = ei + e;

    int nb = (n + SCAN_B - 1) / SCAN_B;

    // workspace layout
    int* cnt    = (int*)d_ws;             // n
    int* rowptr = cnt + n;                // n
    int* cursor = rowptr + n;             // n
    int* bsum   = cursor + n;             // nb (padded 4096)
    int* col    = bsum + 4096;            // e
    float* dinv = (float*)(col + e);      // n
    float* xs   = dinv + n;               // n*64
    float* h2s  = xs + (size_t)n * F_IN;  // n*32

    const int B = 256;

    hipMemsetAsync(cnt, 0, (size_t)n * sizeof(int), stream);
    k_hist<<<(e + B - 1) / B, B, 0, stream>>>(dstIdx, e, cnt);
    k_scan_block<<<nb, SCAN_B, 0, stream>>>(cnt, rowptr, bsum, n);
    k_scan_bsums<<<1, 512, 0, stream>>>(bsum, nb);
    k_scan_add_prep<<<(n + B - 1) / B, B, 0, stream>>>(rowptr, bsum, cnt, cursor, dinv, n);
    k_prescale<<<(n * (F_IN / 4) + B - 1) / B, B, 0, stream>>>(x, dinv, xs, n);
    k_fill<<<(e + B - 1) / B, B, 0, stream>>>(srcIdx, dstIdx, e, cursor, col);

    k_layer1_fused<<<(n + 3) / 4, B, 0, stream>>>(xs, rowptr, cnt, col, dinv, W1, b1, W2, h2s, n);
    k_gather2<<<(n + 3) / 4, B, 0, stream>>>(h2s, rowptr, cnt, col, dinv, b2, out, n);
}

// Round 5
// 352.829 us; speedup vs baseline: 1.1864x; 1.1864x over previous
//
#include <hip/hip_runtime.h>

// GCN 2-layer forward, round 5:
//   - CSR-by-dst, atomic-free gathers (unroll x4, 16 rows in flight per wave)
//   - standalone tiled MLP kernel: weights staged in LDS ONCE per 64-row block
//     (R4's fused kernel re-read 48KB of weights per wave -> L1-bound)
//   ax[v]  = dinv[v]*(sum xs[s] + xs[v]),  xs = dinv.*x
//   h2s    = dinv .* (relu(ax@W1+b1) @ W2)
//   out[v] = dinv[v]*(sum h2s[s] + h2s[v]) + b2

#define F_IN 64
#define HDIM 128
#define CDIM 32
#define SCAN_B 256

// ---------- CSR build ----------
__global__ void k_hist(const int* __restrict__ dst, int e, int* __restrict__ cnt) {
    int i = blockIdx.x * blockDim.x + threadIdx.x;
    if (i < e) atomicAdd(&cnt[dst[i]], 1);
}

__global__ void k_scan_block(const int* __restrict__ cnt, int* __restrict__ rowptr,
                             int* __restrict__ bsum, int n) {
    __shared__ int sh[SCAN_B];
    int tid = threadIdx.x;
    int i = blockIdx.x * SCAN_B + tid;
    int v = (i < n) ? cnt[i] : 0;
    sh[tid] = v;
    __syncthreads();
    for (int off = 1; off < SCAN_B; off <<= 1) {
        int t = (tid >= off) ? sh[tid - off] : 0;
        __syncthreads();
        sh[tid] += t;
        __syncthreads();
    }
    if (i < n) rowptr[i] = sh[tid] - v;  // exclusive
    if (tid == SCAN_B - 1) bsum[blockIdx.x] = sh[tid];
}

__global__ void k_scan_bsums(int* __restrict__ bsum, int nb) {
    __shared__ int sh[512];
    int tid = threadIdx.x;
    if (nb <= 512) {
        int v = (tid < nb) ? bsum[tid] : 0;
        sh[tid] = v;
        __syncthreads();
        for (int off = 1; off < 512; off <<= 1) {
            int t = (tid >= off) ? sh[tid - off] : 0;
            __syncthreads();
            sh[tid] += t;
            __syncthreads();
        }
        if (tid < nb) bsum[tid] = sh[tid] - v;
    } else if (tid == 0) {
        int run = 0;
        for (int i = 0; i < nb; ++i) { int t = bsum[i]; bsum[i] = run; run += t; }
    }
}

__global__ void k_scan_add_prep(int* __restrict__ rowptr, const int* __restrict__ bsum,
                                const int* __restrict__ cnt, int* __restrict__ cursor,
                                float* __restrict__ dinv, int n) {
    int i = blockIdx.x * blockDim.x + threadIdx.x;
    if (i >= n) return;
    int rp = rowptr[i] + bsum[i / SCAN_B];
    rowptr[i] = rp;
    cursor[i] = rp;
    dinv[i] = rsqrtf((float)(cnt[i] + 1));
}

__global__ void k_fill(const int* __restrict__ src, const int* __restrict__ dst, int e,
                       int* __restrict__ cursor, int* __restrict__ col) {
    int i = blockIdx.x * blockDim.x + threadIdx.x;
    if (i >= e) return;
    int pos = atomicAdd(&cursor[dst[i]], 1);
    col[pos] = src[i];
}

// xs = dinv .* x  (float4 over n*16)
__global__ void k_prescale(const float* __restrict__ x, const float* __restrict__ dinv,
                           float* __restrict__ xs, int n) {
    int i = blockIdx.x * blockDim.x + threadIdx.x;
    if (i >= n * (F_IN / 4)) return;
    int v = i >> 4;
    float s = dinv[v];
    float4 val = ((const float4*)x)[i];
    val.x *= s; val.y *= s; val.z *= s; val.w *= s;
    ((float4*)xs)[i] = val;
}

// ---------- gather 1 (F=64): wave per node, 16-lane quarters x float4, unroll x4 ----
__global__ void k_gather1(const float* __restrict__ xs, const int* __restrict__ rowptr,
                          const int* __restrict__ cnt, const int* __restrict__ col,
                          const float* __restrict__ dinv, float* __restrict__ ax, int n) {
    int tid = threadIdx.x;
    int w = tid >> 6, lane = tid & 63;
    int v = blockIdx.x * 4 + w;
    if (v >= n) return;  // wave-uniform
    int q = lane >> 4, l = lane & 15;
    int beg = rowptr[v], deg = cnt[v];
    float4 a0 = make_float4(0.f, 0.f, 0.f, 0.f);
    float4 a1 = make_float4(0.f, 0.f, 0.f, 0.f);
    float4 a2 = make_float4(0.f, 0.f, 0.f, 0.f);
    float4 a3 = make_float4(0.f, 0.f, 0.f, 0.f);
    int j = q;
    for (; j + 12 < deg; j += 16) {
        int s0 = col[beg + j];
        int s1 = col[beg + j + 4];
        int s2 = col[beg + j + 8];
        int s3 = col[beg + j + 12];
        float4 v0 = ((const float4*)(xs + (size_t)s0 * F_IN))[l];
        float4 v1 = ((const float4*)(xs + (size_t)s1 * F_IN))[l];
        float4 v2 = ((const float4*)(xs + (size_t)s2 * F_IN))[l];
        float4 v3 = ((const float4*)(xs + (size_t)s3 * F_IN))[l];
        a0.x += v0.x; a0.y += v0.y; a0.z += v0.z; a0.w += v0.w;
        a1.x += v1.x; a1.y += v1.y; a1.z += v1.z; a1.w += v1.w;
        a2.x += v2.x; a2.y += v2.y; a2.z += v2.z; a2.w += v2.w;
        a3.x += v3.x; a3.y += v3.y; a3.z += v3.z; a3.w += v3.w;
    }
    for (; j < deg; j += 4) {
        int s = col[beg + j];
        float4 vv = ((const float4*)(xs + (size_t)s * F_IN))[l];
        a0.x += vv.x; a0.y += vv.y; a0.z += vv.z; a0.w += vv.w;
    }
    a0.x += a1.x + a2.x + a3.x;
    a0.y += a1.y + a2.y + a3.y;
    a0.z += a1.z + a2.z + a3.z;
    a0.w += a1.w + a2.w + a3.w;
    a0.x += __shfl_xor(a0.x, 16); a0.y += __shfl_xor(a0.y, 16);
    a0.z += __shfl_xor(a0.z, 16); a0.w += __shfl_xor(a0.w, 16);
    a0.x += __shfl_xor(a0.x, 32); a0.y += __shfl_xor(a0.y, 32);
    a0.z += __shfl_xor(a0.z, 32); a0.w += __shfl_xor(a0.w, 32);
    if (q == 0) {
        float dv = dinv[v];
        float4 self = ((const float4*)(xs + (size_t)v * F_IN))[l];
        float4 r;
        r.x = dv * (a0.x + self.x);
        r.y = dv * (a0.y + self.y);
        r.z = dv * (a0.z + self.z);
        r.w = dv * (a0.w + self.w);
        ((float4*)(ax + (size_t)v * F_IN))[l] = r;
    }
}

// ---------- tiled MLP: h2s = dinv .* (relu(ax@W1+b1) @ W2) ----------
// block = 256 thr, tile = 64 rows. LDS (floats):
//   phase A: W1s @0 (64*128=8192), axs @8192 ([64][67]=4288)
//   phase B: hsT @0 ([128][68]=8704, overlays dead W1s/axs-head), W2s @8704 (4096)
// total 12800 floats = 51.2KB -> 3 blocks/CU.
__global__ __launch_bounds__(256) void k_mlp(const float* __restrict__ ax,
                                             const float* __restrict__ W1,
                                             const float* __restrict__ b1,
                                             const float* __restrict__ W2,
                                             const float* __restrict__ dinv,
                                             float* __restrict__ h2s, int n) {
    __shared__ float smem[12800];
    float* W1s = smem;          // [64][128]
    float* axs = smem + 8192;   // [64][67] padded
    float* hsT = smem;          // [128][68] padded (phase B)
    float* W2s = smem + 8704;   // [128][32]

    int tid = threadIdx.x;
    int v0 = blockIdx.x * 64;
    int rg = tid >> 4;          // 0..15 (row group of 4)
    int cg = tid & 15;          // 0..15

    // stage W1 and ax tile
    for (int t = tid; t < 2048; t += 256) {
        int k = t >> 5, c4 = (t & 31) * 4;
        *(float4*)&W1s[k * 128 + c4] = *(const float4*)&W1[k * 128 + c4];
    }
    for (int t = tid; t < 1024; t += 256) {
        int row = t >> 4, k4 = (t & 15) * 4;
        float4 val = make_float4(0.f, 0.f, 0.f, 0.f);
        if (v0 + row < n) val = *(const float4*)&ax[(size_t)(v0 + row) * F_IN + k4];
        axs[row * 67 + k4 + 0] = val.x;
        axs[row * 67 + k4 + 1] = val.y;
        axs[row * 67 + k4 + 2] = val.z;
        axs[row * 67 + k4 + 3] = val.w;
    }
    __syncthreads();

    // phase A: [64x64] @ [64x128] -> acc[4][8]
    float acc[4][8];
#pragma unroll
    for (int i = 0; i < 4; ++i)
#pragma unroll
        for (int j = 0; j < 8; ++j) acc[i][j] = 0.f;

#pragma unroll 4
    for (int k = 0; k < 64; ++k) {
        float a0 = axs[(rg * 4 + 0) * 67 + k];
        float a1 = axs[(rg * 4 + 1) * 67 + k];
        float a2 = axs[(rg * 4 + 2) * 67 + k];
        float a3 = axs[(rg * 4 + 3) * 67 + k];
        float4 w0 = *(float4*)&W1s[k * 128 + cg * 8];
        float4 w1 = *(float4*)&W1s[k * 128 + cg * 8 + 4];
        acc[0][0] = fmaf(a0, w0.x, acc[0][0]); acc[0][1] = fmaf(a0, w0.y, acc[0][1]);
        acc[0][2] = fmaf(a0, w0.z, acc[0][2]); acc[0][3] = fmaf(a0, w0.w, acc[0][3]);
        acc[0][4] = fmaf(a0, w1.x, acc[0][4]); acc[0][5] = fmaf(a0, w1.y, acc[0][5]);
        acc[0][6] = fmaf(a0, w1.z, acc[0][6]); acc[0][7] = fmaf(a0, w1.w, acc[0][7]);
        acc[1][0] = fmaf(a1, w0.x, acc[1][0]); acc[1][1] = fmaf(a1, w0.y, acc[1][1]);
        acc[1][2] = fmaf(a1, w0.z, acc[1][2]); acc[1][3] = fmaf(a1, w0.w, acc[1][3]);
        acc[1][4] = fmaf(a1, w1.x, acc[1][4]); acc[1][5] = fmaf(a1, w1.y, acc[1][5]);
        acc[1][6] = fmaf(a1, w1.z, acc[1][6]); acc[1][7] = fmaf(a1, w1.w, acc[1][7]);
        acc[2][0] = fmaf(a2, w0.x, acc[2][0]); acc[2][1] = fmaf(a2, w0.y, acc[2][1]);
        acc[2][2] = fmaf(a2, w0.z, acc[2][2]); acc[2][3] = fmaf(a2, w0.w, acc[2][3]);
        acc[2][4] = fmaf(a2, w1.x, acc[2][4]); acc[2][5] = fmaf(a2, w1.y, acc[2][5]);
        acc[2][6] = fmaf(a2, w1.z, acc[2][6]); acc[2][7] = fmaf(a2, w1.w, acc[2][7]);
        acc[3][0] = fmaf(a3, w0.x, acc[3][0]); acc[3][1] = fmaf(a3, w0.y, acc[3][1]);
        acc[3][2] = fmaf(a3, w0.z, acc[3][2]); acc[3][3] = fmaf(a3, w0.w, acc[3][3]);
        acc[3][4] = fmaf(a3, w1.x, acc[3][4]); acc[3][5] = fmaf(a3, w1.y, acc[3][5]);
        acc[3][6] = fmaf(a3, w1.z, acc[3][6]); acc[3][7] = fmaf(a3, w1.w, acc[3][7]);
    }
    __syncthreads();  // W1s/axs dead; safe to overwrite with hsT

    // epilogue A: bias + relu, store h transposed; stage W2
    {
        float4 bb0 = *(const float4*)&b1[cg * 8];
        float4 bb1 = *(const float4*)&b1[cg * 8 + 4];
        float bias[8] = {bb0.x, bb0.y, bb0.z, bb0.w, bb1.x, bb1.y, bb1.z, bb1.w};
#pragma unroll
        for (int j = 0; j < 8; ++j) {
            float4 hv;
            hv.x = acc[0][j] + bias[j]; hv.x = hv.x > 0.f ? hv.x : 0.f;
            hv.y = acc[1][j] + bias[j]; hv.y = hv.y > 0.f ? hv.y : 0.f;
            hv.z = acc[2][j] + bias[j]; hv.z = hv.z > 0.f ? hv.z : 0.f;
            hv.w = acc[3][j] + bias[j]; hv.w = hv.w > 0.f ? hv.w : 0.f;
            *(float4*)&hsT[(cg * 8 + j) * 68 + rg * 4] = hv;
        }
    }
    for (int t = tid; t < 1024; t += 256) {
        int k = t >> 3, c4 = (t & 7) * 4;
        *(float4*)&W2s[k * 32 + c4] = *(const float4*)&W2[k * 32 + c4];
    }
    __syncthreads();

    // phase B: [64x128] @ [128x32] -> acc2[4][2]
    float acc2[4][2] = {{0.f, 0.f}, {0.f, 0.f}, {0.f, 0.f}, {0.f, 0.f}};
#pragma unroll 8
    for (int k = 0; k < 128; ++k) {
        float4 hh = *(float4*)&hsT[k * 68 + rg * 4];
        float w0 = W2s[k * 32 + cg * 2];
        float w1 = W2s[k * 32 + cg * 2 + 1];
        acc2[0][0] = fmaf(hh.x, w0, acc2[0][0]); acc2[0][1] = fmaf(hh.x, w1, acc2[0][1]);
        acc2[1][0] = fmaf(hh.y, w0, acc2[1][0]); acc2[1][1] = fmaf(hh.y, w1, acc2[1][1]);
        acc2[2][0] = fmaf(hh.z, w0, acc2[2][0]); acc2[2][1] = fmaf(hh.z, w1, acc2[2][1]);
        acc2[3][0] = fmaf(hh.w, w0, acc2[3][0]); acc2[3][1] = fmaf(hh.w, w1, acc2[3][1]);
    }
#pragma unroll
    for (int i = 0; i < 4; ++i) {
        int v = v0 + rg * 4 + i;
        if (v < n) {
            float dv = dinv[v];
            float2 o = make_float2(dv * acc2[i][0], dv * acc2[i][1]);
            *(float2*)&h2s[(size_t)v * CDIM + cg * 2] = o;
        }
    }
}

// ---------- gather 2 (C=32): wave per node, 8-lane groups x float4, unroll x2 ----
__global__ void k_gather2(const float* __restrict__ h2s, const int* __restrict__ rowptr,
                          const int* __restrict__ cnt, const int* __restrict__ col,
                          const float* __restrict__ dinv, const float* __restrict__ b2,
                          float* __restrict__ out, int n) {
    int tid = threadIdx.x;
    int w = tid >> 6, lane = tid & 63;
    int v = blockIdx.x * 4 + w;
    if (v >= n) return;  // wave-uniform
    int g = lane >> 3, l = lane & 7;
    int beg = rowptr[v], deg = cnt[v];
    float4 a0 = make_float4(0.f, 0.f, 0.f, 0.f);
    float4 a1 = make_float4(0.f, 0.f, 0.f, 0.f);
    int j = g;
    for (; j + 8 < deg; j += 16) {
        int s0 = col[beg + j];
        int s1 = col[beg + j + 8];
        float4 v0 = ((const float4*)(h2s + (size_t)s0 * CDIM))[l];
        float4 v1 = ((const float4*)(h2s + (size_t)s1 * CDIM))[l];
        a0.x += v0.x; a0.y += v0.y; a0.z += v0.z; a0.w += v0.w;
        a1.x += v1.x; a1.y += v1.y; a1.z += v1.z; a1.w += v1.w;
    }
    if (j < deg) {
        int s0 = col[beg + j];
        float4 v0 = ((const float4*)(h2s + (size_t)s0 * CDIM))[l];
        a0.x += v0.x; a0.y += v0.y; a0.z += v0.z; a0.w += v0.w;
    }
    a0.x += a1.x; a0.y += a1.y; a0.z += a1.z; a0.w += a1.w;
    a0.x += __shfl_xor(a0.x, 8);  a0.y += __shfl_xor(a0.y, 8);
    a0.z += __shfl_xor(a0.z, 8);  a0.w += __shfl_xor(a0.w, 8);
    a0.x += __shfl_xor(a0.x, 16); a0.y += __shfl_xor(a0.y, 16);
    a0.z += __shfl_xor(a0.z, 16); a0.w += __shfl_xor(a0.w, 16);
    a0.x += __shfl_xor(a0.x, 32); a0.y += __shfl_xor(a0.y, 32);
    a0.z += __shfl_xor(a0.z, 32); a0.w += __shfl_xor(a0.w, 32);
    if (g == 0) {
        float dv = dinv[v];
        float4 self = ((const float4*)(h2s + (size_t)v * CDIM))[l];
        float4 bb = ((const float4*)b2)[l];
        float4 o;
        o.x = dv * (a0.x + self.x) + bb.x;
        o.y = dv * (a0.y + self.y) + bb.y;
        o.z = dv * (a0.z + self.z) + bb.z;
        o.w = dv * (a0.w + self.w) + bb.w;
        ((float4*)(out + (size_t)v * CDIM))[l] = o;
    }
}

extern "C" void kernel_launch(void* const* d_in, const int* in_sizes, int n_in,
                              void* d_out, int out_size, void* d_ws, size_t ws_size,
                              hipStream_t stream) {
    const float* x  = (const float*)d_in[0];
    const int*   ei = (const int*)d_in[1];
    const float* W1 = (const float*)d_in[2];
    const float* b1 = (const float*)d_in[3];
    const float* W2 = (const float*)d_in[4];
    const float* b2 = (const float*)d_in[5];
    float* out = (float*)d_out;

    int n = in_sizes[0] / F_IN;
    int e = in_sizes[1] / 2;
    const int* srcIdx = ei;
    const int* dstIdx = ei + e;

    int nb = (n + SCAN_B - 1) / SCAN_B;

    // workspace layout
    int* cnt    = (int*)d_ws;             // n
    int* rowptr = cnt + n;                // n
    int* cursor = rowptr + n;             // n
    int* bsum   = cursor + n;             // nb (padded 4096)
    int* col    = bsum + 4096;            // e
    float* dinv = (float*)(col + e);      // n
    float* xs   = dinv + n;               // n*64
    float* ax   = xs + (size_t)n * F_IN;  // n*64
    float* h2s  = ax + (size_t)n * F_IN;  // n*32

    const int B = 256;

    hipMemsetAsync(cnt, 0, (size_t)n * sizeof(int), stream);
    k_hist<<<(e + B - 1) / B, B, 0, stream>>>(dstIdx, e, cnt);
    k_scan_block<<<nb, SCAN_B, 0, stream>>>(cnt, rowptr, bsum, n);
    k_scan_bsums<<<1, 512, 0, stream>>>(bsum, nb);
    k_scan_add_prep<<<(n + B - 1) / B, B, 0, stream>>>(rowptr, bsum, cnt, cursor, dinv, n);
    k_prescale<<<(n * (F_IN / 4) + B - 1) / B, B, 0, stream>>>(x, dinv, xs, n);
    k_fill<<<(e + B - 1) / B, B, 0, stream>>>(srcIdx, dstIdx, e, cursor, col);

    k_gather1<<<(n + 3) / 4, B, 0, stream>>>(xs, rowptr, cnt, col, dinv, ax, n);
    k_mlp<<<(n + 63) / 64, B, 0, stream>>>(ax, W1, b1, W2, dinv, h2s, n);
    k_gather2<<<(n + 3) / 4, B, 0, stream>>>(h2s, rowptr, cnt, col, dinv, b2, out, n);
}

// Round 6
// 351.874 us; speedup vs baseline: 1.1896x; 1.0027x over previous
//
#include <hip/hip_runtime.h>

// GCN 2-layer forward, round 6:
//   R5 + binned CSR build (k_fill's 105MB scattered partial-line writes -> 
//   two-level bucket sort with coalesced run writes + L2-local counting sort).
//   ax[v]  = dinv[v]*(sum xs[s] + xs[v]),  xs = dinv.*x
//   h2s    = dinv .* (relu(ax@W1+b1) @ W2)
//   out[v] = dinv[v]*(sum h2s[s] + h2s[v]) + b2

#define F_IN 64
#define HDIM 128
#define CDIM 32
#define SCAN_B 256
#define BK 256          // nodes per bucket (must equal kb_fill2 blockDim)
#define SC_CHUNK 16384  // edges per kb_scatter workgroup

// ---------- degree histogram ----------
__global__ void k_hist(const int* __restrict__ dst, int e, int* __restrict__ cnt) {
    int i = blockIdx.x * blockDim.x + threadIdx.x;
    if (i < e) atomicAdd(&cnt[dst[i]], 1);
}

__global__ void k_scan_block(const int* __restrict__ cnt, int* __restrict__ rowptr,
                             int* __restrict__ bsum, int n) {
    __shared__ int sh[SCAN_B];
    int tid = threadIdx.x;
    int i = blockIdx.x * SCAN_B + tid;
    int v = (i < n) ? cnt[i] : 0;
    sh[tid] = v;
    __syncthreads();
    for (int off = 1; off < SCAN_B; off <<= 1) {
        int t = (tid >= off) ? sh[tid - off] : 0;
        __syncthreads();
        sh[tid] += t;
        __syncthreads();
    }
    if (i < n) rowptr[i] = sh[tid] - v;  // exclusive
    if (tid == SCAN_B - 1) bsum[blockIdx.x] = sh[tid];
}

__global__ void k_scan_bsums(int* __restrict__ bsum, int nb) {
    __shared__ int sh[512];
    int tid = threadIdx.x;
    if (nb <= 512) {
        int v = (tid < nb) ? bsum[tid] : 0;
        sh[tid] = v;
        __syncthreads();
        for (int off = 1; off < 512; off <<= 1) {
            int t = (tid >= off) ? sh[tid - off] : 0;
            __syncthreads();
            sh[tid] += t;
            __syncthreads();
        }
        if (tid < nb) bsum[tid] = sh[tid] - v;
    } else if (tid == 0) {
        int run = 0;
        for (int i = 0; i < nb; ++i) { int t = bsum[i]; bsum[i] = run; run += t; }
    }
}

// rowptr += block offset; dinv = rsqrt(deg+1)
__global__ void k_scan_add_prep(int* __restrict__ rowptr, const int* __restrict__ bsum,
                                const int* __restrict__ cnt, float* __restrict__ dinv, int n) {
    int i = blockIdx.x * blockDim.x + threadIdx.x;
    if (i >= n) return;
    rowptr[i] += bsum[i / SCAN_B];
    dinv[i] = rsqrtf((float)(cnt[i] + 1));
}

// ---------- binned CSR fill ----------
// bucket = dst >> 8 (BK=256 nodes/bucket); nbk <= 511 for n <= 130816.
__global__ void kb_hist(const int* __restrict__ dst, int e, int nbk,
                        int* __restrict__ bucketCnt) {
    __shared__ int lh[512];
    int tid = threadIdx.x;
    for (int i = tid; i < nbk; i += blockDim.x) lh[i] = 0;
    __syncthreads();
    for (int i = blockIdx.x * blockDim.x + tid; i < e; i += gridDim.x * blockDim.x)
        atomicAdd(&lh[dst[i] >> 8], 1);
    __syncthreads();
    for (int i = tid; i < nbk; i += blockDim.x)
        if (lh[i]) atomicAdd(&bucketCnt[i], lh[i]);
}

// exclusive scan of bucketCnt -> bucketBase (+total at [nbk]); cursor copy
__global__ void kb_scan(const int* __restrict__ bucketCnt, int* __restrict__ bucketBase,
                        int* __restrict__ bucketCursor, int nbk) {
    __shared__ int sh[512];
    int tid = threadIdx.x;
    int v = (tid < nbk) ? bucketCnt[tid] : 0;
    sh[tid] = v;
    __syncthreads();
    for (int off = 1; off < 512; off <<= 1) {
        int t = (tid >= off) ? sh[tid - off] : 0;
        __syncthreads();
        sh[tid] += t;
        __syncthreads();
    }
    if (tid < nbk) {
        bucketBase[tid] = sh[tid] - v;
        bucketCursor[tid] = sh[tid] - v;
    }
    if (tid == nbk) bucketBase[tid] = sh[511];  // total = e
}

// per-wg LDS histogram -> contiguous run reservation -> coalesced staging writes
__global__ void kb_scatter(const int* __restrict__ src, const int* __restrict__ dst, int e,
                           int nbk, int* __restrict__ bucketCursor, uint2* __restrict__ staging) {
    __shared__ int lh[512];
    __shared__ int lbase[512];
    int tid = threadIdx.x;
    int c0 = blockIdx.x * SC_CHUNK;
    int c1 = min(c0 + SC_CHUNK, e);
    for (int i = tid; i < nbk; i += blockDim.x) lh[i] = 0;
    __syncthreads();
    for (int i = c0 + tid; i < c1; i += blockDim.x)
        atomicAdd(&lh[dst[i] >> 8], 1);
    __syncthreads();
    for (int i = tid; i < nbk; i += blockDim.x) {
        int c = lh[i];
        lbase[i] = c ? atomicAdd(&bucketCursor[i], c) : 0;
        lh[i] = 0;  // becomes local cursor
    }
    __syncthreads();
    for (int i = c0 + tid; i < c1; i += blockDim.x) {
        int d = dst[i];
        int b = d >> 8;
        int r = atomicAdd(&lh[b], 1);
        staging[lbase[b] + r] = make_uint2((unsigned)src[i], (unsigned)d);
    }
}

// one wg per bucket: counting-sort staged edges into col (L2-local 16KB window)
__global__ void kb_fill2(const uint2* __restrict__ staging, const int* __restrict__ bucketBase,
                         const int* __restrict__ rowptr, int* __restrict__ col, int n) {
    __shared__ int cur[BK];
    int b = blockIdx.x;
    int tid = threadIdx.x;  // == BK
    int v = b * BK + tid;
    cur[tid] = (v < n) ? rowptr[v] : 0;
    __syncthreads();
    int beg = bucketBase[b], end = bucketBase[b + 1];
    for (int i = beg + tid; i < end; i += blockDim.x) {
        uint2 sd = staging[i];
        int pos = atomicAdd(&cur[sd.y & (BK - 1)], 1);
        col[pos] = (int)sd.x;
    }
}

// xs = dinv .* x  (float4 over n*16)
__global__ void k_prescale(const float* __restrict__ x, const float* __restrict__ dinv,
                           float* __restrict__ xs, int n) {
    int i = blockIdx.x * blockDim.x + threadIdx.x;
    if (i >= n * (F_IN / 4)) return;
    int v = i >> 4;
    float s = dinv[v];
    float4 val = ((const float4*)x)[i];
    val.x *= s; val.y *= s; val.z *= s; val.w *= s;
    ((float4*)xs)[i] = val;
}

// ---------- gather 1 (F=64): wave per node, 16-lane quarters x float4, unroll x4 ----
__global__ void k_gather1(const float* __restrict__ xs, const int* __restrict__ rowptr,
                          const int* __restrict__ cnt, const int* __restrict__ col,
                          const float* __restrict__ dinv, float* __restrict__ ax, int n) {
    int tid = threadIdx.x;
    int w = tid >> 6, lane = tid & 63;
    int v = blockIdx.x * 4 + w;
    if (v >= n) return;  // wave-uniform
    int q = lane >> 4, l = lane & 15;
    int beg = rowptr[v], deg = cnt[v];
    float4 a0 = make_float4(0.f, 0.f, 0.f, 0.f);
    float4 a1 = make_float4(0.f, 0.f, 0.f, 0.f);
    float4 a2 = make_float4(0.f, 0.f, 0.f, 0.f);
    float4 a3 = make_float4(0.f, 0.f, 0.f, 0.f);
    int j = q;
    for (; j + 12 < deg; j += 16) {
        int s0 = col[beg + j];
        int s1 = col[beg + j + 4];
        int s2 = col[beg + j + 8];
        int s3 = col[beg + j + 12];
        float4 v0 = ((const float4*)(xs + (size_t)s0 * F_IN))[l];
        float4 v1 = ((const float4*)(xs + (size_t)s1 * F_IN))[l];
        float4 v2 = ((const float4*)(xs + (size_t)s2 * F_IN))[l];
        float4 v3 = ((const float4*)(xs + (size_t)s3 * F_IN))[l];
        a0.x += v0.x; a0.y += v0.y; a0.z += v0.z; a0.w += v0.w;
        a1.x += v1.x; a1.y += v1.y; a1.z += v1.z; a1.w += v1.w;
        a2.x += v2.x; a2.y += v2.y; a2.z += v2.z; a2.w += v2.w;
        a3.x += v3.x; a3.y += v3.y; a3.z += v3.z; a3.w += v3.w;
    }
    for (; j < deg; j += 4) {
        int s = col[beg + j];
        float4 vv = ((const float4*)(xs + (size_t)s * F_IN))[l];
        a0.x += vv.x; a0.y += vv.y; a0.z += vv.z; a0.w += vv.w;
    }
    a0.x += a1.x + a2.x + a3.x;
    a0.y += a1.y + a2.y + a3.y;
    a0.z += a1.z + a2.z + a3.z;
    a0.w += a1.w + a2.w + a3.w;
    a0.x += __shfl_xor(a0.x, 16); a0.y += __shfl_xor(a0.y, 16);
    a0.z += __shfl_xor(a0.z, 16); a0.w += __shfl_xor(a0.w, 16);
    a0.x += __shfl_xor(a0.x, 32); a0.y += __shfl_xor(a0.y, 32);
    a0.z += __shfl_xor(a0.z, 32); a0.w += __shfl_xor(a0.w, 32);
    if (q == 0) {
        float dv = dinv[v];
        float4 self = ((const float4*)(xs + (size_t)v * F_IN))[l];
        float4 r;
        r.x = dv * (a0.x + self.x);
        r.y = dv * (a0.y + self.y);
        r.z = dv * (a0.z + self.z);
        r.w = dv * (a0.w + self.w);
        ((float4*)(ax + (size_t)v * F_IN))[l] = r;
    }
}

// ---------- tiled MLP: h2s = dinv .* (relu(ax@W1+b1) @ W2) ----------
__global__ __launch_bounds__(256) void k_mlp(const float* __restrict__ ax,
                                             const float* __restrict__ W1,
                                             const float* __restrict__ b1,
                                             const float* __restrict__ W2,
                                             const float* __restrict__ dinv,
                                             float* __restrict__ h2s, int n) {
    __shared__ float smem[12800];
    float* W1s = smem;          // [64][128]
    float* axs = smem + 8192;   // [64][67] padded
    float* hsT = smem;          // [128][68] padded (phase B)
    float* W2s = smem + 8704;   // [128][32]

    int tid = threadIdx.x;
    int v0 = blockIdx.x * 64;
    int rg = tid >> 4;          // 0..15
    int cg = tid & 15;          // 0..15

    for (int t = tid; t < 2048; t += 256) {
        int k = t >> 5, c4 = (t & 31) * 4;
        *(float4*)&W1s[k * 128 + c4] = *(const float4*)&W1[k * 128 + c4];
    }
    for (int t = tid; t < 1024; t += 256) {
        int row = t >> 4, k4 = (t & 15) * 4;
        float4 val = make_float4(0.f, 0.f, 0.f, 0.f);
        if (v0 + row < n) val = *(const float4*)&ax[(size_t)(v0 + row) * F_IN + k4];
        axs[row * 67 + k4 + 0] = val.x;
        axs[row * 67 + k4 + 1] = val.y;
        axs[row * 67 + k4 + 2] = val.z;
        axs[row * 67 + k4 + 3] = val.w;
    }
    __syncthreads();

    float acc[4][8];
#pragma unroll
    for (int i = 0; i < 4; ++i)
#pragma unroll
        for (int j = 0; j < 8; ++j) acc[i][j] = 0.f;

#pragma unroll 4
    for (int k = 0; k < 64; ++k) {
        float a0 = axs[(rg * 4 + 0) * 67 + k];
        float a1 = axs[(rg * 4 + 1) * 67 + k];
        float a2 = axs[(rg * 4 + 2) * 67 + k];
        float a3 = axs[(rg * 4 + 3) * 67 + k];
        float4 w0 = *(float4*)&W1s[k * 128 + cg * 8];
        float4 w1 = *(float4*)&W1s[k * 128 + cg * 8 + 4];
        acc[0][0] = fmaf(a0, w0.x, acc[0][0]); acc[0][1] = fmaf(a0, w0.y, acc[0][1]);
        acc[0][2] = fmaf(a0, w0.z, acc[0][2]); acc[0][3] = fmaf(a0, w0.w, acc[0][3]);
        acc[0][4] = fmaf(a0, w1.x, acc[0][4]); acc[0][5] = fmaf(a0, w1.y, acc[0][5]);
        acc[0][6] = fmaf(a0, w1.z, acc[0][6]); acc[0][7] = fmaf(a0, w1.w, acc[0][7]);
        acc[1][0] = fmaf(a1, w0.x, acc[1][0]); acc[1][1] = fmaf(a1, w0.y, acc[1][1]);
        acc[1][2] = fmaf(a1, w0.z, acc[1][2]); acc[1][3] = fmaf(a1, w0.w, acc[1][3]);
        acc[1][4] = fmaf(a1, w1.x, acc[1][4]); acc[1][5] = fmaf(a1, w1.y, acc[1][5]);
        acc[1][6] = fmaf(a1, w1.z, acc[1][6]); acc[1][7] = fmaf(a1, w1.w, acc[1][7]);
        acc[2][0] = fmaf(a2, w0.x, acc[2][0]); acc[2][1] = fmaf(a2, w0.y, acc[2][1]);
        acc[2][2] = fmaf(a2, w0.z, acc[2][2]); acc[2][3] = fmaf(a2, w0.w, acc[2][3]);
        acc[2][4] = fmaf(a2, w1.x, acc[2][4]); acc[2][5] = fmaf(a2, w1.y, acc[2][5]);
        acc[2][6] = fmaf(a2, w1.z, acc[2][6]); acc[2][7] = fmaf(a2, w1.w, acc[2][7]);
        acc[3][0] = fmaf(a3, w0.x, acc[3][0]); acc[3][1] = fmaf(a3, w0.y, acc[3][1]);
        acc[3][2] = fmaf(a3, w0.z, acc[3][2]); acc[3][3] = fmaf(a3, w0.w, acc[3][3]);
        acc[3][4] = fmaf(a3, w1.x, acc[3][4]); acc[3][5] = fmaf(a3, w1.y, acc[3][5]);
        acc[3][6] = fmaf(a3, w1.z, acc[3][6]); acc[3][7] = fmaf(a3, w1.w, acc[3][7]);
    }
    __syncthreads();  // W1s/axs dead

    {
        float4 bb0 = *(const float4*)&b1[cg * 8];
        float4 bb1 = *(const float4*)&b1[cg * 8 + 4];
        float bias[8] = {bb0.x, bb0.y, bb0.z, bb0.w, bb1.x, bb1.y, bb1.z, bb1.w};
#pragma unroll
        for (int j = 0; j < 8; ++j) {
            float4 hv;
            hv.x = acc[0][j] + bias[j]; hv.x = hv.x > 0.f ? hv.x : 0.f;
            hv.y = acc[1][j] + bias[j]; hv.y = hv.y > 0.f ? hv.y : 0.f;
            hv.z = acc[2][j] + bias[j]; hv.z = hv.z > 0.f ? hv.z : 0.f;
            hv.w = acc[3][j] + bias[j]; hv.w = hv.w > 0.f ? hv.w : 0.f;
            *(float4*)&hsT[(cg * 8 + j) * 68 + rg * 4] = hv;
        }
    }
    for (int t = tid; t < 1024; t += 256) {
        int k = t >> 3, c4 = (t & 7) * 4;
        *(float4*)&W2s[k * 32 + c4] = *(const float4*)&W2[k * 32 + c4];
    }
    __syncthreads();

    float acc2[4][2] = {{0.f, 0.f}, {0.f, 0.f}, {0.f, 0.f}, {0.f, 0.f}};
#pragma unroll 8
    for (int k = 0; k < 128; ++k) {
        float4 hh = *(float4*)&hsT[k * 68 + rg * 4];
        float w0 = W2s[k * 32 + cg * 2];
        float w1 = W2s[k * 32 + cg * 2 + 1];
        acc2[0][0] = fmaf(hh.x, w0, acc2[0][0]); acc2[0][1] = fmaf(hh.x, w1, acc2[0][1]);
        acc2[1][0] = fmaf(hh.y, w0, acc2[1][0]); acc2[1][1] = fmaf(hh.y, w1, acc2[1][1]);
        acc2[2][0] = fmaf(hh.z, w0, acc2[2][0]); acc2[2][1] = fmaf(hh.z, w1, acc2[2][1]);
        acc2[3][0] = fmaf(hh.w, w0, acc2[3][0]); acc2[3][1] = fmaf(hh.w, w1, acc2[3][1]);
    }
#pragma unroll
    for (int i = 0; i < 4; ++i) {
        int v = v0 + rg * 4 + i;
        if (v < n) {
            float dv = dinv[v];
            float2 o = make_float2(dv * acc2[i][0], dv * acc2[i][1]);
            *(float2*)&h2s[(size_t)v * CDIM + cg * 2] = o;
        }
    }
}

// ---------- gather 2 (C=32): wave per node, 8-lane groups x float4, unroll x2 ----
__global__ void k_gather2(const float* __restrict__ h2s, const int* __restrict__ rowptr,
                          const int* __restrict__ cnt, const int* __restrict__ col,
                          const float* __restrict__ dinv, const float* __restrict__ b2,
                          float* __restrict__ out, int n) {
    int tid = threadIdx.x;
    int w = tid >> 6, lane = tid & 63;
    int v = blockIdx.x * 4 + w;
    if (v >= n) return;  // wave-uniform
    int g = lane >> 3, l = lane & 7;
    int beg = rowptr[v], deg = cnt[v];
    float4 a0 = make_float4(0.f, 0.f, 0.f, 0.f);
    float4 a1 = make_float4(0.f, 0.f, 0.f, 0.f);
    int j = g;
    for (; j + 8 < deg; j += 16) {
        int s0 = col[beg + j];
        int s1 = col[beg + j + 8];
        float4 v0 = ((const float4*)(h2s + (size_t)s0 * CDIM))[l];
        float4 v1 = ((const float4*)(h2s + (size_t)s1 * CDIM))[l];
        a0.x += v0.x; a0.y += v0.y; a0.z += v0.z; a0.w += v0.w;
        a1.x += v1.x; a1.y += v1.y; a1.z += v1.z; a1.w += v1.w;
    }
    if (j < deg) {
        int s0 = col[beg + j];
        float4 v0 = ((const float4*)(h2s + (size_t)s0 * CDIM))[l];
        a0.x += v0.x; a0.y += v0.y; a0.z += v0.z; a0.w += v0.w;
    }
    a0.x += a1.x; a0.y += a1.y; a0.z += a1.z; a0.w += a1.w;
    a0.x += __shfl_xor(a0.x, 8);  a0.y += __shfl_xor(a0.y, 8);
    a0.z += __shfl_xor(a0.z, 8);  a0.w += __shfl_xor(a0.w, 8);
    a0.x += __shfl_xor(a0.x, 16); a0.y += __shfl_xor(a0.y, 16);
    a0.z += __shfl_xor(a0.z, 16); a0.w += __shfl_xor(a0.w, 16);
    a0.x += __shfl_xor(a0.x, 32); a0.y += __shfl_xor(a0.y, 32);
    a0.z += __shfl_xor(a0.z, 32); a0.w += __shfl_xor(a0.w, 32);
    if (g == 0) {
        float dv = dinv[v];
        float4 self = ((const float4*)(h2s + (size_t)v * CDIM))[l];
        float4 bb = ((const float4*)b2)[l];
        float4 o;
        o.x = dv * (a0.x + self.x) + bb.x;
        o.y = dv * (a0.y + self.y) + bb.y;
        o.z = dv * (a0.z + self.z) + bb.z;
        o.w = dv * (a0.w + self.w) + bb.w;
        ((float4*)(out + (size_t)v * CDIM))[l] = o;
    }
}

extern "C" void kernel_launch(void* const* d_in, const int* in_sizes, int n_in,
                              void* d_out, int out_size, void* d_ws, size_t ws_size,
                              hipStream_t stream) {
    const float* x  = (const float*)d_in[0];
    const int*   ei = (const int*)d_in[1];
    const float* W1 = (const float*)d_in[2];
    const float* b1 = (const float*)d_in[3];
    const float* W2 = (const float*)d_in[4];
    const float* b2 = (const float*)d_in[5];
    float* out = (float*)d_out;

    int n = in_sizes[0] / F_IN;
    int e = in_sizes[1] / 2;
    const int* srcIdx = ei;
    const int* dstIdx = ei + e;

    int nb = (n + SCAN_B - 1) / SCAN_B;
    int nbk = (n + BK - 1) / BK;  // coarse buckets (391 for n=100K, needs <= 511)

    // workspace layout (4B units):
    //   cnt[n] | bucketCnt[512] | bucketBase[520] | bucketCursor[512] |
    //   rowptr[n] | bsum[4096] | col[e] | dinv[n] | xs[64n] | ax[64n] | h2s[32n]
    //   staging(uint2 e) overlays ax (dead until gather1; 8e bytes <= 256n bytes)
    int* cnt          = (int*)d_ws;
    int* bucketCnt    = cnt + n;
    int* bucketBase   = bucketCnt + 512;
    int* bucketCursor = bucketBase + 520;
    int* rowptr       = bucketCursor + 512;
    int* bsum         = rowptr + n;
    int* col          = bsum + 4096;
    float* dinv       = (float*)(col + e);
    float* xs         = dinv + n;
    float* ax         = xs + (size_t)n * F_IN;
    float* h2s        = ax + (size_t)n * F_IN;
    uint2* staging    = (uint2*)ax;

    const int B = 256;

    // zero cnt + bucketCnt in one shot (adjacent)
    hipMemsetAsync(cnt, 0, ((size_t)n + 512) * sizeof(int), stream);

    // degree + CSR rowptr + dinv
    k_hist<<<(e + B - 1) / B, B, 0, stream>>>(dstIdx, e, cnt);
    k_scan_block<<<nb, SCAN_B, 0, stream>>>(cnt, rowptr, bsum, n);
    k_scan_bsums<<<1, 512, 0, stream>>>(bsum, nb);
    k_scan_add_prep<<<(n + B - 1) / B, B, 0, stream>>>(rowptr, bsum, cnt, dinv, n);

    // binned edge sort -> col
    kb_hist<<<256, B, 0, stream>>>(dstIdx, e, nbk, bucketCnt);
    kb_scan<<<1, 512, 0, stream>>>(bucketCnt, bucketBase, bucketCursor, nbk);
    kb_scatter<<<(e + SC_CHUNK - 1) / SC_CHUNK, B, 0, stream>>>(srcIdx, dstIdx, e, nbk,
                                                                bucketCursor, staging);
    kb_fill2<<<nbk, BK, 0, stream>>>(staging, bucketBase, rowptr, col, n);

    // layer 1
    k_prescale<<<(n * (F_IN / 4) + B - 1) / B, B, 0, stream>>>(x, dinv, xs, n);
    k_gather1<<<(n + 3) / 4, B, 0, stream>>>(xs, rowptr, cnt, col, dinv, ax, n);
    k_mlp<<<(n + 63) / 64, B, 0, stream>>>(ax, W1, b1, W2, dinv, h2s, n);
    k_gather2<<<(n + 3) / 4, B, 0, stream>>>(h2s, rowptr, cnt, col, dinv, b2, out, n);
}

// Round 7
// 281.961 us; speedup vs baseline: 1.4846x; 1.2480x over previous
//
#include <hip/hip_runtime.h>
#include <hip/hip_fp16.h>

// GCN 2-layer forward, round 7:
//   R6 + fp16 gather payloads (xs, h2s as __half: halves random-row traffic)
//      + fused degree/bucket histogram (one dst pass)
//      + 4x kb_scatter parallelism (SC_CHUNK 16384 -> 4096)
//   ax[v]  = dinv[v]*(sum xs[s] + xs[v]),  xs = fp16(dinv.*x)
//   h2s    = fp16(dinv .* (relu(ax@W1+b1) @ W2))
//   out[v] = dinv[v]*(sum h2s[s] + h2s[v]) + b2

#define F_IN 64
#define HDIM 128
#define CDIM 32
#define SCAN_B 256
#define BK 256          // nodes per bucket (== kb_fill2 blockDim)
#define SC_CHUNK 4096   // edges per kb_scatter workgroup

struct h4 { __half2 a, b; };  // 8-byte packed 4x fp16

// ---------- fused degree + bucket histogram (one pass over dst) ----------
__global__ void k_histboth(const int* __restrict__ dst, int e, int nbk,
                           int* __restrict__ cnt, int* __restrict__ bucketCnt) {
    __shared__ int lh[512];
    int tid = threadIdx.x;
    for (int i = tid; i < nbk; i += blockDim.x) lh[i] = 0;
    __syncthreads();
    for (int i = blockIdx.x * blockDim.x + tid; i < e; i += gridDim.x * blockDim.x) {
        int d = dst[i];
        atomicAdd(&cnt[d], 1);
        atomicAdd(&lh[d >> 8], 1);
    }
    __syncthreads();
    for (int i = tid; i < nbk; i += blockDim.x)
        if (lh[i]) atomicAdd(&bucketCnt[i], lh[i]);
}

__global__ void k_scan_block(const int* __restrict__ cnt, int* __restrict__ rowptr,
                             int* __restrict__ bsum, int n) {
    __shared__ int sh[SCAN_B];
    int tid = threadIdx.x;
    int i = blockIdx.x * SCAN_B + tid;
    int v = (i < n) ? cnt[i] : 0;
    sh[tid] = v;
    __syncthreads();
    for (int off = 1; off < SCAN_B; off <<= 1) {
        int t = (tid >= off) ? sh[tid - off] : 0;
        __syncthreads();
        sh[tid] += t;
        __syncthreads();
    }
    if (i < n) rowptr[i] = sh[tid] - v;  // exclusive
    if (tid == SCAN_B - 1) bsum[blockIdx.x] = sh[tid];
}

__global__ void k_scan_bsums(int* __restrict__ bsum, int nb) {
    __shared__ int sh[512];
    int tid = threadIdx.x;
    if (nb <= 512) {
        int v = (tid < nb) ? bsum[tid] : 0;
        sh[tid] = v;
        __syncthreads();
        for (int off = 1; off < 512; off <<= 1) {
            int t = (tid >= off) ? sh[tid - off] : 0;
            __syncthreads();
            sh[tid] += t;
            __syncthreads();
        }
        if (tid < nb) bsum[tid] = sh[tid] - v;
    } else if (tid == 0) {
        int run = 0;
        for (int i = 0; i < nb; ++i) { int t = bsum[i]; bsum[i] = run; run += t; }
    }
}

__global__ void k_scan_add_prep(int* __restrict__ rowptr, const int* __restrict__ bsum,
                                const int* __restrict__ cnt, float* __restrict__ dinv, int n) {
    int i = blockIdx.x * blockDim.x + threadIdx.x;
    if (i >= n) return;
    rowptr[i] += bsum[i / SCAN_B];
    dinv[i] = rsqrtf((float)(cnt[i] + 1));
}

// ---------- binned CSR fill ----------
__global__ void kb_scan(const int* __restrict__ bucketCnt, int* __restrict__ bucketBase,
                        int* __restrict__ bucketCursor, int nbk) {
    __shared__ int sh[512];
    int tid = threadIdx.x;
    int v = (tid < nbk) ? bucketCnt[tid] : 0;
    sh[tid] = v;
    __syncthreads();
    for (int off = 1; off < 512; off <<= 1) {
        int t = (tid >= off) ? sh[tid - off] : 0;
        __syncthreads();
        sh[tid] += t;
        __syncthreads();
    }
    if (tid < nbk) {
        bucketBase[tid] = sh[tid] - v;
        bucketCursor[tid] = sh[tid] - v;
    }
    if (tid == nbk) bucketBase[tid] = sh[511];  // total = e
}

__global__ void kb_scatter(const int* __restrict__ src, const int* __restrict__ dst, int e,
                           int nbk, int* __restrict__ bucketCursor, uint2* __restrict__ staging) {
    __shared__ int lh[512];
    __shared__ int lbase[512];
    int tid = threadIdx.x;
    int c0 = blockIdx.x * SC_CHUNK;
    int c1 = min(c0 + SC_CHUNK, e);
    for (int i = tid; i < nbk; i += blockDim.x) lh[i] = 0;
    __syncthreads();
    for (int i = c0 + tid; i < c1; i += blockDim.x)
        atomicAdd(&lh[dst[i] >> 8], 1);
    __syncthreads();
    for (int i = tid; i < nbk; i += blockDim.x) {
        int c = lh[i];
        lbase[i] = c ? atomicAdd(&bucketCursor[i], c) : 0;
        lh[i] = 0;  // becomes local cursor
    }
    __syncthreads();
    for (int i = c0 + tid; i < c1; i += blockDim.x) {
        int d = dst[i];
        int b = d >> 8;
        int r = atomicAdd(&lh[b], 1);
        staging[lbase[b] + r] = make_uint2((unsigned)src[i], (unsigned)d);
    }
}

__global__ void kb_fill2(const uint2* __restrict__ staging, const int* __restrict__ bucketBase,
                         const int* __restrict__ rowptr, int* __restrict__ col, int n) {
    __shared__ int cur[BK];
    int b = blockIdx.x;
    int tid = threadIdx.x;
    int v = b * BK + tid;
    cur[tid] = (v < n) ? rowptr[v] : 0;
    __syncthreads();
    int beg = bucketBase[b], end = bucketBase[b + 1];
    for (int i = beg + tid; i < end; i += blockDim.x) {
        uint2 sd = staging[i];
        int pos = atomicAdd(&cur[sd.y & (BK - 1)], 1);
        col[pos] = (int)sd.x;
    }
}

// xs = fp16(dinv .* x): thread handles 4 floats -> one 8B h4 store
__global__ void k_prescale(const float* __restrict__ x, const float* __restrict__ dinv,
                           h4* __restrict__ xs, int n) {
    int i = blockIdx.x * blockDim.x + threadIdx.x;
    if (i >= n * (F_IN / 4)) return;
    int v = i >> 4;
    float s = dinv[v];
    float4 val = ((const float4*)x)[i];
    h4 o;
    o.a = __floats2half2_rn(val.x * s, val.y * s);
    o.b = __floats2half2_rn(val.z * s, val.w * s);
    xs[i] = o;
}

// ---------- gather 1 (F=64 fp16): wave per node, 16-lane quarters x 8B, unroll x4 ----
__global__ void k_gather1(const h4* __restrict__ xs, const int* __restrict__ rowptr,
                          const int* __restrict__ cnt, const int* __restrict__ col,
                          const float* __restrict__ dinv, float* __restrict__ ax, int n) {
    int tid = threadIdx.x;
    int w = tid >> 6, lane = tid & 63;
    int v = blockIdx.x * 4 + w;
    if (v >= n) return;  // wave-uniform
    int q = lane >> 4, l = lane & 15;
    int beg = rowptr[v], deg = cnt[v];
    float2 a0 = make_float2(0.f, 0.f), b0 = make_float2(0.f, 0.f);
    float2 a1 = make_float2(0.f, 0.f), b1 = make_float2(0.f, 0.f);
    float2 a2 = make_float2(0.f, 0.f), b2 = make_float2(0.f, 0.f);
    float2 a3 = make_float2(0.f, 0.f), b3 = make_float2(0.f, 0.f);
    int j = q;
    for (; j + 12 < deg; j += 16) {
        int s0 = col[beg + j];
        int s1 = col[beg + j + 4];
        int s2 = col[beg + j + 8];
        int s3 = col[beg + j + 12];
        h4 v0 = xs[(size_t)s0 * 16 + l];
        h4 v1 = xs[(size_t)s1 * 16 + l];
        h4 v2 = xs[(size_t)s2 * 16 + l];
        h4 v3 = xs[(size_t)s3 * 16 + l];
        float2 f;
        f = __half22float2(v0.a); a0.x += f.x; a0.y += f.y;
        f = __half22float2(v0.b); b0.x += f.x; b0.y += f.y;
        f = __half22float2(v1.a); a1.x += f.x; a1.y += f.y;
        f = __half22float2(v1.b); b1.x += f.x; b1.y += f.y;
        f = __half22float2(v2.a); a2.x += f.x; a2.y += f.y;
        f = __half22float2(v2.b); b2.x += f.x; b2.y += f.y;
        f = __half22float2(v3.a); a3.x += f.x; a3.y += f.y;
        f = __half22float2(v3.b); b3.x += f.x; b3.y += f.y;
    }
    for (; j < deg; j += 4) {
        h4 v0 = xs[(size_t)col[beg + j] * 16 + l];
        float2 f;
        f = __half22float2(v0.a); a0.x += f.x; a0.y += f.y;
        f = __half22float2(v0.b); b0.x += f.x; b0.y += f.y;
    }
    a0.x += a1.x + a2.x + a3.x;  a0.y += a1.y + a2.y + a3.y;
    b0.x += b1.x + b2.x + b3.x;  b0.y += b1.y + b2.y + b3.y;
    a0.x += __shfl_xor(a0.x, 16); a0.y += __shfl_xor(a0.y, 16);
    b0.x += __shfl_xor(b0.x, 16); b0.y += __shfl_xor(b0.y, 16);
    a0.x += __shfl_xor(a0.x, 32); a0.y += __shfl_xor(a0.y, 32);
    b0.x += __shfl_xor(b0.x, 32); b0.y += __shfl_xor(b0.y, 32);
    if (q == 0) {
        float dv = dinv[v];
        h4 sf = xs[(size_t)v * 16 + l];
        float2 s0 = __half22float2(sf.a), s1 = __half22float2(sf.b);
        float4 r;
        r.x = dv * (a0.x + s0.x);
        r.y = dv * (a0.y + s0.y);
        r.z = dv * (b0.x + s1.x);
        r.w = dv * (b0.y + s1.y);
        ((float4*)(ax + (size_t)v * F_IN))[l] = r;
    }
}

// ---------- tiled MLP: h2s = fp16(dinv .* (relu(ax@W1+b1) @ W2)) ----------
__global__ __launch_bounds__(256) void k_mlp(const float* __restrict__ ax,
                                             const float* __restrict__ W1,
                                             const float* __restrict__ b1,
                                             const float* __restrict__ W2,
                                             const float* __restrict__ dinv,
                                             __half2* __restrict__ h2s, int n) {
    __shared__ float smem[12800];
    float* W1s = smem;          // [64][128]
    float* axs = smem + 8192;   // [64][67] padded
    float* hsT = smem;          // [128][68] padded (phase B)
    float* W2s = smem + 8704;   // [128][32]

    int tid = threadIdx.x;
    int v0 = blockIdx.x * 64;
    int rg = tid >> 4;          // 0..15
    int cg = tid & 15;          // 0..15

    for (int t = tid; t < 2048; t += 256) {
        int k = t >> 5, c4 = (t & 31) * 4;
        *(float4*)&W1s[k * 128 + c4] = *(const float4*)&W1[k * 128 + c4];
    }
    for (int t = tid; t < 1024; t += 256) {
        int row = t >> 4, k4 = (t & 15) * 4;
        float4 val = make_float4(0.f, 0.f, 0.f, 0.f);
        if (v0 + row < n) val = *(const float4*)&ax[(size_t)(v0 + row) * F_IN + k4];
        axs[row * 67 + k4 + 0] = val.x;
        axs[row * 67 + k4 + 1] = val.y;
        axs[row * 67 + k4 + 2] = val.z;
        axs[row * 67 + k4 + 3] = val.w;
    }
    __syncthreads();

    float acc[4][8];
#pragma unroll
    for (int i = 0; i < 4; ++i)
#pragma unroll
        for (int j = 0; j < 8; ++j) acc[i][j] = 0.f;

#pragma unroll 4
    for (int k = 0; k < 64; ++k) {
        float a0 = axs[(rg * 4 + 0) * 67 + k];
        float a1 = axs[(rg * 4 + 1) * 67 + k];
        float a2 = axs[(rg * 4 + 2) * 67 + k];
        float a3 = axs[(rg * 4 + 3) * 67 + k];
        float4 w0 = *(float4*)&W1s[k * 128 + cg * 8];
        float4 w1 = *(float4*)&W1s[k * 128 + cg * 8 + 4];
        acc[0][0] = fmaf(a0, w0.x, acc[0][0]); acc[0][1] = fmaf(a0, w0.y, acc[0][1]);
        acc[0][2] = fmaf(a0, w0.z, acc[0][2]); acc[0][3] = fmaf(a0, w0.w, acc[0][3]);
        acc[0][4] = fmaf(a0, w1.x, acc[0][4]); acc[0][5] = fmaf(a0, w1.y, acc[0][5]);
        acc[0][6] = fmaf(a0, w1.z, acc[0][6]); acc[0][7] = fmaf(a0, w1.w, acc[0][7]);
        acc[1][0] = fmaf(a1, w0.x, acc[1][0]); acc[1][1] = fmaf(a1, w0.y, acc[1][1]);
        acc[1][2] = fmaf(a1, w0.z, acc[1][2]); acc[1][3] = fmaf(a1, w0.w, acc[1][3]);
        acc[1][4] = fmaf(a1, w1.x, acc[1][4]); acc[1][5] = fmaf(a1, w1.y, acc[1][5]);
        acc[1][6] = fmaf(a1, w1.z, acc[1][6]); acc[1][7] = fmaf(a1, w1.w, acc[1][7]);
        acc[2][0] = fmaf(a2, w0.x, acc[2][0]); acc[2][1] = fmaf(a2, w0.y, acc[2][1]);
        acc[2][2] = fmaf(a2, w0.z, acc[2][2]); acc[2][3] = fmaf(a2, w0.w, acc[2][3]);
        acc[2][4] = fmaf(a2, w1.x, acc[2][4]); acc[2][5] = fmaf(a2, w1.y, acc[2][5]);
        acc[2][6] = fmaf(a2, w1.z, acc[2][6]); acc[2][7] = fmaf(a2, w1.w, acc[2][7]);
        acc[3][0] = fmaf(a3, w0.x, acc[3][0]); acc[3][1] = fmaf(a3, w0.y, acc[3][1]);
        acc[3][2] = fmaf(a3, w0.z, acc[3][2]); acc[3][3] = fmaf(a3, w0.w, acc[3][3]);
        acc[3][4] = fmaf(a3, w1.x, acc[3][4]); acc[3][5] = fmaf(a3, w1.y, acc[3][5]);
        acc[3][6] = fmaf(a3, w1.z, acc[3][6]); acc[3][7] = fmaf(a3, w1.w, acc[3][7]);
    }
    __syncthreads();  // W1s/axs dead

    {
        float4 bb0 = *(const float4*)&b1[cg * 8];
        float4 bb1 = *(const float4*)&b1[cg * 8 + 4];
        float bias[8] = {bb0.x, bb0.y, bb0.z, bb0.w, bb1.x, bb1.y, bb1.z, bb1.w};
#pragma unroll
        for (int j = 0; j < 8; ++j) {
            float4 hv;
            hv.x = acc[0][j] + bias[j]; hv.x = hv.x > 0.f ? hv.x : 0.f;
            hv.y = acc[1][j] + bias[j]; hv.y = hv.y > 0.f ? hv.y : 0.f;
            hv.z = acc[2][j] + bias[j]; hv.z = hv.z > 0.f ? hv.z : 0.f;
            hv.w = acc[3][j] + bias[j]; hv.w = hv.w > 0.f ? hv.w : 0.f;
            *(float4*)&hsT[(cg * 8 + j) * 68 + rg * 4] = hv;
        }
    }
    for (int t = tid; t < 1024; t += 256) {
        int k = t >> 3, c4 = (t & 7) * 4;
        *(float4*)&W2s[k * 32 + c4] = *(const float4*)&W2[k * 32 + c4];
    }
    __syncthreads();

    float acc2[4][2] = {{0.f, 0.f}, {0.f, 0.f}, {0.f, 0.f}, {0.f, 0.f}};
#pragma unroll 8
    for (int k = 0; k < 128; ++k) {
        float4 hh = *(float4*)&hsT[k * 68 + rg * 4];
        float w0 = W2s[k * 32 + cg * 2];
        float w1 = W2s[k * 32 + cg * 2 + 1];
        acc2[0][0] = fmaf(hh.x, w0, acc2[0][0]); acc2[0][1] = fmaf(hh.x, w1, acc2[0][1]);
        acc2[1][0] = fmaf(hh.y, w0, acc2[1][0]); acc2[1][1] = fmaf(hh.y, w1, acc2[1][1]);
        acc2[2][0] = fmaf(hh.z, w0, acc2[2][0]); acc2[2][1] = fmaf(hh.z, w1, acc2[2][1]);
        acc2[3][0] = fmaf(hh.w, w0, acc2[3][0]); acc2[3][1] = fmaf(hh.w, w1, acc2[3][1]);
    }
#pragma unroll
    for (int i = 0; i < 4; ++i) {
        int v = v0 + rg * 4 + i;
        if (v < n) {
            float dv = dinv[v];
            h2s[(size_t)v * (CDIM / 2) + cg] = __floats2half2_rn(dv * acc2[i][0], dv * acc2[i][1]);
        }
    }
}

// ---------- gather 2 (C=32 fp16): wave per node, 8-lane groups x 8B, unroll x2 ----
__global__ void k_gather2(const h4* __restrict__ h2s, const int* __restrict__ rowptr,
                          const int* __restrict__ cnt, const int* __restrict__ col,
                          const float* __restrict__ dinv, const float* __restrict__ b2,
                          float* __restrict__ out, int n) {
    int tid = threadIdx.x;
    int w = tid >> 6, lane = tid & 63;
    int v = blockIdx.x * 4 + w;
    if (v >= n) return;  // wave-uniform
    int g = lane >> 3, l = lane & 7;
    int beg = rowptr[v], deg = cnt[v];
    float2 a0 = make_float2(0.f, 0.f), b0 = make_float2(0.f, 0.f);
    float2 a1 = make_float2(0.f, 0.f), b1 = make_float2(0.f, 0.f);
    int j = g;
    for (; j + 8 < deg; j += 16) {
        int s0 = col[beg + j];
        int s1 = col[beg + j + 8];
        h4 v0 = h2s[(size_t)s0 * 8 + l];
        h4 v1 = h2s[(size_t)s1 * 8 + l];
        float2 f;
        f = __half22float2(v0.a); a0.x += f.x; a0.y += f.y;
        f = __half22float2(v0.b); b0.x += f.x; b0.y += f.y;
        f = __half22float2(v1.a); a1.x += f.x; a1.y += f.y;
        f = __half22float2(v1.b); b1.x += f.x; b1.y += f.y;
    }
    if (j < deg) {
        h4 v0 = h2s[(size_t)col[beg + j] * 8 + l];
        float2 f;
        f = __half22float2(v0.a); a0.x += f.x; a0.y += f.y;
        f = __half22float2(v0.b); b0.x += f.x; b0.y += f.y;
    }
    a0.x += a1.x; a0.y += a1.y; b0.x += b1.x; b0.y += b1.y;
    a0.x += __shfl_xor(a0.x, 8);  a0.y += __shfl_xor(a0.y, 8);
    b0.x += __shfl_xor(b0.x, 8);  b0.y += __shfl_xor(b0.y, 8);
    a0.x += __shfl_xor(a0.x, 16); a0.y += __shfl_xor(a0.y, 16);
    b0.x += __shfl_xor(b0.x, 16); b0.y += __shfl_xor(b0.y, 16);
    a0.x += __shfl_xor(a0.x, 32); a0.y += __shfl_xor(a0.y, 32);
    b0.x += __shfl_xor(b0.x, 32); b0.y += __shfl_xor(b0.y, 32);
    if (g == 0) {
        float dv = dinv[v];
        h4 sf = h2s[(size_t)v * 8 + l];
        float2 s0 = __half22float2(sf.a), s1 = __half22float2(sf.b);
        float4 bb = ((const float4*)b2)[l];
        float4 o;
        o.x = dv * (a0.x + s0.x) + bb.x;
        o.y = dv * (a0.y + s0.y) + bb.y;
        o.z = dv * (b0.x + s1.x) + bb.z;
        o.w = dv * (b0.y + s1.y) + bb.w;
        ((float4*)(out + (size_t)v * CDIM))[l] = o;
    }
}

extern "C" void kernel_launch(void* const* d_in, const int* in_sizes, int n_in,
                              void* d_out, int out_size, void* d_ws, size_t ws_size,
                              hipStream_t stream) {
    const float* x  = (const float*)d_in[0];
    const int*   ei = (const int*)d_in[1];
    const float* W1 = (const float*)d_in[2];
    const float* b1 = (const float*)d_in[3];
    const float* W2 = (const float*)d_in[4];
    const float* b2 = (const float*)d_in[5];
    float* out = (float*)d_out;

    int n = in_sizes[0] / F_IN;
    int e = in_sizes[1] / 2;
    const int* srcIdx = ei;
    const int* dstIdx = ei + e;

    int nb = (n + SCAN_B - 1) / SCAN_B;
    int nbk = (n + BK - 1) / BK;  // 391 for n=100K (needs <= 511)

    // workspace layout (4B units):
    //   cnt[n] | bucketCnt[512] | bucketBase[520] | bucketCursor[512] |
    //   rowptr[n] | bsum[4096] | col[e] | dinv[n] | xs(h4, n*16 u64 = n*32 u32) |
    //   ax[64n] | h2s(half, 32n = 16n u32)
    //   staging(uint2 e) overlays ax (dead until gather1)
    int* cnt          = (int*)d_ws;
    int* bucketCnt    = cnt + n;
    int* bucketBase   = bucketCnt + 512;
    int* bucketCursor = bucketBase + 520;
    int* rowptr       = bucketCursor + 512;
    int* bsum         = rowptr + n;
    int* col          = bsum + 4096;
    float* dinv       = (float*)(col + e);
    h4* xs            = (h4*)(dinv + n);                  // n*16 h4
    float* ax         = (float*)(xs + (size_t)n * 16);    // n*64 f32
    __half2* h2s      = (__half2*)(ax + (size_t)n * F_IN);// n*16 half2
    uint2* staging    = (uint2*)ax;

    const int B = 256;

    hipMemsetAsync(cnt, 0, ((size_t)n + 512) * sizeof(int), stream);

    // degree + bucket histogram (fused, one dst pass) -> scans -> dinv
    k_histboth<<<256, B, 0, stream>>>(dstIdx, e, nbk, cnt, bucketCnt);
    k_scan_block<<<nb, SCAN_B, 0, stream>>>(cnt, rowptr, bsum, n);
    k_scan_bsums<<<1, 512, 0, stream>>>(bsum, nb);
    k_scan_add_prep<<<(n + B - 1) / B, B, 0, stream>>>(rowptr, bsum, cnt, dinv, n);
    kb_scan<<<1, 512, 0, stream>>>(bucketCnt, bucketBase, bucketCursor, nbk);
    kb_scatter<<<(e + SC_CHUNK - 1) / SC_CHUNK, B, 0, stream>>>(srcIdx, dstIdx, e, nbk,
                                                                bucketCursor, staging);
    kb_fill2<<<nbk, BK, 0, stream>>>(staging, bucketBase, rowptr, col, n);

    // layer 1
    k_prescale<<<(n * (F_IN / 4) + B - 1) / B, B, 0, stream>>>(x, dinv, xs, n);
    k_gather1<<<(n + 3) / 4, B, 0, stream>>>(xs, rowptr, cnt, col, dinv, ax, n);
    k_mlp<<<(n + 63) / 64, B, 0, stream>>>(ax, W1, b1, W2, dinv, h2s, n);
    k_gather2<<<(n + 3) / 4, B, 0, stream>>>((const h4*)h2s, rowptr, cnt, col, dinv, b2, out, n);
}

// Round 8
// 229.409 us; speedup vs baseline: 1.8247x; 1.2291x over previous
//
#include <hip/hip_runtime.h>
#include <hip/hip_fp16.h>

// GCN 2-layer forward, round 8:
//   R7, but degree-count no longer uses global atomics (R7's k_histboth was
//   latency-bound at 1 WG/CU). Degree derived from the binned staging buffer:
//     kb_hist -> kb_scan -> kb_scatter -> kb_count(LDS hist per bucket)
//     -> node scan -> kb_fill2 (counting sort)
//   ax[v]  = dinv[v]*(sum xs[s] + xs[v]),  xs = fp16(dinv.*x)
//   h2s    = fp16(dinv .* (relu(ax@W1+b1) @ W2))
//   out[v] = dinv[v]*(sum h2s[s] + h2s[v]) + b2

#define F_IN 64
#define HDIM 128
#define CDIM 32
#define SCAN_B 256
#define BK 256          // nodes per bucket (== kb_fill2/kb_count blockDim)
#define SC_CHUNK 4096   // edges per kb_scatter workgroup

struct h4 { __half2 a, b; };  // 8-byte packed 4x fp16

// ---------- bucket histogram (LDS only; 256 wgs) ----------
__global__ void kb_hist(const int* __restrict__ dst, int e, int nbk,
                        int* __restrict__ bucketCnt) {
    __shared__ int lh[512];
    int tid = threadIdx.x;
    for (int i = tid; i < nbk; i += blockDim.x) lh[i] = 0;
    __syncthreads();
    for (int i = blockIdx.x * blockDim.x + tid; i < e; i += gridDim.x * blockDim.x)
        atomicAdd(&lh[dst[i] >> 8], 1);
    __syncthreads();
    for (int i = tid; i < nbk; i += blockDim.x)
        if (lh[i]) atomicAdd(&bucketCnt[i], lh[i]);
}

// exclusive scan of bucketCnt -> bucketBase (+total at [nbk]); cursor copy
__global__ void kb_scan(const int* __restrict__ bucketCnt, int* __restrict__ bucketBase,
                        int* __restrict__ bucketCursor, int nbk) {
    __shared__ int sh[512];
    int tid = threadIdx.x;
    int v = (tid < nbk) ? bucketCnt[tid] : 0;
    sh[tid] = v;
    __syncthreads();
    for (int off = 1; off < 512; off <<= 1) {
        int t = (tid >= off) ? sh[tid - off] : 0;
        __syncthreads();
        sh[tid] += t;
        __syncthreads();
    }
    if (tid < nbk) {
        bucketBase[tid] = sh[tid] - v;
        bucketCursor[tid] = sh[tid] - v;
    }
    if (tid == nbk) bucketBase[tid] = sh[511];  // total = e
}

// per-wg LDS histogram -> contiguous run reservation -> coalesced staging writes
__global__ void kb_scatter(const int* __restrict__ src, const int* __restrict__ dst, int e,
                           int nbk, int* __restrict__ bucketCursor, uint2* __restrict__ staging) {
    __shared__ int lh[512];
    __shared__ int lbase[512];
    int tid = threadIdx.x;
    int c0 = blockIdx.x * SC_CHUNK;
    int c1 = min(c0 + SC_CHUNK, e);
    for (int i = tid; i < nbk; i += blockDim.x) lh[i] = 0;
    __syncthreads();
    for (int i = c0 + tid; i < c1; i += blockDim.x)
        atomicAdd(&lh[dst[i] >> 8], 1);
    __syncthreads();
    for (int i = tid; i < nbk; i += blockDim.x) {
        int c = lh[i];
        lbase[i] = c ? atomicAdd(&bucketCursor[i], c) : 0;
        lh[i] = 0;  // becomes local cursor
    }
    __syncthreads();
    for (int i = c0 + tid; i < c1; i += blockDim.x) {
        int d = dst[i];
        int b = d >> 8;
        int r = atomicAdd(&lh[b], 1);
        staging[lbase[b] + r] = make_uint2((unsigned)src[i], (unsigned)d);
    }
}

// per-node degree from binned staging: one wg per bucket, LDS-only atomics
__global__ void kb_count(const uint2* __restrict__ staging, const int* __restrict__ bucketBase,
                         int* __restrict__ cnt, int n) {
    __shared__ int lc[BK];
    int b = blockIdx.x;
    int tid = threadIdx.x;
    lc[tid] = 0;
    __syncthreads();
    int beg = bucketBase[b], end = bucketBase[b + 1];
    for (int i = beg + tid; i < end; i += blockDim.x)
        atomicAdd(&lc[staging[i].y & (BK - 1)], 1);
    __syncthreads();
    int v = b * BK + tid;
    if (v < n) cnt[v] = lc[tid];
}

// ---------- node-degree scan -> rowptr, dinv ----------
__global__ void k_scan_block(const int* __restrict__ cnt, int* __restrict__ rowptr,
                             int* __restrict__ bsum, int n) {
    __shared__ int sh[SCAN_B];
    int tid = threadIdx.x;
    int i = blockIdx.x * SCAN_B + tid;
    int v = (i < n) ? cnt[i] : 0;
    sh[tid] = v;
    __syncthreads();
    for (int off = 1; off < SCAN_B; off <<= 1) {
        int t = (tid >= off) ? sh[tid - off] : 0;
        __syncthreads();
        sh[tid] += t;
        __syncthreads();
    }
    if (i < n) rowptr[i] = sh[tid] - v;  // exclusive
    if (tid == SCAN_B - 1) bsum[blockIdx.x] = sh[tid];
}

__global__ void k_scan_bsums(int* __restrict__ bsum, int nb) {
    __shared__ int sh[512];
    int tid = threadIdx.x;
    if (nb <= 512) {
        int v = (tid < nb) ? bsum[tid] : 0;
        sh[tid] = v;
        __syncthreads();
        for (int off = 1; off < 512; off <<= 1) {
            int t = (tid >= off) ? sh[tid - off] : 0;
            __syncthreads();
            sh[tid] += t;
            __syncthreads();
        }
        if (tid < nb) bsum[tid] = sh[tid] - v;
    } else if (tid == 0) {
        int run = 0;
        for (int i = 0; i < nb; ++i) { int t = bsum[i]; bsum[i] = run; run += t; }
    }
}

__global__ void k_scan_add_prep(int* __restrict__ rowptr, const int* __restrict__ bsum,
                                const int* __restrict__ cnt, float* __restrict__ dinv, int n) {
    int i = blockIdx.x * blockDim.x + threadIdx.x;
    if (i >= n) return;
    rowptr[i] += bsum[i / SCAN_B];
    dinv[i] = rsqrtf((float)(cnt[i] + 1));
}

// counting-sort staged edges into col (L2-local window per bucket)
__global__ void kb_fill2(const uint2* __restrict__ staging, const int* __restrict__ bucketBase,
                         const int* __restrict__ rowptr, int* __restrict__ col, int n) {
    __shared__ int cur[BK];
    int b = blockIdx.x;
    int tid = threadIdx.x;
    int v = b * BK + tid;
    cur[tid] = (v < n) ? rowptr[v] : 0;
    __syncthreads();
    int beg = bucketBase[b], end = bucketBase[b + 1];
    for (int i = beg + tid; i < end; i += blockDim.x) {
        uint2 sd = staging[i];
        int pos = atomicAdd(&cur[sd.y & (BK - 1)], 1);
        col[pos] = (int)sd.x;
    }
}

// xs = fp16(dinv .* x)
__global__ void k_prescale(const float* __restrict__ x, const float* __restrict__ dinv,
                           h4* __restrict__ xs, int n) {
    int i = blockIdx.x * blockDim.x + threadIdx.x;
    if (i >= n * (F_IN / 4)) return;
    int v = i >> 4;
    float s = dinv[v];
    float4 val = ((const float4*)x)[i];
    h4 o;
    o.a = __floats2half2_rn(val.x * s, val.y * s);
    o.b = __floats2half2_rn(val.z * s, val.w * s);
    xs[i] = o;
}

// ---------- gather 1 (F=64 fp16): wave per node, 16-lane quarters x 8B, unroll x4 ----
__global__ void k_gather1(const h4* __restrict__ xs, const int* __restrict__ rowptr,
                          const int* __restrict__ cnt, const int* __restrict__ col,
                          const float* __restrict__ dinv, float* __restrict__ ax, int n) {
    int tid = threadIdx.x;
    int w = tid >> 6, lane = tid & 63;
    int v = blockIdx.x * 4 + w;
    if (v >= n) return;  // wave-uniform
    int q = lane >> 4, l = lane & 15;
    int beg = rowptr[v], deg = cnt[v];
    float2 a0 = make_float2(0.f, 0.f), b0 = make_float2(0.f, 0.f);
    float2 a1 = make_float2(0.f, 0.f), b1 = make_float2(0.f, 0.f);
    float2 a2 = make_float2(0.f, 0.f), b2 = make_float2(0.f, 0.f);
    float2 a3 = make_float2(0.f, 0.f), b3 = make_float2(0.f, 0.f);
    int j = q;
    for (; j + 12 < deg; j += 16) {
        int s0 = col[beg + j];
        int s1 = col[beg + j + 4];
        int s2 = col[beg + j + 8];
        int s3 = col[beg + j + 12];
        h4 v0 = xs[(size_t)s0 * 16 + l];
        h4 v1 = xs[(size_t)s1 * 16 + l];
        h4 v2 = xs[(size_t)s2 * 16 + l];
        h4 v3 = xs[(size_t)s3 * 16 + l];
        float2 f;
        f = __half22float2(v0.a); a0.x += f.x; a0.y += f.y;
        f = __half22float2(v0.b); b0.x += f.x; b0.y += f.y;
        f = __half22float2(v1.a); a1.x += f.x; a1.y += f.y;
        f = __half22float2(v1.b); b1.x += f.x; b1.y += f.y;
        f = __half22float2(v2.a); a2.x += f.x; a2.y += f.y;
        f = __half22float2(v2.b); b2.x += f.x; b2.y += f.y;
        f = __half22float2(v3.a); a3.x += f.x; a3.y += f.y;
        f = __half22float2(v3.b); b3.x += f.x; b3.y += f.y;
    }
    for (; j < deg; j += 4) {
        h4 v0 = xs[(size_t)col[beg + j] * 16 + l];
        float2 f;
        f = __half22float2(v0.a); a0.x += f.x; a0.y += f.y;
        f = __half22float2(v0.b); b0.x += f.x; b0.y += f.y;
    }
    a0.x += a1.x + a2.x + a3.x;  a0.y += a1.y + a2.y + a3.y;
    b0.x += b1.x + b2.x + b3.x;  b0.y += b1.y + b2.y + b3.y;
    a0.x += __shfl_xor(a0.x, 16); a0.y += __shfl_xor(a0.y, 16);
    b0.x += __shfl_xor(b0.x, 16); b0.y += __shfl_xor(b0.y, 16);
    a0.x += __shfl_xor(a0.x, 32); a0.y += __shfl_xor(a0.y, 32);
    b0.x += __shfl_xor(b0.x, 32); b0.y += __shfl_xor(b0.y, 32);
    if (q == 0) {
        float dv = dinv[v];
        h4 sf = xs[(size_t)v * 16 + l];
        float2 s0 = __half22float2(sf.a), s1 = __half22float2(sf.b);
        float4 r;
        r.x = dv * (a0.x + s0.x);
        r.y = dv * (a0.y + s0.y);
        r.z = dv * (b0.x + s1.x);
        r.w = dv * (b0.y + s1.y);
        ((float4*)(ax + (size_t)v * F_IN))[l] = r;
    }
}

// ---------- tiled MLP: h2s = fp16(dinv .* (relu(ax@W1+b1) @ W2)) ----------
__global__ __launch_bounds__(256) void k_mlp(const float* __restrict__ ax,
                                             const float* __restrict__ W1,
                                             const float* __restrict__ b1,
                                             const float* __restrict__ W2,
                                             const float* __restrict__ dinv,
                                             __half2* __restrict__ h2s, int n) {
    __shared__ float smem[12800];
    float* W1s = smem;          // [64][128]
    float* axs = smem + 8192;   // [64][67] padded
    float* hsT = smem;          // [128][68] padded (phase B)
    float* W2s = smem + 8704;   // [128][32]

    int tid = threadIdx.x;
    int v0 = blockIdx.x * 64;
    int rg = tid >> 4;          // 0..15
    int cg = tid & 15;          // 0..15

    for (int t = tid; t < 2048; t += 256) {
        int k = t >> 5, c4 = (t & 31) * 4;
        *(float4*)&W1s[k * 128 + c4] = *(const float4*)&W1[k * 128 + c4];
    }
    for (int t = tid; t < 1024; t += 256) {
        int row = t >> 4, k4 = (t & 15) * 4;
        float4 val = make_float4(0.f, 0.f, 0.f, 0.f);
        if (v0 + row < n) val = *(const float4*)&ax[(size_t)(v0 + row) * F_IN + k4];
        axs[row * 67 + k4 + 0] = val.x;
        axs[row * 67 + k4 + 1] = val.y;
        axs[row * 67 + k4 + 2] = val.z;
        axs[row * 67 + k4 + 3] = val.w;
    }
    __syncthreads();

    float acc[4][8];
#pragma unroll
    for (int i = 0; i < 4; ++i)
#pragma unroll
        for (int j = 0; j < 8; ++j) acc[i][j] = 0.f;

#pragma unroll 4
    for (int k = 0; k < 64; ++k) {
        float a0 = axs[(rg * 4 + 0) * 67 + k];
        float a1 = axs[(rg * 4 + 1) * 67 + k];
        float a2 = axs[(rg * 4 + 2) * 67 + k];
        float a3 = axs[(rg * 4 + 3) * 67 + k];
        float4 w0 = *(float4*)&W1s[k * 128 + cg * 8];
        float4 w1 = *(float4*)&W1s[k * 128 + cg * 8 + 4];
        acc[0][0] = fmaf(a0, w0.x, acc[0][0]); acc[0][1] = fmaf(a0, w0.y, acc[0][1]);
        acc[0][2] = fmaf(a0, w0.z, acc[0][2]); acc[0][3] = fmaf(a0, w0.w, acc[0][3]);
        acc[0][4] = fmaf(a0, w1.x, acc[0][4]); acc[0][5] = fmaf(a0, w1.y, acc[0][5]);
        acc[0][6] = fmaf(a0, w1.z, acc[0][6]); acc[0][7] = fmaf(a0, w1.w, acc[0][7]);
        acc[1][0] = fmaf(a1, w0.x, acc[1][0]); acc[1][1] = fmaf(a1, w0.y, acc[1][1]);
        acc[1][2] = fmaf(a1, w0.z, acc[1][2]); acc[1][3] = fmaf(a1, w0.w, acc[1][3]);
        acc[1][4] = fmaf(a1, w1.x, acc[1][4]); acc[1][5] = fmaf(a1, w1.y, acc[1][5]);
        acc[1][6] = fmaf(a1, w1.z, acc[1][6]); acc[1][7] = fmaf(a1, w1.w, acc[1][7]);
        acc[2][0] = fmaf(a2, w0.x, acc[2][0]); acc[2][1] = fmaf(a2, w0.y, acc[2][1]);
        acc[2][2] = fmaf(a2, w0.z, acc[2][2]); acc[2][3] = fmaf(a2, w0.w, acc[2][3]);
        acc[2][4] = fmaf(a2, w1.x, acc[2][4]); acc[2][5] = fmaf(a2, w1.y, acc[2][5]);
        acc[2][6] = fmaf(a2, w1.z, acc[2][6]); acc[2][7] = fmaf(a2, w1.w, acc[2][7]);
        acc[3][0] = fmaf(a3, w0.x, acc[3][0]); acc[3][1] = fmaf(a3, w0.y, acc[3][1]);
        acc[3][2] = fmaf(a3, w0.z, acc[3][2]); acc[3][3] = fmaf(a3, w0.w, acc[3][3]);
        acc[3][4] = fmaf(a3, w1.x, acc[3][4]); acc[3][5] = fmaf(a3, w1.y, acc[3][5]);
        acc[3][6] = fmaf(a3, w1.z, acc[3][6]); acc[3][7] = fmaf(a3, w1.w, acc[3][7]);
    }
    __syncthreads();  // W1s/axs dead

    {
        float4 bb0 = *(const float4*)&b1[cg * 8];
        float4 bb1 = *(const float4*)&b1[cg * 8 + 4];
        float bias[8] = {bb0.x, bb0.y, bb0.z, bb0.w, bb1.x, bb1.y, bb1.z, bb1.w};
#pragma unroll
        for (int j = 0; j < 8; ++j) {
            float4 hv;
            hv.x = acc[0][j] + bias[j]; hv.x = hv.x > 0.f ? hv.x : 0.f;
            hv.y = acc[1][j] + bias[j]; hv.y = hv.y > 0.f ? hv.y : 0.f;
            hv.z = acc[2][j] + bias[j]; hv.z = hv.z > 0.f ? hv.z : 0.f;
            hv.w = acc[3][j] + bias[j]; hv.w = hv.w > 0.f ? hv.w : 0.f;
            *(float4*)&hsT[(cg * 8 + j) * 68 + rg * 4] = hv;
        }
    }
    for (int t = tid; t < 1024; t += 256) {
        int k = t >> 3, c4 = (t & 7) * 4;
        *(float4*)&W2s[k * 32 + c4] = *(const float4*)&W2[k * 32 + c4];
    }
    __syncthreads();

    float acc2[4][2] = {{0.f, 0.f}, {0.f, 0.f}, {0.f, 0.f}, {0.f, 0.f}};
#pragma unroll 8
    for (int k = 0; k < 128; ++k) {
        float4 hh = *(float4*)&hsT[k * 68 + rg * 4];
        float w0 = W2s[k * 32 + cg * 2];
        float w1 = W2s[k * 32 + cg * 2 + 1];
        acc2[0][0] = fmaf(hh.x, w0, acc2[0][0]); acc2[0][1] = fmaf(hh.x, w1, acc2[0][1]);
        acc2[1][0] = fmaf(hh.y, w0, acc2[1][0]); acc2[1][1] = fmaf(hh.y, w1, acc2[1][1]);
        acc2[2][0] = fmaf(hh.z, w0, acc2[2][0]); acc2[2][1] = fmaf(hh.z, w1, acc2[2][1]);
        acc2[3][0] = fmaf(hh.w, w0, acc2[3][0]); acc2[3][1] = fmaf(hh.w, w1, acc2[3][1]);
    }
#pragma unroll
    for (int i = 0; i < 4; ++i) {
        int v = v0 + rg * 4 + i;
        if (v < n) {
            float dv = dinv[v];
            h2s[(size_t)v * (CDIM / 2) + cg] = __floats2half2_rn(dv * acc2[i][0], dv * acc2[i][1]);
        }
    }
}

// ---------- gather 2 (C=32 fp16): wave per node, 8-lane groups x 8B, unroll x2 ----
__global__ void k_gather2(const h4* __restrict__ h2s, const int* __restrict__ rowptr,
                          const int* __restrict__ cnt, const int* __restrict__ col,
                          const float* __restrict__ dinv, const float* __restrict__ b2,
                          float* __restrict__ out, int n) {
    int tid = threadIdx.x;
    int w = tid >> 6, lane = tid & 63;
    int v = blockIdx.x * 4 + w;
    if (v >= n) return;  // wave-uniform
    int g = lane >> 3, l = lane & 7;
    int beg = rowptr[v], deg = cnt[v];
    float2 a0 = make_float2(0.f, 0.f), b0 = make_float2(0.f, 0.f);
    float2 a1 = make_float2(0.f, 0.f), b1 = make_float2(0.f, 0.f);
    int j = g;
    for (; j + 8 < deg; j += 16) {
        int s0 = col[beg + j];
        int s1 = col[beg + j + 8];
        h4 v0 = h2s[(size_t)s0 * 8 + l];
        h4 v1 = h2s[(size_t)s1 * 8 + l];
        float2 f;
        f = __half22float2(v0.a); a0.x += f.x; a0.y += f.y;
        f = __half22float2(v0.b); b0.x += f.x; b0.y += f.y;
        f = __half22float2(v1.a); a1.x += f.x; a1.y += f.y;
        f = __half22float2(v1.b); b1.x += f.x; b1.y += f.y;
    }
    if (j < deg) {
        h4 v0 = h2s[(size_t)col[beg + j] * 8 + l];
        float2 f;
        f = __half22float2(v0.a); a0.x += f.x; a0.y += f.y;
        f = __half22float2(v0.b); b0.x += f.x; b0.y += f.y;
    }
    a0.x += a1.x; a0.y += a1.y; b0.x += b1.x; b0.y += b1.y;
    a0.x += __shfl_xor(a0.x, 8);  a0.y += __shfl_xor(a0.y, 8);
    b0.x += __shfl_xor(b0.x, 8);  b0.y += __shfl_xor(b0.y, 8);
    a0.x += __shfl_xor(a0.x, 16); a0.y += __shfl_xor(a0.y, 16);
    b0.x += __shfl_xor(b0.x, 16); b0.y += __shfl_xor(b0.y, 16);
    a0.x += __shfl_xor(a0.x, 32); a0.y += __shfl_xor(a0.y, 32);
    b0.x += __shfl_xor(b0.x, 32); b0.y += __shfl_xor(b0.y, 32);
    if (g == 0) {
        float dv = dinv[v];
        h4 sf = h2s[(size_t)v * 8 + l];
        float2 s0 = __half22float2(sf.a), s1 = __half22float2(sf.b);
        float4 bb = ((const float4*)b2)[l];
        float4 o;
        o.x = dv * (a0.x + s0.x) + bb.x;
        o.y = dv * (a0.y + s0.y) + bb.y;
        o.z = dv * (b0.x + s1.x) + bb.z;
        o.w = dv * (b0.y + s1.y) + bb.w;
        ((float4*)(out + (size_t)v * CDIM))[l] = o;
    }
}

extern "C" void kernel_launch(void* const* d_in, const int* in_sizes, int n_in,
                              void* d_out, int out_size, void* d_ws, size_t ws_size,
                              hipStream_t stream) {
    const float* x  = (const float*)d_in[0];
    const int*   ei = (const int*)d_in[1];
    const float* W1 = (const float*)d_in[2];
    const float* b1 = (const float*)d_in[3];
    const float* W2 = (const float*)d_in[4];
    const float* b2 = (const float*)d_in[5];
    float* out = (float*)d_out;

    int n = in_sizes[0] / F_IN;
    int e = in_sizes[1] / 2;
    const int* srcIdx = ei;
    const int* dstIdx = ei + e;

    int nb = (n + SCAN_B - 1) / SCAN_B;
    int nbk = (n + BK - 1) / BK;  // 391 for n=100K (needs <= 511)

    // workspace layout (4B units):
    //   cnt[n] | bucketCnt[512] | bucketBase[520] | bucketCursor[512] |
    //   rowptr[n] | bsum[4096] | col[e] | dinv[n] | xs(h4, n*16) |
    //   ax[64n] | h2s(half2, n*16)
    //   staging(uint2 e) overlays ax (dead until gather1)
    int* cnt          = (int*)d_ws;
    int* bucketCnt    = cnt + n;
    int* bucketBase   = bucketCnt + 512;
    int* bucketCursor = bucketBase + 520;
    int* rowptr       = bucketCursor + 512;
    int* bsum         = rowptr + n;
    int* col          = bsum + 4096;
    float* dinv       = (float*)(col + e);
    h4* xs            = (h4*)(dinv + n);                   // n*16 h4
    float* ax         = (float*)(xs + (size_t)n * 16);     // n*64 f32
    __half2* h2s      = (__half2*)(ax + (size_t)n * F_IN); // n*16 half2
    uint2* staging    = (uint2*)ax;

    const int B = 256;

    hipMemsetAsync(bucketCnt, 0, 512 * sizeof(int), stream);

    // binned edge sort; degree derived from bins (no global atomics)
    kb_hist<<<256, B, 0, stream>>>(dstIdx, e, nbk, bucketCnt);
    kb_scan<<<1, 512, 0, stream>>>(bucketCnt, bucketBase, bucketCursor, nbk);
    kb_scatter<<<(e + SC_CHUNK - 1) / SC_CHUNK, B, 0, stream>>>(srcIdx, dstIdx, e, nbk,
                                                                bucketCursor, staging);
    kb_count<<<nbk, BK, 0, stream>>>(staging, bucketBase, cnt, n);
    k_scan_block<<<nb, SCAN_B, 0, stream>>>(cnt, rowptr, bsum, n);
    k_scan_bsums<<<1, 512, 0, stream>>>(bsum, nb);
    k_scan_add_prep<<<(n + B - 1) / B, B, 0, stream>>>(rowptr, bsum, cnt, dinv, n);
    kb_fill2<<<nbk, BK, 0, stream>>>(staging, bucketBase, rowptr, col, n);

    // layer 1
    k_prescale<<<(n * (F_IN / 4) + B - 1) / B, B, 0, stream>>>(x, dinv, xs, n);
    k_gather1<<<(n + 3) / 4, B, 0, stream>>>(xs, rowptr, cnt, col, dinv, ax, n);
    k_mlp<<<(n + 63) / 64, B, 0, stream>>>(ax, W1, b1, W2, dinv, h2s, n);
    k_gather2<<<(n + 3) / 4, B, 0, stream>>>((const h4*)h2s, rowptr, cnt, col, dinv, b2, out, n);
}

// Round 9
// 205.324 us; speedup vs baseline: 2.0387x; 1.1173x over previous
//
#include <hip/hip_runtime.h>
#include <hip/hip_fp16.h>

// GCN 2-layer forward, round 9:
//   R8 + MFMA MLP: k_mlp (59us VALU matmul, 6.2M LDS bank conflicts) replaced by
//   mfma_f32_16x16x32_f16 kernel. gather1 now emits fp16 ax; W1/W2 pre-transposed
//   to fp16 (k_wconv) so all MFMA fragments are contiguous 16B loads.
//   ax[v]  = dinv[v]*(sum xs[s] + xs[v]),  xs = fp16(dinv.*x)
//   h2s    = fp16(dinv .* (relu(ax@W1+b1) @ W2))
//   out[v] = dinv[v]*(sum h2s[s] + h2s[v]) + b2

#define F_IN 64
#define HDIM 128
#define CDIM 32
#define SCAN_B 256
#define BK 256          // nodes per bucket (== kb_fill2/kb_count blockDim)
#define SC_CHUNK 4096   // edges per kb_scatter workgroup

struct h4 { __half2 a, b; };  // 8-byte packed 4x fp16

typedef _Float16 half8 __attribute__((ext_vector_type(8)));
typedef float f32x4 __attribute__((ext_vector_type(4)));

// ---------- bucket histogram (LDS only; 256 wgs) ----------
__global__ void kb_hist(const int* __restrict__ dst, int e, int nbk,
                        int* __restrict__ bucketCnt) {
    __shared__ int lh[512];
    int tid = threadIdx.x;
    for (int i = tid; i < nbk; i += blockDim.x) lh[i] = 0;
    __syncthreads();
    for (int i = blockIdx.x * blockDim.x + tid; i < e; i += gridDim.x * blockDim.x)
        atomicAdd(&lh[dst[i] >> 8], 1);
    __syncthreads();
    for (int i = tid; i < nbk; i += blockDim.x)
        if (lh[i]) atomicAdd(&bucketCnt[i], lh[i]);
}

__global__ void kb_scan(const int* __restrict__ bucketCnt, int* __restrict__ bucketBase,
                        int* __restrict__ bucketCursor, int nbk) {
    __shared__ int sh[512];
    int tid = threadIdx.x;
    int v = (tid < nbk) ? bucketCnt[tid] : 0;
    sh[tid] = v;
    __syncthreads();
    for (int off = 1; off < 512; off <<= 1) {
        int t = (tid >= off) ? sh[tid - off] : 0;
        __syncthreads();
        sh[tid] += t;
        __syncthreads();
    }
    if (tid < nbk) {
        bucketBase[tid] = sh[tid] - v;
        bucketCursor[tid] = sh[tid] - v;
    }
    if (tid == nbk) bucketBase[tid] = sh[511];  // total = e
}

__global__ void kb_scatter(const int* __restrict__ src, const int* __restrict__ dst, int e,
                           int nbk, int* __restrict__ bucketCursor, uint2* __restrict__ staging) {
    __shared__ int lh[512];
    __shared__ int lbase[512];
    int tid = threadIdx.x;
    int c0 = blockIdx.x * SC_CHUNK;
    int c1 = min(c0 + SC_CHUNK, e);
    for (int i = tid; i < nbk; i += blockDim.x) lh[i] = 0;
    __syncthreads();
    for (int i = c0 + tid; i < c1; i += blockDim.x)
        atomicAdd(&lh[dst[i] >> 8], 1);
    __syncthreads();
    for (int i = tid; i < nbk; i += blockDim.x) {
        int c = lh[i];
        lbase[i] = c ? atomicAdd(&bucketCursor[i], c) : 0;
        lh[i] = 0;  // becomes local cursor
    }
    __syncthreads();
    for (int i = c0 + tid; i < c1; i += blockDim.x) {
        int d = dst[i];
        int b = d >> 8;
        int r = atomicAdd(&lh[b], 1);
        staging[lbase[b] + r] = make_uint2((unsigned)src[i], (unsigned)d);
    }
}

__global__ void kb_count(const uint2* __restrict__ staging, const int* __restrict__ bucketBase,
                         int* __restrict__ cnt, int n) {
    __shared__ int lc[BK];
    int b = blockIdx.x;
    int tid = threadIdx.x;
    lc[tid] = 0;
    __syncthreads();
    int beg = bucketBase[b], end = bucketBase[b + 1];
    for (int i = beg + tid; i < end; i += blockDim.x)
        atomicAdd(&lc[staging[i].y & (BK - 1)], 1);
    __syncthreads();
    int v = b * BK + tid;
    if (v < n) cnt[v] = lc[tid];
}

__global__ void k_scan_block(const int* __restrict__ cnt, int* __restrict__ rowptr,
                             int* __restrict__ bsum, int n) {
    __shared__ int sh[SCAN_B];
    int tid = threadIdx.x;
    int i = blockIdx.x * SCAN_B + tid;
    int v = (i < n) ? cnt[i] : 0;
    sh[tid] = v;
    __syncthreads();
    for (int off = 1; off < SCAN_B; off <<= 1) {
        int t = (tid >= off) ? sh[tid - off] : 0;
        __syncthreads();
        sh[tid] += t;
        __syncthreads();
    }
    if (i < n) rowptr[i] = sh[tid] - v;  // exclusive
    if (tid == SCAN_B - 1) bsum[blockIdx.x] = sh[tid];
}

__global__ void k_scan_bsums(int* __restrict__ bsum, int nb) {
    __shared__ int sh[512];
    int tid = threadIdx.x;
    if (nb <= 512) {
        int v = (tid < nb) ? bsum[tid] : 0;
        sh[tid] = v;
        __syncthreads();
        for (int off = 1; off < 512; off <<= 1) {
            int t = (tid >= off) ? sh[tid - off] : 0;
            __syncthreads();
            sh[tid] += t;
            __syncthreads();
        }
        if (tid < nb) bsum[tid] = sh[tid] - v;
    } else if (tid == 0) {
        int run = 0;
        for (int i = 0; i < nb; ++i) { int t = bsum[i]; bsum[i] = run; run += t; }
    }
}

__global__ void k_scan_add_prep(int* __restrict__ rowptr, const int* __restrict__ bsum,
                                const int* __restrict__ cnt, float* __restrict__ dinv, int n) {
    int i = blockIdx.x * blockDim.x + threadIdx.x;
    if (i >= n) return;
    rowptr[i] += bsum[i / SCAN_B];
    dinv[i] = rsqrtf((float)(cnt[i] + 1));
}

__global__ void kb_fill2(const uint2* __restrict__ staging, const int* __restrict__ bucketBase,
                         const int* __restrict__ rowptr, int* __restrict__ col, int n) {
    __shared__ int cur[BK];
    int b = blockIdx.x;
    int tid = threadIdx.x;
    int v = b * BK + tid;
    cur[tid] = (v < n) ? rowptr[v] : 0;
    __syncthreads();
    int beg = bucketBase[b], end = bucketBase[b + 1];
    for (int i = beg + tid; i < end; i += blockDim.x) {
        uint2 sd = staging[i];
        int pos = atomicAdd(&cur[sd.y & (BK - 1)], 1);
        col[pos] = (int)sd.x;
    }
}

// W1 [64][128] f32 -> W1T [128][64] fp16 ; W2 [128][32] f32 -> W2T [32][128] fp16
__global__ void k_wconv(const float* __restrict__ W1, const float* __restrict__ W2,
                        _Float16* __restrict__ W1T, _Float16* __restrict__ W2T) {
    int i = blockIdx.x * blockDim.x + threadIdx.x;
    if (i < F_IN * HDIM) {
        int k = i >> 7, c = i & 127;
        W1T[c * F_IN + k] = (_Float16)W1[i];
    } else if (i < F_IN * HDIM + HDIM * CDIM) {
        int j = i - F_IN * HDIM;
        int k = j >> 5, c = j & 31;
        W2T[c * HDIM + k] = (_Float16)W2[j];
    }
}

// xs = fp16(dinv .* x)
__global__ void k_prescale(const float* __restrict__ x, const float* __restrict__ dinv,
                           h4* __restrict__ xs, int n) {
    int i = blockIdx.x * blockDim.x + threadIdx.x;
    if (i >= n * (F_IN / 4)) return;
    int v = i >> 4;
    float s = dinv[v];
    float4 val = ((const float4*)x)[i];
    h4 o;
    o.a = __floats2half2_rn(val.x * s, val.y * s);
    o.b = __floats2half2_rn(val.z * s, val.w * s);
    xs[i] = o;
}

// ---------- gather 1 (F=64 fp16 in/out): wave per node, 16-lane quarters x 8B ----
__global__ void k_gather1(const h4* __restrict__ xs, const int* __restrict__ rowptr,
                          const int* __restrict__ cnt, const int* __restrict__ col,
                          const float* __restrict__ dinv, h4* __restrict__ axh, int n) {
    int tid = threadIdx.x;
    int w = tid >> 6, lane = tid & 63;
    int v = blockIdx.x * 4 + w;
    if (v >= n) return;  // wave-uniform
    int q = lane >> 4, l = lane & 15;
    int beg = rowptr[v], deg = cnt[v];
    float2 a0 = make_float2(0.f, 0.f), b0 = make_float2(0.f, 0.f);
    float2 a1 = make_float2(0.f, 0.f), b1 = make_float2(0.f, 0.f);
    float2 a2 = make_float2(0.f, 0.f), b2 = make_float2(0.f, 0.f);
    float2 a3 = make_float2(0.f, 0.f), b3 = make_float2(0.f, 0.f);
    int j = q;
    for (; j + 12 < deg; j += 16) {
        int s0 = col[beg + j];
        int s1 = col[beg + j + 4];
        int s2 = col[beg + j + 8];
        int s3 = col[beg + j + 12];
        h4 v0 = xs[(size_t)s0 * 16 + l];
        h4 v1 = xs[(size_t)s1 * 16 + l];
        h4 v2 = xs[(size_t)s2 * 16 + l];
        h4 v3 = xs[(size_t)s3 * 16 + l];
        float2 f;
        f = __half22float2(v0.a); a0.x += f.x; a0.y += f.y;
        f = __half22float2(v0.b); b0.x += f.x; b0.y += f.y;
        f = __half22float2(v1.a); a1.x += f.x; a1.y += f.y;
        f = __half22float2(v1.b); b1.x += f.x; b1.y += f.y;
        f = __half22float2(v2.a); a2.x += f.x; a2.y += f.y;
        f = __half22float2(v2.b); b2.x += f.x; b2.y += f.y;
        f = __half22float2(v3.a); a3.x += f.x; a3.y += f.y;
        f = __half22float2(v3.b); b3.x += f.x; b3.y += f.y;
    }
    for (; j < deg; j += 4) {
        h4 v0 = xs[(size_t)col[beg + j] * 16 + l];
        float2 f;
        f = __half22float2(v0.a); a0.x += f.x; a0.y += f.y;
        f = __half22float2(v0.b); b0.x += f.x; b0.y += f.y;
    }
    a0.x += a1.x + a2.x + a3.x;  a0.y += a1.y + a2.y + a3.y;
    b0.x += b1.x + b2.x + b3.x;  b0.y += b1.y + b2.y + b3.y;
    a0.x += __shfl_xor(a0.x, 16); a0.y += __shfl_xor(a0.y, 16);
    b0.x += __shfl_xor(b0.x, 16); b0.y += __shfl_xor(b0.y, 16);
    a0.x += __shfl_xor(a0.x, 32); a0.y += __shfl_xor(a0.y, 32);
    b0.x += __shfl_xor(b0.x, 32); b0.y += __shfl_xor(b0.y, 32);
    if (q == 0) {
        float dv = dinv[v];
        h4 sf = xs[(size_t)v * 16 + l];
        float2 s0 = __half22float2(sf.a), s1 = __half22float2(sf.b);
        h4 o;
        o.a = __floats2half2_rn(dv * (a0.x + s0.x), dv * (a0.y + s0.y));
        o.b = __floats2half2_rn(dv * (b0.x + s1.x), dv * (b0.y + s1.y));
        axh[(size_t)v * 16 + l] = o;
    }
}

// ---------- MFMA MLP: h2s = fp16(dinv .* (relu(axh@W1+b1) @ W2)) ----------
// block = 256 = 4 waves; wave handles 16 rows. Layout (mfma_f32_16x16x32_f16):
//   A frag: lane lo=l&15 -> row, hi=l>>4 -> k-octet; B frag: lo -> col, hi -> k-octet
//   D frag: lo -> col, hi*4+reg -> row
// hbuf f32 [64][132]: per-wave rows only -> NO barriers; 2-way (free) bank pattern.
__global__ __launch_bounds__(256) void k_mlp_mfma(
    const _Float16* __restrict__ axh,   // [n][64]
    const _Float16* __restrict__ W1T,   // [128][64]
    const float* __restrict__ b1,
    const _Float16* __restrict__ W2T,   // [32][128]
    const float* __restrict__ dinv,
    __half* __restrict__ h2s, int n) {
    __shared__ float hbuf[64 * 132];
    int tid = threadIdx.x;
    int w = tid >> 6, lane = tid & 63;
    int lo = lane & 15, hi = lane >> 4;
    int m0 = blockIdx.x * 64 + w * 16;

    // ---- layer 1: A frags (2 k-steps) ----
    int arow = m0 + lo; if (arow >= n) arow = n - 1;  // clamp; garbage rows unused
    const half8* aptr = (const half8*)(axh + (size_t)arow * F_IN);
    half8 a0 = aptr[hi];      // k = hi*8
    half8 a1 = aptr[4 + hi];  // k = 32 + hi*8

    float b1v[8];
    f32x4 acc[8];
#pragma unroll
    for (int j = 0; j < 8; ++j) {
        b1v[j] = b1[j * 16 + lo];
        const half8* bptr = (const half8*)(W1T + (size_t)(j * 16 + lo) * F_IN);
        half8 bf0 = bptr[hi];
        half8 bf1 = bptr[4 + hi];
        f32x4 c = {0.f, 0.f, 0.f, 0.f};
        c = __builtin_amdgcn_mfma_f32_16x16x32_f16(a0, bf0, c, 0, 0, 0);
        c = __builtin_amdgcn_mfma_f32_16x16x32_f16(a1, bf1, c, 0, 0, 0);
        acc[j] = c;
    }

    // epilogue 1: bias + relu -> hbuf (own wave's rows; no __syncthreads needed)
#pragma unroll
    for (int j = 0; j < 8; ++j) {
#pragma unroll
        for (int r = 0; r < 4; ++r) {
            int R = w * 16 + hi * 4 + r;
            float hv = acc[j][r] + b1v[j];
            hbuf[R * 132 + j * 16 + lo] = hv > 0.f ? hv : 0.f;
        }
    }

    // ---- layer 2: A from hbuf (f32 -> fp16), B from W2T ----
    f32x4 acc2[2] = {{0.f, 0.f, 0.f, 0.f}, {0.f, 0.f, 0.f, 0.f}};
#pragma unroll
    for (int ks = 0; ks < 4; ++ks) {
        const float* hp = &hbuf[(w * 16 + lo) * 132 + ks * 32 + hi * 8];
        half8 a;
#pragma unroll
        for (int r = 0; r < 8; ++r) a[r] = (_Float16)hp[r];
#pragma unroll
        for (int t = 0; t < 2; ++t) {
            const half8* b2p = (const half8*)(W2T + (size_t)(t * 16 + lo) * HDIM);
            acc2[t] = __builtin_amdgcn_mfma_f32_16x16x32_f16(a, b2p[ks * 4 + hi], acc2[t], 0, 0, 0);
        }
    }

    // epilogue 2: dinv scale -> fp16 h2s
#pragma unroll
    for (int r = 0; r < 4; ++r) {
        int R = m0 + hi * 4 + r;
        if (R < n) {
            float dv = dinv[R];
            h2s[(size_t)R * CDIM + lo]      = __float2half(dv * acc2[0][r]);
            h2s[(size_t)R * CDIM + 16 + lo] = __float2half(dv * acc2[1][r]);
        }
    }
}

// ---------- gather 2 (C=32 fp16): wave per node, 8-lane groups x 8B, unroll x2 ----
__global__ void k_gather2(const h4* __restrict__ h2s, const int* __restrict__ rowptr,
                          const int* __restrict__ cnt, const int* __restrict__ col,
                          const float* __restrict__ dinv, const float* __restrict__ b2,
                          float* __restrict__ out, int n) {
    int tid = threadIdx.x;
    int w = tid >> 6, lane = tid & 63;
    int v = blockIdx.x * 4 + w;
    if (v >= n) return;  // wave-uniform
    int g = lane >> 3, l = lane & 7;
    int beg = rowptr[v], deg = cnt[v];
    float2 a0 = make_float2(0.f, 0.f), b0 = make_float2(0.f, 0.f);
    float2 a1 = make_float2(0.f, 0.f), b1 = make_float2(0.f, 0.f);
    int j = g;
    for (; j + 8 < deg; j += 16) {
        int s0 = col[beg + j];
        int s1 = col[beg + j + 8];
        h4 v0 = h2s[(size_t)s0 * 8 + l];
        h4 v1 = h2s[(size_t)s1 * 8 + l];
        float2 f;
        f = __half22float2(v0.a); a0.x += f.x; a0.y += f.y;
        f = __half22float2(v0.b); b0.x += f.x; b0.y += f.y;
        f = __half22float2(v1.a); a1.x += f.x; a1.y += f.y;
        f = __half22float2(v1.b); b1.x += f.x; b1.y += f.y;
    }
    if (j < deg) {
        h4 v0 = h2s[(size_t)col[beg + j] * 8 + l];
        float2 f;
        f = __half22float2(v0.a); a0.x += f.x; a0.y += f.y;
        f = __half22float2(v0.b); b0.x += f.x; b0.y += f.y;
    }
    a0.x += a1.x; a0.y += a1.y; b0.x += b1.x; b0.y += b1.y;
    a0.x += __shfl_xor(a0.x, 8);  a0.y += __shfl_xor(a0.y, 8);
    b0.x += __shfl_xor(b0.x, 8);  b0.y += __shfl_xor(b0.y, 8);
    a0.x += __shfl_xor(a0.x, 16); a0.y += __shfl_xor(a0.y, 16);
    b0.x += __shfl_xor(b0.x, 16); b0.y += __shfl_xor(b0.y, 16);
    a0.x += __shfl_xor(a0.x, 32); a0.y += __shfl_xor(a0.y, 32);
    b0.x += __shfl_xor(b0.x, 32); b0.y += __shfl_xor(b0.y, 32);
    if (g == 0) {
        float dv = dinv[v];
        h4 sf = h2s[(size_t)v * 8 + l];
        float2 s0 = __half22float2(sf.a), s1 = __half22float2(sf.b);
        float4 bb = ((const float4*)b2)[l];
        float4 o;
        o.x = dv * (a0.x + s0.x) + bb.x;
        o.y = dv * (a0.y + s0.y) + bb.y;
        o.z = dv * (b0.x + s1.x) + bb.z;
        o.w = dv * (b0.y + s1.y) + bb.w;
        ((float4*)(out + (size_t)v * CDIM))[l] = o;
    }
}

extern "C" void kernel_launch(void* const* d_in, const int* in_sizes, int n_in,
                              void* d_out, int out_size, void* d_ws, size_t ws_size,
                              hipStream_t stream) {
    const float* x  = (const float*)d_in[0];
    const int*   ei = (const int*)d_in[1];
    const float* W1 = (const float*)d_in[2];
    const float* b1 = (const float*)d_in[3];
    const float* W2 = (const float*)d_in[4];
    const float* b2 = (const float*)d_in[5];
    float* out = (float*)d_out;

    int n = in_sizes[0] / F_IN;
    int e = in_sizes[1] / 2;
    const int* srcIdx = ei;
    const int* dstIdx = ei + e;

    int nb = (n + SCAN_B - 1) / SCAN_B;
    int nbk = (n + BK - 1) / BK;  // 391 for n=100K (needs <= 511)

    // workspace layout (4B words):
    //   cnt[n] | bucketCnt[512] | bucketBase[520] | bucketCursor[512] |
    //   rowptr[n] | bsum[4096] | col[e] | dinv[n] | xs(h4 n*16) |
    //   axh(fp16 n*64 = n*32 words) | h2s(fp16 n*32 = n*16 words) |
    //   W1T(4096 words) | W2T(2048 words)
    //   staging(uint2 e) overlays axh (dead until gather1; e*2 <= n*32 words)
    int* cnt          = (int*)d_ws;
    int* bucketCnt    = cnt + n;
    int* bucketBase   = bucketCnt + 512;
    int* bucketCursor = bucketBase + 520;
    int* rowptr       = bucketCursor + 512;
    int* bsum         = rowptr + n;
    int* col          = bsum + 4096;
    float* dinv       = (float*)(col + e);
    h4* xs            = (h4*)(dinv + n);                     // n*16 h4
    h4* axh           = xs + (size_t)n * 16;                 // n*16 h4 (fp16 [n][64])
    __half* h2s       = (__half*)(axh + (size_t)n * 16);     // fp16 [n][32]
    _Float16* W1T     = (_Float16*)(h2s + (size_t)n * CDIM); // [128][64]
    _Float16* W2T     = W1T + HDIM * F_IN;                   // [32][128]
    uint2* staging    = (uint2*)axh;

    const int B = 256;

    hipMemsetAsync(bucketCnt, 0, 512 * sizeof(int), stream);
    k_wconv<<<(F_IN * HDIM + HDIM * CDIM + B - 1) / B, B, 0, stream>>>(W1, W2, W1T, W2T);

    // binned edge sort; degree derived from bins (no global atomics)
    kb_hist<<<256, B, 0, stream>>>(dstIdx, e, nbk, bucketCnt);
    kb_scan<<<1, 512, 0, stream>>>(bucketCnt, bucketBase, bucketCursor, nbk);
    kb_scatter<<<(e + SC_CHUNK - 1) / SC_CHUNK, B, 0, stream>>>(srcIdx, dstIdx, e, nbk,
                                                                bucketCursor, staging);
    kb_count<<<nbk, BK, 0, stream>>>(staging, bucketBase, cnt, n);
    k_scan_block<<<nb, SCAN_B, 0, stream>>>(cnt, rowptr, bsum, n);
    k_scan_bsums<<<1, 512, 0, stream>>>(bsum, nb);
    k_scan_add_prep<<<(n + B - 1) / B, B, 0, stream>>>(rowptr, bsum, cnt, dinv, n);
    kb_fill2<<<nbk, BK, 0, stream>>>(staging, bucketBase, rowptr, col, n);

    // layer 1
    k_prescale<<<(n * (F_IN / 4) + B - 1) / B, B, 0, stream>>>(x, dinv, xs, n);
    k_gather1<<<(n + 3) / 4, B, 0, stream>>>(xs, rowptr, cnt, col, dinv, axh, n);
    k_mlp_mfma<<<(n + 63) / 64, B, 0, stream>>>((const _Float16*)axh, W1T, b1, W2T, dinv, h2s, n);
    k_gather2<<<(n + 3) / 4, B, 0, stream>>>((const h4*)h2s, rowptr, cnt, col, dinv, b2, out, n);
}

// Round 10
// 195.415 us; speedup vs baseline: 2.1421x; 1.0507x over previous
//
#include <hip/hip_runtime.h>
#include <hip/hip_fp16.h>

// GCN 2-layer forward, round 10:
//   R9 + fused CSR-build tail. Since buckets are contiguous node ranges and col
//   is bucket-sorted, rowptr[v] = bucketBase[b] + in-bucket degree prefix -- the
//   global node scan was unnecessary. kb_count+3 scans+kb_fill2 -> kb_finalize.
//   Staging packed to uint32 ((dst&255)<<24 | src): halves staging traffic.
//   ax[v]  = dinv[v]*(sum xs[s] + xs[v]),  xs = fp16(dinv.*x)
//   h2s    = fp16(dinv .* (relu(ax@W1+b1) @ W2))   [MFMA]
//   out[v] = dinv[v]*(sum h2s[s] + h2s[v]) + b2

#define F_IN 64
#define HDIM 128
#define CDIM 32
#define BK 256          // nodes per bucket (== kb_finalize blockDim)
#define SC_CHUNK 4096   // edges per kb_scatter workgroup

struct h4 { __half2 a, b; };  // 8-byte packed 4x fp16

typedef _Float16 half8 __attribute__((ext_vector_type(8)));
typedef float f32x4 __attribute__((ext_vector_type(4)));

// ---------- bucket histogram (LDS only; 256 wgs) ----------
__global__ void kb_hist(const int* __restrict__ dst, int e, int nbk,
                        int* __restrict__ bucketCnt) {
    __shared__ int lh[512];
    int tid = threadIdx.x;
    for (int i = tid; i < nbk; i += blockDim.x) lh[i] = 0;
    __syncthreads();
    for (int i = blockIdx.x * blockDim.x + tid; i < e; i += gridDim.x * blockDim.x)
        atomicAdd(&lh[dst[i] >> 8], 1);
    __syncthreads();
    for (int i = tid; i < nbk; i += blockDim.x)
        if (lh[i]) atomicAdd(&bucketCnt[i], lh[i]);
}

// exclusive scan of bucketCnt -> bucketBase (+total at [nbk]); cursor copy
__global__ void kb_scan(const int* __restrict__ bucketCnt, int* __restrict__ bucketBase,
                        int* __restrict__ bucketCursor, int nbk) {
    __shared__ int sh[512];
    int tid = threadIdx.x;
    int v = (tid < nbk) ? bucketCnt[tid] : 0;
    sh[tid] = v;
    __syncthreads();
    for (int off = 1; off < 512; off <<= 1) {
        int t = (tid >= off) ? sh[tid - off] : 0;
        __syncthreads();
        sh[tid] += t;
        __syncthreads();
    }
    if (tid < nbk) {
        bucketBase[tid] = sh[tid] - v;
        bucketCursor[tid] = sh[tid] - v;
    }
    if (tid == nbk) bucketBase[tid] = sh[511];  // total = e
}

// per-wg LDS histogram -> contiguous run reservation -> packed staging writes
__global__ void kb_scatter(const int* __restrict__ src, const int* __restrict__ dst, int e,
                           int nbk, int* __restrict__ bucketCursor,
                           unsigned* __restrict__ staging) {
    __shared__ int lh[512];
    __shared__ int lbase[512];
    int tid = threadIdx.x;
    int c0 = blockIdx.x * SC_CHUNK;
    int c1 = min(c0 + SC_CHUNK, e);
    for (int i = tid; i < nbk; i += blockDim.x) lh[i] = 0;
    __syncthreads();
    for (int i = c0 + tid; i < c1; i += blockDim.x)
        atomicAdd(&lh[dst[i] >> 8], 1);
    __syncthreads();
    for (int i = tid; i < nbk; i += blockDim.x) {
        int c = lh[i];
        lbase[i] = c ? atomicAdd(&bucketCursor[i], c) : 0;
        lh[i] = 0;  // becomes local cursor
    }
    __syncthreads();
    for (int i = c0 + tid; i < c1; i += blockDim.x) {
        int d = dst[i];
        int b = d >> 8;
        int r = atomicAdd(&lh[b], 1);
        staging[lbase[b] + r] = ((unsigned)(d & (BK - 1)) << 24) | (unsigned)src[i];
    }
}

// fused: per-node degree count + in-bucket scan -> rowptr/cnt/dinv + counting sort
__global__ void kb_finalize(const unsigned* __restrict__ staging,
                            const int* __restrict__ bucketBase,
                            int* __restrict__ rowptr, int* __restrict__ cnt,
                            float* __restrict__ dinv, int* __restrict__ col, int n) {
    __shared__ int lc[BK];
    __shared__ int lscan[BK];
    int b = blockIdx.x;
    int tid = threadIdx.x;
    lc[tid] = 0;
    __syncthreads();
    int beg = bucketBase[b], end = bucketBase[b + 1];
    for (int i = beg + tid; i < end; i += blockDim.x)
        atomicAdd(&lc[staging[i] >> 24], 1);
    __syncthreads();
    int deg = lc[tid];
    lscan[tid] = deg;
    __syncthreads();
    for (int off = 1; off < BK; off <<= 1) {
        int t = (tid >= off) ? lscan[tid - off] : 0;
        __syncthreads();
        lscan[tid] += t;
        __syncthreads();
    }
    int rp = beg + lscan[tid] - deg;   // exclusive in-bucket prefix + bucket base
    int v = b * BK + tid;
    if (v < n) {
        rowptr[v] = rp;
        cnt[v] = deg;
        dinv[v] = rsqrtf((float)(deg + 1));
    }
    lc[tid] = rp;  // becomes cursor
    __syncthreads();
    for (int i = beg + tid; i < end; i += blockDim.x) {
        unsigned sd = staging[i];
        int pos = atomicAdd(&lc[sd >> 24], 1);
        col[pos] = (int)(sd & 0xFFFFFFu);
    }
}

// W1 [64][128] f32 -> W1T [128][64] fp16 ; W2 [128][32] f32 -> W2T [32][128] fp16
__global__ void k_wconv(const float* __restrict__ W1, const float* __restrict__ W2,
                        _Float16* __restrict__ W1T, _Float16* __restrict__ W2T) {
    int i = blockIdx.x * blockDim.x + threadIdx.x;
    if (i < F_IN * HDIM) {
        int k = i >> 7, c = i & 127;
        W1T[c * F_IN + k] = (_Float16)W1[i];
    } else if (i < F_IN * HDIM + HDIM * CDIM) {
        int j = i - F_IN * HDIM;
        int k = j >> 5, c = j & 31;
        W2T[c * HDIM + k] = (_Float16)W2[j];
    }
}

// xs = fp16(dinv .* x)
__global__ void k_prescale(const float* __restrict__ x, const float* __restrict__ dinv,
                           h4* __restrict__ xs, int n) {
    int i = blockIdx.x * blockDim.x + threadIdx.x;
    if (i >= n * (F_IN / 4)) return;
    int v = i >> 4;
    float s = dinv[v];
    float4 val = ((const float4*)x)[i];
    h4 o;
    o.a = __floats2half2_rn(val.x * s, val.y * s);
    o.b = __floats2half2_rn(val.z * s, val.w * s);
    xs[i] = o;
}

// ---------- gather 1 (F=64 fp16 in/out): wave per node, 16-lane quarters x 8B ----
__global__ void k_gather1(const h4* __restrict__ xs, const int* __restrict__ rowptr,
                          const int* __restrict__ cnt, const int* __restrict__ col,
                          const float* __restrict__ dinv, h4* __restrict__ axh, int n) {
    int tid = threadIdx.x;
    int w = tid >> 6, lane = tid & 63;
    int v = blockIdx.x * 4 + w;
    if (v >= n) return;  // wave-uniform
    int q = lane >> 4, l = lane & 15;
    int beg = rowptr[v], deg = cnt[v];
    float2 a0 = make_float2(0.f, 0.f), b0 = make_float2(0.f, 0.f);
    float2 a1 = make_float2(0.f, 0.f), b1 = make_float2(0.f, 0.f);
    float2 a2 = make_float2(0.f, 0.f), b2 = make_float2(0.f, 0.f);
    float2 a3 = make_float2(0.f, 0.f), b3 = make_float2(0.f, 0.f);
    int j = q;
    for (; j + 12 < deg; j += 16) {
        int s0 = col[beg + j];
        int s1 = col[beg + j + 4];
        int s2 = col[beg + j + 8];
        int s3 = col[beg + j + 12];
        h4 v0 = xs[(size_t)s0 * 16 + l];
        h4 v1 = xs[(size_t)s1 * 16 + l];
        h4 v2 = xs[(size_t)s2 * 16 + l];
        h4 v3 = xs[(size_t)s3 * 16 + l];
        float2 f;
        f = __half22float2(v0.a); a0.x += f.x; a0.y += f.y;
        f = __half22float2(v0.b); b0.x += f.x; b0.y += f.y;
        f = __half22float2(v1.a); a1.x += f.x; a1.y += f.y;
        f = __half22float2(v1.b); b1.x += f.x; b1.y += f.y;
        f = __half22float2(v2.a); a2.x += f.x; a2.y += f.y;
        f = __half22float2(v2.b); b2.x += f.x; b2.y += f.y;
        f = __half22float2(v3.a); a3.x += f.x; a3.y += f.y;
        f = __half22float2(v3.b); b3.x += f.x; b3.y += f.y;
    }
    for (; j < deg; j += 4) {
        h4 v0 = xs[(size_t)col[beg + j] * 16 + l];
        float2 f;
        f = __half22float2(v0.a); a0.x += f.x; a0.y += f.y;
        f = __half22float2(v0.b); b0.x += f.x; b0.y += f.y;
    }
    a0.x += a1.x + a2.x + a3.x;  a0.y += a1.y + a2.y + a3.y;
    b0.x += b1.x + b2.x + b3.x;  b0.y += b1.y + b2.y + b3.y;
    a0.x += __shfl_xor(a0.x, 16); a0.y += __shfl_xor(a0.y, 16);
    b0.x += __shfl_xor(b0.x, 16); b0.y += __shfl_xor(b0.y, 16);
    a0.x += __shfl_xor(a0.x, 32); a0.y += __shfl_xor(a0.y, 32);
    b0.x += __shfl_xor(b0.x, 32); b0.y += __shfl_xor(b0.y, 32);
    if (q == 0) {
        float dv = dinv[v];
        h4 sf = xs[(size_t)v * 16 + l];
        float2 s0 = __half22float2(sf.a), s1 = __half22float2(sf.b);
        h4 o;
        o.a = __floats2half2_rn(dv * (a0.x + s0.x), dv * (a0.y + s0.y));
        o.b = __floats2half2_rn(dv * (b0.x + s1.x), dv * (b0.y + s1.y));
        axh[(size_t)v * 16 + l] = o;
    }
}

// ---------- MFMA MLP: h2s = fp16(dinv .* (relu(axh@W1+b1) @ W2)) ----------
__global__ __launch_bounds__(256) void k_mlp_mfma(
    const _Float16* __restrict__ axh,   // [n][64]
    const _Float16* __restrict__ W1T,   // [128][64]
    const float* __restrict__ b1,
    const _Float16* __restrict__ W2T,   // [32][128]
    const float* __restrict__ dinv,
    __half* __restrict__ h2s, int n) {
    __shared__ float hbuf[64 * 132];
    int tid = threadIdx.x;
    int w = tid >> 6, lane = tid & 63;
    int lo = lane & 15, hi = lane >> 4;
    int m0 = blockIdx.x * 64 + w * 16;

    int arow = m0 + lo; if (arow >= n) arow = n - 1;  // clamp; garbage rows unused
    const half8* aptr = (const half8*)(axh + (size_t)arow * F_IN);
    half8 a0 = aptr[hi];      // k = hi*8
    half8 a1 = aptr[4 + hi];  // k = 32 + hi*8

    float b1v[8];
    f32x4 acc[8];
#pragma unroll
    for (int j = 0; j < 8; ++j) {
        b1v[j] = b1[j * 16 + lo];
        const half8* bptr = (const half8*)(W1T + (size_t)(j * 16 + lo) * F_IN);
        half8 bf0 = bptr[hi];
        half8 bf1 = bptr[4 + hi];
        f32x4 c = {0.f, 0.f, 0.f, 0.f};
        c = __builtin_amdgcn_mfma_f32_16x16x32_f16(a0, bf0, c, 0, 0, 0);
        c = __builtin_amdgcn_mfma_f32_16x16x32_f16(a1, bf1, c, 0, 0, 0);
        acc[j] = c;
    }

#pragma unroll
    for (int j = 0; j < 8; ++j) {
#pragma unroll
        for (int r = 0; r < 4; ++r) {
            int R = w * 16 + hi * 4 + r;
            float hv = acc[j][r] + b1v[j];
            hbuf[R * 132 + j * 16 + lo] = hv > 0.f ? hv : 0.f;
        }
    }

    f32x4 acc2[2] = {{0.f, 0.f, 0.f, 0.f}, {0.f, 0.f, 0.f, 0.f}};
#pragma unroll
    for (int ks = 0; ks < 4; ++ks) {
        const float* hp = &hbuf[(w * 16 + lo) * 132 + ks * 32 + hi * 8];
        half8 a;
#pragma unroll
        for (int r = 0; r < 8; ++r) a[r] = (_Float16)hp[r];
#pragma unroll
        for (int t = 0; t < 2; ++t) {
            const half8* b2p = (const half8*)(W2T + (size_t)(t * 16 + lo) * HDIM);
            acc2[t] = __builtin_amdgcn_mfma_f32_16x16x32_f16(a, b2p[ks * 4 + hi], acc2[t], 0, 0, 0);
        }
    }

#pragma unroll
    for (int r = 0; r < 4; ++r) {
        int R = m0 + hi * 4 + r;
        if (R < n) {
            float dv = dinv[R];
            h2s[(size_t)R * CDIM + lo]      = __float2half(dv * acc2[0][r]);
            h2s[(size_t)R * CDIM + 16 + lo] = __float2half(dv * acc2[1][r]);
        }
    }
}

// ---------- gather 2 (C=32 fp16): wave per node, 8-lane groups x 8B, unroll x2 ----
__global__ void k_gather2(const h4* __restrict__ h2s, const int* __restrict__ rowptr,
                          const int* __restrict__ cnt, const int* __restrict__ col,
                          const float* __restrict__ dinv, const float* __restrict__ b2,
                          float* __restrict__ out, int n) {
    int tid = threadIdx.x;
    int w = tid >> 6, lane = tid & 63;
    int v = blockIdx.x * 4 + w;
    if (v >= n) return;  // wave-uniform
    int g = lane >> 3, l = lane & 7;
    int beg = rowptr[v], deg = cnt[v];
    float2 a0 = make_float2(0.f, 0.f), b0 = make_float2(0.f, 0.f);
    float2 a1 = make_float2(0.f, 0.f), b1 = make_float2(0.f, 0.f);
    int j = g;
    for (; j + 8 < deg; j += 16) {
        int s0 = col[beg + j];
        int s1 = col[beg + j + 8];
        h4 v0 = h2s[(size_t)s0 * 8 + l];
        h4 v1 = h2s[(size_t)s1 * 8 + l];
        float2 f;
        f = __half22float2(v0.a); a0.x += f.x; a0.y += f.y;
        f = __half22float2(v0.b); b0.x += f.x; b0.y += f.y;
        f = __half22float2(v1.a); a1.x += f.x; a1.y += f.y;
        f = __half22float2(v1.b); b1.x += f.x; b1.y += f.y;
    }
    if (j < deg) {
        h4 v0 = h2s[(size_t)col[beg + j] * 8 + l];
        float2 f;
        f = __half22float2(v0.a); a0.x += f.x; a0.y += f.y;
        f = __half22float2(v0.b); b0.x += f.x; b0.y += f.y;
    }
    a0.x += a1.x; a0.y += a1.y; b0.x += b1.x; b0.y += b1.y;
    a0.x += __shfl_xor(a0.x, 8);  a0.y += __shfl_xor(a0.y, 8);
    b0.x += __shfl_xor(b0.x, 8);  b0.y += __shfl_xor(b0.y, 8);
    a0.x += __shfl_xor(a0.x, 16); a0.y += __shfl_xor(a0.y, 16);
    b0.x += __shfl_xor(b0.x, 16); b0.y += __shfl_xor(b0.y, 16);
    a0.x += __shfl_xor(a0.x, 32); a0.y += __shfl_xor(a0.y, 32);
    b0.x += __shfl_xor(b0.x, 32); b0.y += __shfl_xor(b0.y, 32);
    if (g == 0) {
        float dv = dinv[v];
        h4 sf = h2s[(size_t)v * 8 + l];
        float2 s0 = __half22float2(sf.a), s1 = __half22float2(sf.b);
        float4 bb = ((const float4*)b2)[l];
        float4 o;
        o.x = dv * (a0.x + s0.x) + bb.x;
        o.y = dv * (a0.y + s0.y) + bb.y;
        o.z = dv * (b0.x + s1.x) + bb.z;
        o.w = dv * (b0.y + s1.y) + bb.w;
        ((float4*)(out + (size_t)v * CDIM))[l] = o;
    }
}

extern "C" void kernel_launch(void* const* d_in, const int* in_sizes, int n_in,
                              void* d_out, int out_size, void* d_ws, size_t ws_size,
                              hipStream_t stream) {
    const float* x  = (const float*)d_in[0];
    const int*   ei = (const int*)d_in[1];
    const float* W1 = (const float*)d_in[2];
    const float* b1 = (const float*)d_in[3];
    const float* W2 = (const float*)d_in[4];
    const float* b2 = (const float*)d_in[5];
    float* out = (float*)d_out;

    int n = in_sizes[0] / F_IN;
    int e = in_sizes[1] / 2;
    const int* srcIdx = ei;
    const int* dstIdx = ei + e;

    int nbk = (n + BK - 1) / BK;  // 391 for n=100K (needs <= 511)

    // workspace layout (4B words):
    //   cnt[n] | bucketCnt[512] | bucketBase[520] | bucketCursor[512] |
    //   rowptr[n] | col[e] | dinv[n] | xs(h4 n*16) |
    //   axh(fp16 n*64 = n*32 words) | h2s(fp16 n*32 = n*16 words) |
    //   W1T(4096 words) | W2T(2048 words)
    //   staging(uint e) overlays axh (dead until gather1; e <= n*32 words)
    int* cnt          = (int*)d_ws;
    int* bucketCnt    = cnt + n;
    int* bucketBase   = bucketCnt + 512;
    int* bucketCursor = bucketBase + 520;
    int* rowptr       = bucketCursor + 512;
    int* col          = rowptr + n;
    float* dinv       = (float*)(col + e);
    h4* xs            = (h4*)(dinv + n);                     // n*16 h4
    h4* axh           = xs + (size_t)n * 16;                 // n*16 h4 (fp16 [n][64])
    __half* h2s       = (__half*)(axh + (size_t)n * 16);     // fp16 [n][32]
    _Float16* W1T     = (_Float16*)(h2s + (size_t)n * CDIM); // [128][64]
    _Float16* W2T     = W1T + HDIM * F_IN;                   // [32][128]
    unsigned* staging = (unsigned*)axh;

    const int B = 256;

    hipMemsetAsync(bucketCnt, 0, 512 * sizeof(int), stream);
    k_wconv<<<(F_IN * HDIM + HDIM * CDIM + B - 1) / B, B, 0, stream>>>(W1, W2, W1T, W2T);

    // binned edge sort + fused degree/rowptr/dinv/col build
    kb_hist<<<256, B, 0, stream>>>(dstIdx, e, nbk, bucketCnt);
    kb_scan<<<1, 512, 0, stream>>>(bucketCnt, bucketBase, bucketCursor, nbk);
    kb_scatter<<<(e + SC_CHUNK - 1) / SC_CHUNK, B, 0, stream>>>(srcIdx, dstIdx, e, nbk,
                                                                bucketCursor, staging);
    kb_finalize<<<nbk, BK, 0, stream>>>(staging, bucketBase, rowptr, cnt, dinv, col, n);

    // layer 1
    k_prescale<<<(n * (F_IN / 4) + B - 1) / B, B, 0, stream>>>(x, dinv, xs, n);
    k_gather1<<<(n + 3) / 4, B, 0, stream>>>(xs, rowptr, cnt, col, dinv, axh, n);
    k_mlp_mfma<<<(n + 63) / 64, B, 0, stream>>>((const _Float16*)axh, W1T, b1, W2T, dinv, h2s, n);
    k_gather2<<<(n + 3) / 4, B, 0, stream>>>((const h4*)h2s, rowptr, cnt, col, dinv, b2, out, n);
}

// Round 11
// 194.774 us; speedup vs baseline: 2.1492x; 1.0033x over previous
//
#include <hip/hip_runtime.h>
#include <hip/hip_fp16.h>

// GCN 2-layer forward, round 11:
//   R10 + gather microstructure: 16B/lane row loads (gather1: 8 lanes/row,
//   gather2: 4 lanes/row) and v_pk_add_f16 partial accumulation (4x less
//   hot-loop VALU; <=3 fp16 adds per chain before f32 shuffle reduce).
//   k_wconv folded into kb_hist launch.
//   ax[v]  = dinv[v]*(sum xs[s] + xs[v]),  xs = fp16(dinv.*x)
//   h2s    = fp16(dinv .* (relu(ax@W1+b1) @ W2))   [MFMA]
//   out[v] = dinv[v]*(sum h2s[s] + h2s[v]) + b2

#define F_IN 64
#define HDIM 128
#define CDIM 32
#define BK 256          // nodes per bucket (== kb_finalize blockDim)
#define SC_CHUNK 4096   // edges per kb_scatter workgroup
#define HIST_BLOCKS 256

struct h4 { __half2 a, b; };  // 8-byte packed 4x fp16

typedef _Float16 half8 __attribute__((ext_vector_type(8)));
typedef float f32x4 __attribute__((ext_vector_type(4)));

// ---------- bucket histogram (LDS only) + weight transpose/convert ----------
__global__ void kb_hist(const int* __restrict__ dst, int e, int nbk,
                        int* __restrict__ bucketCnt,
                        const float* __restrict__ W1, const float* __restrict__ W2,
                        _Float16* __restrict__ W1T, _Float16* __restrict__ W2T) {
    int tid = threadIdx.x;
    if (blockIdx.x == HIST_BLOCKS) {  // weight conversion block
        for (int i = tid; i < F_IN * HDIM + HDIM * CDIM; i += blockDim.x) {
            if (i < F_IN * HDIM) {
                int k = i >> 7, c = i & 127;
                W1T[c * F_IN + k] = (_Float16)W1[i];
            } else {
                int j = i - F_IN * HDIM;
                int k = j >> 5, c = j & 31;
                W2T[c * HDIM + k] = (_Float16)W2[j];
            }
        }
        return;
    }
    __shared__ int lh[512];
    for (int i = tid; i < nbk; i += blockDim.x) lh[i] = 0;
    __syncthreads();
    for (int i = blockIdx.x * blockDim.x + tid; i < e; i += HIST_BLOCKS * blockDim.x)
        atomicAdd(&lh[dst[i] >> 8], 1);
    __syncthreads();
    for (int i = tid; i < nbk; i += blockDim.x)
        if (lh[i]) atomicAdd(&bucketCnt[i], lh[i]);
}

// exclusive scan of bucketCnt -> bucketBase (+total at [nbk]); cursor copy
__global__ void kb_scan(const int* __restrict__ bucketCnt, int* __restrict__ bucketBase,
                        int* __restrict__ bucketCursor, int nbk) {
    __shared__ int sh[512];
    int tid = threadIdx.x;
    int v = (tid < nbk) ? bucketCnt[tid] : 0;
    sh[tid] = v;
    __syncthreads();
    for (int off = 1; off < 512; off <<= 1) {
        int t = (tid >= off) ? sh[tid - off] : 0;
        __syncthreads();
        sh[tid] += t;
        __syncthreads();
    }
    if (tid < nbk) {
        bucketBase[tid] = sh[tid] - v;
        bucketCursor[tid] = sh[tid] - v;
    }
    if (tid == nbk) bucketBase[tid] = sh[511];  // total = e
}

// per-wg LDS histogram -> contiguous run reservation -> packed staging writes
__global__ void kb_scatter(const int* __restrict__ src, const int* __restrict__ dst, int e,
                           int nbk, int* __restrict__ bucketCursor,
                           unsigned* __restrict__ staging) {
    __shared__ int lh[512];
    __shared__ int lbase[512];
    int tid = threadIdx.x;
    int c0 = blockIdx.x * SC_CHUNK;
    int c1 = min(c0 + SC_CHUNK, e);
    for (int i = tid; i < nbk; i += blockDim.x) lh[i] = 0;
    __syncthreads();
    for (int i = c0 + tid; i < c1; i += blockDim.x)
        atomicAdd(&lh[dst[i] >> 8], 1);
    __syncthreads();
    for (int i = tid; i < nbk; i += blockDim.x) {
        int c = lh[i];
        lbase[i] = c ? atomicAdd(&bucketCursor[i], c) : 0;
        lh[i] = 0;  // becomes local cursor
    }
    __syncthreads();
    for (int i = c0 + tid; i < c1; i += blockDim.x) {
        int d = dst[i];
        int b = d >> 8;
        int r = atomicAdd(&lh[b], 1);
        staging[lbase[b] + r] = ((unsigned)(d & (BK - 1)) << 24) | (unsigned)src[i];
    }
}

// fused: per-node degree count + in-bucket scan -> rowptr/cnt/dinv + counting sort
__global__ void kb_finalize(const unsigned* __restrict__ staging,
                            const int* __restrict__ bucketBase,
                            int* __restrict__ rowptr, int* __restrict__ cnt,
                            float* __restrict__ dinv, int* __restrict__ col, int n) {
    __shared__ int lc[BK];
    __shared__ int lscan[BK];
    int b = blockIdx.x;
    int tid = threadIdx.x;
    lc[tid] = 0;
    __syncthreads();
    int beg = bucketBase[b], end = bucketBase[b + 1];
    for (int i = beg + tid; i < end; i += blockDim.x)
        atomicAdd(&lc[staging[i] >> 24], 1);
    __syncthreads();
    int deg = lc[tid];
    lscan[tid] = deg;
    __syncthreads();
    for (int off = 1; off < BK; off <<= 1) {
        int t = (tid >= off) ? lscan[tid - off] : 0;
        __syncthreads();
        lscan[tid] += t;
        __syncthreads();
    }
    int rp = beg + lscan[tid] - deg;   // exclusive in-bucket prefix + bucket base
    int v = b * BK + tid;
    if (v < n) {
        rowptr[v] = rp;
        cnt[v] = deg;
        dinv[v] = rsqrtf((float)(deg + 1));
    }
    lc[tid] = rp;  // becomes cursor
    __syncthreads();
    for (int i = beg + tid; i < end; i += blockDim.x) {
        unsigned sd = staging[i];
        int pos = atomicAdd(&lc[sd >> 24], 1);
        col[pos] = (int)(sd & 0xFFFFFFu);
    }
}

// xs = fp16(dinv .* x)
__global__ void k_prescale(const float* __restrict__ x, const float* __restrict__ dinv,
                           h4* __restrict__ xs, int n) {
    int i = blockIdx.x * blockDim.x + threadIdx.x;
    if (i >= n * (F_IN / 4)) return;
    int v = i >> 4;
    float s = dinv[v];
    float4 val = ((const float4*)x)[i];
    h4 o;
    o.a = __floats2half2_rn(val.x * s, val.y * s);
    o.b = __floats2half2_rn(val.z * s, val.w * s);
    xs[i] = o;
}

// ---------- gather 1: wave/node, 8-lane groups x 16B rows, pk-fp16 partials ----
__global__ void k_gather1(const _Float16* __restrict__ xs, const int* __restrict__ rowptr,
                          const int* __restrict__ cnt, const int* __restrict__ col,
                          const float* __restrict__ dinv, _Float16* __restrict__ axh, int n) {
    int tid = threadIdx.x;
    int w = tid >> 6, lane = tid & 63;
    int v = blockIdx.x * 4 + w;
    if (v >= n) return;  // wave-uniform
    int g = lane >> 3, l = lane & 7;
    int beg = rowptr[v], deg = cnt[v];

    __half2 pa0 = __float2half2_rn(0.f), pa1 = pa0, pa2 = pa0, pa3 = pa0;
    __half2 pb0 = pa0, pb1 = pa0, pb2 = pa0, pb3 = pa0;
    int j = g;
    for (; j + 8 < deg; j += 16) {
        int s0 = col[beg + j];
        int s1 = col[beg + j + 8];
        float4 r0 = ((const float4*)(xs + (size_t)s0 * F_IN))[l];
        float4 r1 = ((const float4*)(xs + (size_t)s1 * F_IN))[l];
        pa0 = __hadd2(pa0, *(__half2*)&r0.x); pa1 = __hadd2(pa1, *(__half2*)&r0.y);
        pa2 = __hadd2(pa2, *(__half2*)&r0.z); pa3 = __hadd2(pa3, *(__half2*)&r0.w);
        pb0 = __hadd2(pb0, *(__half2*)&r1.x); pb1 = __hadd2(pb1, *(__half2*)&r1.y);
        pb2 = __hadd2(pb2, *(__half2*)&r1.z); pb3 = __hadd2(pb3, *(__half2*)&r1.w);
    }
    if (j < deg) {
        int s0 = col[beg + j];
        float4 r0 = ((const float4*)(xs + (size_t)s0 * F_IN))[l];
        pa0 = __hadd2(pa0, *(__half2*)&r0.x); pa1 = __hadd2(pa1, *(__half2*)&r0.y);
        pa2 = __hadd2(pa2, *(__half2*)&r0.z); pa3 = __hadd2(pa3, *(__half2*)&r0.w);
    }
    pa0 = __hadd2(pa0, pb0); pa1 = __hadd2(pa1, pb1);
    pa2 = __hadd2(pa2, pb2); pa3 = __hadd2(pa3, pb3);

    // f32 reduce across the 8 groups (xor 8, 16, 32)
    float2 f0 = __half22float2(pa0), f1 = __half22float2(pa1);
    float2 f2 = __half22float2(pa2), f3 = __half22float2(pa3);
    float s[8] = {f0.x, f0.y, f1.x, f1.y, f2.x, f2.y, f3.x, f3.y};
#pragma unroll
    for (int d = 8; d <= 32; d <<= 1)
#pragma unroll
        for (int k = 0; k < 8; ++k) s[k] += __shfl_xor(s[k], d);

    if (g == 0) {
        float dv = dinv[v];
        float4 sr = ((const float4*)(xs + (size_t)v * F_IN))[l];
        float2 s0 = __half22float2(*(__half2*)&sr.x), s1 = __half22float2(*(__half2*)&sr.y);
        float2 s2 = __half22float2(*(__half2*)&sr.z), s3 = __half22float2(*(__half2*)&sr.w);
        float4 o;
        __half2 o0 = __floats2half2_rn(dv * (s[0] + s0.x), dv * (s[1] + s0.y));
        __half2 o1 = __floats2half2_rn(dv * (s[2] + s1.x), dv * (s[3] + s1.y));
        __half2 o2 = __floats2half2_rn(dv * (s[4] + s2.x), dv * (s[5] + s2.y));
        __half2 o3 = __floats2half2_rn(dv * (s[6] + s3.x), dv * (s[7] + s3.y));
        o.x = *(float*)&o0; o.y = *(float*)&o1; o.z = *(float*)&o2; o.w = *(float*)&o3;
        ((float4*)(axh + (size_t)v * F_IN))[l] = o;
    }
}

// ---------- MFMA MLP: h2s = fp16(dinv .* (relu(axh@W1+b1) @ W2)) ----------
__global__ __launch_bounds__(256) void k_mlp_mfma(
    const _Float16* __restrict__ axh,   // [n][64]
    const _Float16* __restrict__ W1T,   // [128][64]
    const float* __restrict__ b1,
    const _Float16* __restrict__ W2T,   // [32][128]
    const float* __restrict__ dinv,
    __half* __restrict__ h2s, int n) {
    __shared__ float hbuf[64 * 132];
    int tid = threadIdx.x;
    int w = tid >> 6, lane = tid & 63;
    int lo = lane & 15, hi = lane >> 4;
    int m0 = blockIdx.x * 64 + w * 16;

    int arow = m0 + lo; if (arow >= n) arow = n - 1;  // clamp; garbage rows unused
    const half8* aptr = (const half8*)(axh + (size_t)arow * F_IN);
    half8 a0 = aptr[hi];      // k = hi*8
    half8 a1 = aptr[4 + hi];  // k = 32 + hi*8

    float b1v[8];
    f32x4 acc[8];
#pragma unroll
    for (int j = 0; j < 8; ++j) {
        b1v[j] = b1[j * 16 + lo];
        const half8* bptr = (const half8*)(W1T + (size_t)(j * 16 + lo) * F_IN);
        half8 bf0 = bptr[hi];
        half8 bf1 = bptr[4 + hi];
        f32x4 c = {0.f, 0.f, 0.f, 0.f};
        c = __builtin_amdgcn_mfma_f32_16x16x32_f16(a0, bf0, c, 0, 0, 0);
        c = __builtin_amdgcn_mfma_f32_16x16x32_f16(a1, bf1, c, 0, 0, 0);
        acc[j] = c;
    }

#pragma unroll
    for (int j = 0; j < 8; ++j) {
#pragma unroll
        for (int r = 0; r < 4; ++r) {
            int R = w * 16 + hi * 4 + r;
            float hv = acc[j][r] + b1v[j];
            hbuf[R * 132 + j * 16 + lo] = hv > 0.f ? hv : 0.f;
        }
    }

    f32x4 acc2[2] = {{0.f, 0.f, 0.f, 0.f}, {0.f, 0.f, 0.f, 0.f}};
#pragma unroll
    for (int ks = 0; ks < 4; ++ks) {
        const float* hp = &hbuf[(w * 16 + lo) * 132 + ks * 32 + hi * 8];
        half8 a;
#pragma unroll
        for (int r = 0; r < 8; ++r) a[r] = (_Float16)hp[r];
#pragma unroll
        for (int t = 0; t < 2; ++t) {
            const half8* b2p = (const half8*)(W2T + (size_t)(t * 16 + lo) * HDIM);
            acc2[t] = __builtin_amdgcn_mfma_f32_16x16x32_f16(a, b2p[ks * 4 + hi], acc2[t], 0, 0, 0);
        }
    }

#pragma unroll
    for (int r = 0; r < 4; ++r) {
        int R = m0 + hi * 4 + r;
        if (R < n) {
            float dv = dinv[R];
            h2s[(size_t)R * CDIM + lo]      = __float2half(dv * acc2[0][r]);
            h2s[(size_t)R * CDIM + 16 + lo] = __float2half(dv * acc2[1][r]);
        }
    }
}

// ---------- gather 2: wave/node, 4-lane groups x 16B rows, pk-fp16 partials ----
__global__ void k_gather2(const _Float16* __restrict__ h2s, const int* __restrict__ rowptr,
                          const int* __restrict__ cnt, const int* __restrict__ col,
                          const float* __restrict__ dinv, const float* __restrict__ b2,
                          float* __restrict__ out, int n) {
    int tid = threadIdx.x;
    int w = tid >> 6, lane = tid & 63;
    int v = blockIdx.x * 4 + w;
    if (v >= n) return;  // wave-uniform
    int g = lane >> 2, l = lane & 3;
    int beg = rowptr[v], deg = cnt[v];

    __half2 pa0 = __float2half2_rn(0.f), pa1 = pa0, pa2 = pa0, pa3 = pa0;
    __half2 pb0 = pa0, pb1 = pa0, pb2 = pa0, pb3 = pa0;
    int j = g;
    for (; j + 16 < deg; j += 32) {
        int s0 = col[beg + j];
        int s1 = col[beg + j + 16];
        float4 r0 = ((const float4*)(h2s + (size_t)s0 * CDIM))[l];
        float4 r1 = ((const float4*)(h2s + (size_t)s1 * CDIM))[l];
        pa0 = __hadd2(pa0, *(__half2*)&r0.x); pa1 = __hadd2(pa1, *(__half2*)&r0.y);
        pa2 = __hadd2(pa2, *(__half2*)&r0.z); pa3 = __hadd2(pa3, *(__half2*)&r0.w);
        pb0 = __hadd2(pb0, *(__half2*)&r1.x); pb1 = __hadd2(pb1, *(__half2*)&r1.y);
        pb2 = __hadd2(pb2, *(__half2*)&r1.z); pb3 = __hadd2(pb3, *(__half2*)&r1.w);
    }
    if (j < deg) {
        int s0 = col[beg + j];
        float4 r0 = ((const float4*)(h2s + (size_t)s0 * CDIM))[l];
        pa0 = __hadd2(pa0, *(__half2*)&r0.x); pa1 = __hadd2(pa1, *(__half2*)&r0.y);
        pa2 = __hadd2(pa2, *(__half2*)&r0.z); pa3 = __hadd2(pa3, *(__half2*)&r0.w);
    }
    pa0 = __hadd2(pa0, pb0); pa1 = __hadd2(pa1, pb1);
    pa2 = __hadd2(pa2, pb2); pa3 = __hadd2(pa3, pb3);

    // f32 reduce across the 16 groups (xor 4, 8, 16, 32)
    float2 f0 = __half22float2(pa0), f1 = __half22float2(pa1);
    float2 f2 = __half22float2(pa2), f3 = __half22float2(pa3);
    float s[8] = {f0.x, f0.y, f1.x, f1.y, f2.x, f2.y, f3.x, f3.y};
#pragma unroll
    for (int d = 4; d <= 32; d <<= 1)
#pragma unroll
        for (int k = 0; k < 8; ++k) s[k] += __shfl_xor(s[k], d);

    if (g == 0) {
        float dv = dinv[v];
        float4 sr = ((const float4*)(h2s + (size_t)v * CDIM))[l];
        float2 s0 = __half22float2(*(__half2*)&sr.x), s1 = __half22float2(*(__half2*)&sr.y);
        float2 s2 = __half22float2(*(__half2*)&sr.z), s3 = __half22float2(*(__half2*)&sr.w);
        const float4* bbp = (const float4*)(b2 + l * 8);
        float4 ba = bbp[0], bb = bbp[1];
        float4 o0, o1;
        o0.x = dv * (s[0] + s0.x) + ba.x;
        o0.y = dv * (s[1] + s0.y) + ba.y;
        o0.z = dv * (s[2] + s1.x) + ba.z;
        o0.w = dv * (s[3] + s1.y) + ba.w;
        o1.x = dv * (s[4] + s2.x) + bb.x;
        o1.y = dv * (s[5] + s2.y) + bb.y;
        o1.z = dv * (s[6] + s3.x) + bb.z;
        o1.w = dv * (s[7] + s3.y) + bb.w;
        float4* op = (float4*)(out + (size_t)v * CDIM + l * 8);
        op[0] = o0;
        op[1] = o1;
    }
}

extern "C" void kernel_launch(void* const* d_in, const int* in_sizes, int n_in,
                              void* d_out, int out_size, void* d_ws, size_t ws_size,
                              hipStream_t stream) {
    const float* x  = (const float*)d_in[0];
    const int*   ei = (const int*)d_in[1];
    const float* W1 = (const float*)d_in[2];
    const float* b1 = (const float*)d_in[3];
    const float* W2 = (const float*)d_in[4];
    const float* b2 = (const float*)d_in[5];
    float* out = (float*)d_out;

    int n = in_sizes[0] / F_IN;
    int e = in_sizes[1] / 2;
    const int* srcIdx = ei;
    const int* dstIdx = ei + e;

    int nbk = (n + BK - 1) / BK;  // 391 for n=100K (needs <= 511)

    // workspace layout (4B words) -- xs/axh/h2s offsets all 16B-aligned:
    //   cnt[n] | bucketCnt[512] | bucketBase[520] | bucketCursor[512] |
    //   rowptr[n] | col[e] | dinv[n] | xs(fp16 [n][64]) | axh(fp16 [n][64]) |
    //   h2s(fp16 [n][32]) | W1T | W2T ; staging(uint e) overlays axh
    int* cnt          = (int*)d_ws;
    int* bucketCnt    = cnt + n;
    int* bucketBase   = bucketCnt + 512;
    int* bucketCursor = bucketBase + 520;
    int* rowptr       = bucketCursor + 512;
    int* col          = rowptr + n;
    float* dinv       = (float*)(col + e);
    _Float16* xs      = (_Float16*)(dinv + n);               // [n][64]
    _Float16* axh     = xs + (size_t)n * F_IN;               // [n][64]
    __half* h2s       = (__half*)(axh + (size_t)n * F_IN);   // [n][32]
    _Float16* W1T     = (_Float16*)(h2s + (size_t)n * CDIM); // [128][64]
    _Float16* W2T     = W1T + HDIM * F_IN;                   // [32][128]
    unsigned* staging = (unsigned*)axh;

    const int B = 256;

    hipMemsetAsync(bucketCnt, 0, 512 * sizeof(int), stream);

    // binned edge sort + fused degree/rowptr/dinv/col build (+ weight conv)
    kb_hist<<<HIST_BLOCKS + 1, B, 0, stream>>>(dstIdx, e, nbk, bucketCnt, W1, W2, W1T, W2T);
    kb_scan<<<1, 512, 0, stream>>>(bucketCnt, bucketBase, bucketCursor, nbk);
    kb_scatter<<<(e + SC_CHUNK - 1) / SC_CHUNK, B, 0, stream>>>(srcIdx, dstIdx, e, nbk,
                                                                bucketCursor, staging);
    kb_finalize<<<nbk, BK, 0, stream>>>(staging, bucketBase, rowptr, cnt, dinv, col, n);

    // layer 1
    k_prescale<<<(n * (F_IN / 4) + B - 1) / B, B, 0, stream>>>(x, dinv, (h4*)xs, n);
    k_gather1<<<(n + 3) / 4, B, 0, stream>>>(xs, rowptr, cnt, col, dinv, axh, n);
    k_mlp_mfma<<<(n + 63) / 64, B, 0, stream>>>(axh, W1T, b1, W2T, dinv, h2s, n);
    k_gather2<<<(n + 3) / 4, B, 0, stream>>>((const _Float16*)h2s, rowptr, cnt, col, dinv, b2, out, n);
}

// Round 12
// 180.622 us; speedup vs baseline: 2.3176x; 1.0784x over previous
//
#include <hip/hip_runtime.h>
#include <hip/hip_fp16.h>

// GCN 2-layer forward, round 12:
//   R11 + gather restructure: 2 nodes/wave (4 row-loads in flight per lane),
//   packed-half2 butterfly reduce (half the tail VALU), zero-row padding at
//   xs[n]/h2s[n] so invalid edge slots load harmlessly.
//   ax[v]  = dinv[v]*(sum xs[s] + xs[v]),  xs = fp16(dinv.*x)
//   h2s    = fp16(dinv .* (relu(ax@W1+b1) @ W2))   [MFMA]
//   out[v] = dinv[v]*(sum h2s[s] + h2s[v]) + b2

#define F_IN 64
#define HDIM 128
#define CDIM 32
#define BK 256          // nodes per bucket (== kb_finalize blockDim)
#define SC_CHUNK 4096   // edges per kb_scatter workgroup
#define HIST_BLOCKS 256

struct h4 { __half2 a, b; };  // 8-byte packed 4x fp16

typedef _Float16 half8 __attribute__((ext_vector_type(8)));
typedef float f32x4 __attribute__((ext_vector_type(4)));

__device__ __forceinline__ __half2 hshfl_xor(__half2 h, int d) {
    union { __half2 h2; int i; } u;
    u.h2 = h;
    u.i = __shfl_xor(u.i, d);
    return u.h2;
}

// ---------- bucket histogram (LDS only) + weight transpose/convert ----------
__global__ void kb_hist(const int* __restrict__ dst, int e, int nbk,
                        int* __restrict__ bucketCnt,
                        const float* __restrict__ W1, const float* __restrict__ W2,
                        _Float16* __restrict__ W1T, _Float16* __restrict__ W2T) {
    int tid = threadIdx.x;
    if (blockIdx.x == HIST_BLOCKS) {  // weight conversion block
        for (int i = tid; i < F_IN * HDIM + HDIM * CDIM; i += blockDim.x) {
            if (i < F_IN * HDIM) {
                int k = i >> 7, c = i & 127;
                W1T[c * F_IN + k] = (_Float16)W1[i];
            } else {
                int j = i - F_IN * HDIM;
                int k = j >> 5, c = j & 31;
                W2T[c * HDIM + k] = (_Float16)W2[j];
            }
        }
        return;
    }
    __shared__ int lh[512];
    for (int i = tid; i < nbk; i += blockDim.x) lh[i] = 0;
    __syncthreads();
    for (int i = blockIdx.x * blockDim.x + tid; i < e; i += HIST_BLOCKS * blockDim.x)
        atomicAdd(&lh[dst[i] >> 8], 1);
    __syncthreads();
    for (int i = tid; i < nbk; i += blockDim.x)
        if (lh[i]) atomicAdd(&bucketCnt[i], lh[i]);
}

// exclusive scan of bucketCnt -> bucketBase (+total at [nbk]); cursor copy
__global__ void kb_scan(const int* __restrict__ bucketCnt, int* __restrict__ bucketBase,
                        int* __restrict__ bucketCursor, int nbk) {
    __shared__ int sh[512];
    int tid = threadIdx.x;
    int v = (tid < nbk) ? bucketCnt[tid] : 0;
    sh[tid] = v;
    __syncthreads();
    for (int off = 1; off < 512; off <<= 1) {
        int t = (tid >= off) ? sh[tid - off] : 0;
        __syncthreads();
        sh[tid] += t;
        __syncthreads();
    }
    if (tid < nbk) {
        bucketBase[tid] = sh[tid] - v;
        bucketCursor[tid] = sh[tid] - v;
    }
    if (tid == nbk) bucketBase[tid] = sh[511];  // total = e
}

// per-wg LDS histogram -> contiguous run reservation -> packed staging writes
__global__ void kb_scatter(const int* __restrict__ src, const int* __restrict__ dst, int e,
                           int nbk, int* __restrict__ bucketCursor,
                           unsigned* __restrict__ staging) {
    __shared__ int lh[512];
    __shared__ int lbase[512];
    int tid = threadIdx.x;
    int c0 = blockIdx.x * SC_CHUNK;
    int c1 = min(c0 + SC_CHUNK, e);
    for (int i = tid; i < nbk; i += blockDim.x) lh[i] = 0;
    __syncthreads();
    for (int i = c0 + tid; i < c1; i += blockDim.x)
        atomicAdd(&lh[dst[i] >> 8], 1);
    __syncthreads();
    for (int i = tid; i < nbk; i += blockDim.x) {
        int c = lh[i];
        lbase[i] = c ? atomicAdd(&bucketCursor[i], c) : 0;
        lh[i] = 0;  // becomes local cursor
    }
    __syncthreads();
    for (int i = c0 + tid; i < c1; i += blockDim.x) {
        int d = dst[i];
        int b = d >> 8;
        int r = atomicAdd(&lh[b], 1);
        staging[lbase[b] + r] = ((unsigned)(d & (BK - 1)) << 24) | (unsigned)src[i];
    }
}

// fused: per-node degree count + in-bucket scan -> rowptr/cnt/dinv + counting sort
__global__ void kb_finalize(const unsigned* __restrict__ staging,
                            const int* __restrict__ bucketBase,
                            int* __restrict__ rowptr, int* __restrict__ cnt,
                            float* __restrict__ dinv, int* __restrict__ col, int n) {
    __shared__ int lc[BK];
    __shared__ int lscan[BK];
    int b = blockIdx.x;
    int tid = threadIdx.x;
    lc[tid] = 0;
    __syncthreads();
    int beg = bucketBase[b], end = bucketBase[b + 1];
    for (int i = beg + tid; i < end; i += blockDim.x)
        atomicAdd(&lc[staging[i] >> 24], 1);
    __syncthreads();
    int deg = lc[tid];
    lscan[tid] = deg;
    __syncthreads();
    for (int off = 1; off < BK; off <<= 1) {
        int t = (tid >= off) ? lscan[tid - off] : 0;
        __syncthreads();
        lscan[tid] += t;
        __syncthreads();
    }
    int rp = beg + lscan[tid] - deg;   // exclusive in-bucket prefix + bucket base
    int v = b * BK + tid;
    if (v < n) {
        rowptr[v] = rp;
        cnt[v] = deg;
        dinv[v] = rsqrtf((float)(deg + 1));
    }
    lc[tid] = rp;  // becomes cursor
    __syncthreads();
    for (int i = beg + tid; i < end; i += blockDim.x) {
        unsigned sd = staging[i];
        int pos = atomicAdd(&lc[sd >> 24], 1);
        col[pos] = (int)(sd & 0xFFFFFFu);
    }
}

// xs = fp16(dinv .* x) for v<n; zero row at xs[n] and h2s[n]
__global__ void k_prescale(const float* __restrict__ x, const float* __restrict__ dinv,
                           h4* __restrict__ xs, h4* __restrict__ h2s_h4, int n) {
    int i = blockIdx.x * blockDim.x + threadIdx.x;
    if (i >= (n + 1) * (F_IN / 4)) return;
    int v = i >> 4;
    int q = i & 15;
    h4 o;
    if (v < n) {
        float s = dinv[v];
        float4 val = ((const float4*)x)[i];
        o.a = __floats2half2_rn(val.x * s, val.y * s);
        o.b = __floats2half2_rn(val.z * s, val.w * s);
    } else {
        o.a = __float2half2_rn(0.f);
        o.b = o.a;
        if (q < 8) h2s_h4[(size_t)n * 8 + q] = o;  // zero row of h2s
    }
    xs[i] = o;
}

// ---------- gather 1: wave = 2 nodes, 8-lane groups x 16B rows, 2-deep unroll ----
// 4 row-loads in flight per lane; packed-half2 butterfly; zero-row padding.
__global__ void k_gather1(const _Float16* __restrict__ xs, const int* __restrict__ rowptr,
                          const int* __restrict__ cnt, const int* __restrict__ col,
                          const float* __restrict__ dinv, _Float16* __restrict__ axh, int n) {
    int tid = threadIdx.x;
    int w = tid >> 6, lane = tid & 63;
    int vA = blockIdx.x * 8 + w * 2;
    if (vA >= n) return;  // wave-uniform
    int vB = vA + 1;
    int g = lane >> 3, l = lane & 7;
    int begA = rowptr[vA], degA = cnt[vA];
    int begB = 0, degB = 0;
    if (vB < n) { begB = rowptr[vB]; degB = cnt[vB]; }
    int dmax = max(degA, degB);

    __half2 aA0 = __float2half2_rn(0.f), aA1 = aA0, aA2 = aA0, aA3 = aA0;
    __half2 aB0 = aA0, aB1 = aA0, aB2 = aA0, aB3 = aA0;

    for (int j = g; j < dmax; j += 16) {
        int jb = j + 8;
        int sA0 = (j  < degA) ? col[begA + j]  : n;
        int sA1 = (jb < degA) ? col[begA + jb] : n;
        int sB0 = (j  < degB) ? col[begB + j]  : n;
        int sB1 = (jb < degB) ? col[begB + jb] : n;
        float4 rA0 = ((const float4*)(xs + (size_t)sA0 * F_IN))[l];
        float4 rA1 = ((const float4*)(xs + (size_t)sA1 * F_IN))[l];
        float4 rB0 = ((const float4*)(xs + (size_t)sB0 * F_IN))[l];
        float4 rB1 = ((const float4*)(xs + (size_t)sB1 * F_IN))[l];
        aA0 = __hadd2(aA0, *(__half2*)&rA0.x); aA1 = __hadd2(aA1, *(__half2*)&rA0.y);
        aA2 = __hadd2(aA2, *(__half2*)&rA0.z); aA3 = __hadd2(aA3, *(__half2*)&rA0.w);
        aA0 = __hadd2(aA0, *(__half2*)&rA1.x); aA1 = __hadd2(aA1, *(__half2*)&rA1.y);
        aA2 = __hadd2(aA2, *(__half2*)&rA1.z); aA3 = __hadd2(aA3, *(__half2*)&rA1.w);
        aB0 = __hadd2(aB0, *(__half2*)&rB0.x); aB1 = __hadd2(aB1, *(__half2*)&rB0.y);
        aB2 = __hadd2(aB2, *(__half2*)&rB0.z); aB3 = __hadd2(aB3, *(__half2*)&rB0.w);
        aB0 = __hadd2(aB0, *(__half2*)&rB1.x); aB1 = __hadd2(aB1, *(__half2*)&rB1.y);
        aB2 = __hadd2(aB2, *(__half2*)&rB1.z); aB3 = __hadd2(aB3, *(__half2*)&rB1.w);
    }

    // packed butterfly across the 8 groups (xor 8, 16, 32)
#pragma unroll
    for (int d = 8; d <= 32; d <<= 1) {
        aA0 = __hadd2(aA0, hshfl_xor(aA0, d)); aA1 = __hadd2(aA1, hshfl_xor(aA1, d));
        aA2 = __hadd2(aA2, hshfl_xor(aA2, d)); aA3 = __hadd2(aA3, hshfl_xor(aA3, d));
        aB0 = __hadd2(aB0, hshfl_xor(aB0, d)); aB1 = __hadd2(aB1, hshfl_xor(aB1, d));
        aB2 = __hadd2(aB2, hshfl_xor(aB2, d)); aB3 = __hadd2(aB3, hshfl_xor(aB3, d));
    }

    if (g == 0) {  // epilogue node A
        float dv = dinv[vA];
        float4 sr = ((const float4*)(xs + (size_t)vA * F_IN))[l];
        float2 f0 = __half22float2(aA0), f1 = __half22float2(aA1);
        float2 f2 = __half22float2(aA2), f3 = __half22float2(aA3);
        float2 s0 = __half22float2(*(__half2*)&sr.x), s1 = __half22float2(*(__half2*)&sr.y);
        float2 s2 = __half22float2(*(__half2*)&sr.z), s3 = __half22float2(*(__half2*)&sr.w);
        __half2 o0 = __floats2half2_rn(dv * (f0.x + s0.x), dv * (f0.y + s0.y));
        __half2 o1 = __floats2half2_rn(dv * (f1.x + s1.x), dv * (f1.y + s1.y));
        __half2 o2 = __floats2half2_rn(dv * (f2.x + s2.x), dv * (f2.y + s2.y));
        __half2 o3 = __floats2half2_rn(dv * (f3.x + s3.x), dv * (f3.y + s3.y));
        float4 o;
        o.x = *(float*)&o0; o.y = *(float*)&o1; o.z = *(float*)&o2; o.w = *(float*)&o3;
        ((float4*)(axh + (size_t)vA * F_IN))[l] = o;
    } else if (g == 1 && vB < n) {  // epilogue node B
        float dv = dinv[vB];
        float4 sr = ((const float4*)(xs + (size_t)vB * F_IN))[l];
        float2 f0 = __half22float2(aB0), f1 = __half22float2(aB1);
        float2 f2 = __half22float2(aB2), f3 = __half22float2(aB3);
        float2 s0 = __half22float2(*(__half2*)&sr.x), s1 = __half22float2(*(__half2*)&sr.y);
        float2 s2 = __half22float2(*(__half2*)&sr.z), s3 = __half22float2(*(__half2*)&sr.w);
        __half2 o0 = __floats2half2_rn(dv * (f0.x + s0.x), dv * (f0.y + s0.y));
        __half2 o1 = __floats2half2_rn(dv * (f1.x + s1.x), dv * (f1.y + s1.y));
        __half2 o2 = __floats2half2_rn(dv * (f2.x + s2.x), dv * (f2.y + s2.y));
        __half2 o3 = __floats2half2_rn(dv * (f3.x + s3.x), dv * (f3.y + s3.y));
        float4 o;
        o.x = *(float*)&o0; o.y = *(float*)&o1; o.z = *(float*)&o2; o.w = *(float*)&o3;
        ((float4*)(axh + (size_t)vB * F_IN))[l] = o;
    }
}

// ---------- MFMA MLP: h2s = fp16(dinv .* (relu(axh@W1+b1) @ W2)) ----------
__global__ __launch_bounds__(256) void k_mlp_mfma(
    const _Float16* __restrict__ axh,   // [n][64]
    const _Float16* __restrict__ W1T,   // [128][64]
    const float* __restrict__ b1,
    const _Float16* __restrict__ W2T,   // [32][128]
    const float* __restrict__ dinv,
    __half* __restrict__ h2s, int n) {
    __shared__ float hbuf[64 * 132];
    int tid = threadIdx.x;
    int w = tid >> 6, lane = tid & 63;
    int lo = lane & 15, hi = lane >> 4;
    int m0 = blockIdx.x * 64 + w * 16;

    int arow = m0 + lo; if (arow >= n) arow = n - 1;  // clamp; garbage rows unused
    const half8* aptr = (const half8*)(axh + (size_t)arow * F_IN);
    half8 a0 = aptr[hi];      // k = hi*8
    half8 a1 = aptr[4 + hi];  // k = 32 + hi*8

    float b1v[8];
    f32x4 acc[8];
#pragma unroll
    for (int j = 0; j < 8; ++j) {
        b1v[j] = b1[j * 16 + lo];
        const half8* bptr = (const half8*)(W1T + (size_t)(j * 16 + lo) * F_IN);
        half8 bf0 = bptr[hi];
        half8 bf1 = bptr[4 + hi];
        f32x4 c = {0.f, 0.f, 0.f, 0.f};
        c = __builtin_amdgcn_mfma_f32_16x16x32_f16(a0, bf0, c, 0, 0, 0);
        c = __builtin_amdgcn_mfma_f32_16x16x32_f16(a1, bf1, c, 0, 0, 0);
        acc[j] = c;
    }

#pragma unroll
    for (int j = 0; j < 8; ++j) {
#pragma unroll
        for (int r = 0; r < 4; ++r) {
            int R = w * 16 + hi * 4 + r;
            float hv = acc[j][r] + b1v[j];
            hbuf[R * 132 + j * 16 + lo] = hv > 0.f ? hv : 0.f;
        }
    }

    f32x4 acc2[2] = {{0.f, 0.f, 0.f, 0.f}, {0.f, 0.f, 0.f, 0.f}};
#pragma unroll
    for (int ks = 0; ks < 4; ++ks) {
        const float* hp = &hbuf[(w * 16 + lo) * 132 + ks * 32 + hi * 8];
        half8 a;
#pragma unroll
        for (int r = 0; r < 8; ++r) a[r] = (_Float16)hp[r];
#pragma unroll
        for (int t = 0; t < 2; ++t) {
            const half8* b2p = (const half8*)(W2T + (size_t)(t * 16 + lo) * HDIM);
            acc2[t] = __builtin_amdgcn_mfma_f32_16x16x32_f16(a, b2p[ks * 4 + hi], acc2[t], 0, 0, 0);
        }
    }

#pragma unroll
    for (int r = 0; r < 4; ++r) {
        int R = m0 + hi * 4 + r;
        if (R < n) {
            float dv = dinv[R];
            h2s[(size_t)R * CDIM + lo]      = __float2half(dv * acc2[0][r]);
            h2s[(size_t)R * CDIM + 16 + lo] = __float2half(dv * acc2[1][r]);
        }
    }
}

// ---------- gather 2: wave = 2 nodes, 4-lane groups x 16B rows ----------
__global__ void k_gather2(const _Float16* __restrict__ h2s, const int* __restrict__ rowptr,
                          const int* __restrict__ cnt, const int* __restrict__ col,
                          const float* __restrict__ dinv, const float* __restrict__ b2,
                          float* __restrict__ out, int n) {
    int tid = threadIdx.x;
    int w = tid >> 6, lane = tid & 63;
    int vA = blockIdx.x * 8 + w * 2;
    if (vA >= n) return;  // wave-uniform
    int vB = vA + 1;
    int g = lane >> 2, l = lane & 3;
    int begA = rowptr[vA], degA = cnt[vA];
    int begB = 0, degB = 0;
    if (vB < n) { begB = rowptr[vB]; degB = cnt[vB]; }
    int dmax = max(degA, degB);

    __half2 aA0 = __float2half2_rn(0.f), aA1 = aA0, aA2 = aA0, aA3 = aA0;
    __half2 aB0 = aA0, aB1 = aA0, aB2 = aA0, aB3 = aA0;

    for (int j = g; j < dmax; j += 16) {
        int sA = (j < degA) ? col[begA + j] : n;
        int sB = (j < degB) ? col[begB + j] : n;
        float4 rA = ((const float4*)(h2s + (size_t)sA * CDIM))[l];
        float4 rB = ((const float4*)(h2s + (size_t)sB * CDIM))[l];
        aA0 = __hadd2(aA0, *(__half2*)&rA.x); aA1 = __hadd2(aA1, *(__half2*)&rA.y);
        aA2 = __hadd2(aA2, *(__half2*)&rA.z); aA3 = __hadd2(aA3, *(__half2*)&rA.w);
        aB0 = __hadd2(aB0, *(__half2*)&rB.x); aB1 = __hadd2(aB1, *(__half2*)&rB.y);
        aB2 = __hadd2(aB2, *(__half2*)&rB.z); aB3 = __hadd2(aB3, *(__half2*)&rB.w);
    }

    // packed butterfly across the 16 groups (xor 4, 8, 16, 32)
#pragma unroll
    for (int d = 4; d <= 32; d <<= 1) {
        aA0 = __hadd2(aA0, hshfl_xor(aA0, d)); aA1 = __hadd2(aA1, hshfl_xor(aA1, d));
        aA2 = __hadd2(aA2, hshfl_xor(aA2, d)); aA3 = __hadd2(aA3, hshfl_xor(aA3, d));
        aB0 = __hadd2(aB0, hshfl_xor(aB0, d)); aB1 = __hadd2(aB1, hshfl_xor(aB1, d));
        aB2 = __hadd2(aB2, hshfl_xor(aB2, d)); aB3 = __hadd2(aB3, hshfl_xor(aB3, d));
    }

    if (g == 0) {  // epilogue node A
        float dv = dinv[vA];
        float4 sr = ((const float4*)(h2s + (size_t)vA * CDIM))[l];
        float2 f0 = __half22float2(aA0), f1 = __half22float2(aA1);
        float2 f2 = __half22float2(aA2), f3 = __half22float2(aA3);
        float2 s0 = __half22float2(*(__half2*)&sr.x), s1 = __half22float2(*(__half2*)&sr.y);
        float2 s2 = __half22float2(*(__half2*)&sr.z), s3 = __half22float2(*(__half2*)&sr.w);
        const float4* bbp = (const float4*)(b2 + l * 8);
        float4 ba = bbp[0], bb = bbp[1];
        float4 o0, o1;
        o0.x = dv * (f0.x + s0.x) + ba.x;
        o0.y = dv * (f0.y + s0.y) + ba.y;
        o0.z = dv * (f1.x + s1.x) + ba.z;
        o0.w = dv * (f1.y + s1.y) + ba.w;
        o1.x = dv * (f2.x + s2.x) + bb.x;
        o1.y = dv * (f2.y + s2.y) + bb.y;
        o1.z = dv * (f3.x + s3.x) + bb.z;
        o1.w = dv * (f3.y + s3.y) + bb.w;
        float4* op = (float4*)(out + (size_t)vA * CDIM + l * 8);
        op[0] = o0;
        op[1] = o1;
    } else if (g == 1 && vB < n) {  // epilogue node B
        float dv = dinv[vB];
        float4 sr = ((const float4*)(h2s + (size_t)vB * CDIM))[l];
        float2 f0 = __half22float2(aB0), f1 = __half22float2(aB1);
        float2 f2 = __half22float2(aB2), f3 = __half22float2(aB3);
        float2 s0 = __half22float2(*(__half2*)&sr.x), s1 = __half22float2(*(__half2*)&sr.y);
        float2 s2 = __half22float2(*(__half2*)&sr.z), s3 = __half22float2(*(__half2*)&sr.w);
        const float4* bbp = (const float4*)(b2 + l * 8);
        float4 ba = bbp[0], bb = bbp[1];
        float4 o0, o1;
        o0.x = dv * (f0.x + s0.x) + ba.x;
        o0.y = dv * (f0.y + s0.y) + ba.y;
        o0.z = dv * (f1.x + s1.x) + ba.z;
        o0.w = dv * (f1.y + s1.y) + ba.w;
        o1.x = dv * (f2.x + s2.x) + bb.x;
        o1.y = dv * (f2.y + s2.y) + bb.y;
        o1.z = dv * (f3.x + s3.x) + bb.z;
        o1.w = dv * (f3.y + s3.y) + bb.w;
        float4* op = (float4*)(out + (size_t)vB * CDIM + l * 8);
        op[0] = o0;
        op[1] = o1;
    }
}

extern "C" void kernel_launch(void* const* d_in, const int* in_sizes, int n_in,
                              void* d_out, int out_size, void* d_ws, size_t ws_size,
                              hipStream_t stream) {
    const float* x  = (const float*)d_in[0];
    const int*   ei = (const int*)d_in[1];
    const float* W1 = (const float*)d_in[2];
    const float* b1 = (const float*)d_in[3];
    const float* W2 = (const float*)d_in[4];
    const float* b2 = (const float*)d_in[5];
    float* out = (float*)d_out;

    int n = in_sizes[0] / F_IN;
    int e = in_sizes[1] / 2;
    const int* srcIdx = ei;
    const int* dstIdx = ei + e;

    int nbk = (n + BK - 1) / BK;  // 391 for n=100K (needs <= 511)

    // workspace layout (4B words) -- fp16 buffers padded with a zero row at [n]:
    //   cnt[n] | bucketCnt[512] | bucketBase[520] | bucketCursor[512] |
    //   rowptr[n] | col[e] | dinv[n] | xs(fp16 [n+1][64]) | axh(fp16 [n][64]) |
    //   h2s(fp16 [n+1][32]) | W1T | W2T ; staging(uint e) overlays axh
    int* cnt          = (int*)d_ws;
    int* bucketCnt    = cnt + n;
    int* bucketBase   = bucketCnt + 512;
    int* bucketCursor = bucketBase + 520;
    int* rowptr       = bucketCursor + 512;
    int* col          = rowptr + n;
    float* dinv       = (float*)(col + e);
    _Float16* xs      = (_Float16*)(dinv + n);                     // [n+1][64]
    _Float16* axh     = xs + (size_t)(n + 1) * F_IN;               // [n][64]
    __half* h2s       = (__half*)(axh + (size_t)n * F_IN);         // [n+1][32]
    _Float16* W1T     = (_Float16*)(h2s + (size_t)(n + 1) * CDIM); // [128][64]
    _Float16* W2T     = W1T + HDIM * F_IN;                         // [32][128]
    unsigned* staging = (unsigned*)axh;

    const int B = 256;

    hipMemsetAsync(bucketCnt, 0, 512 * sizeof(int), stream);

    // binned edge sort + fused degree/rowptr/dinv/col build (+ weight conv)
    kb_hist<<<HIST_BLOCKS + 1, B, 0, stream>>>(dstIdx, e, nbk, bucketCnt, W1, W2, W1T, W2T);
    kb_scan<<<1, 512, 0, stream>>>(bucketCnt, bucketBase, bucketCursor, nbk);
    kb_scatter<<<(e + SC_CHUNK - 1) / SC_CHUNK, B, 0, stream>>>(srcIdx, dstIdx, e, nbk,
                                                                bucketCursor, staging);
    kb_finalize<<<nbk, BK, 0, stream>>>(staging, bucketBase, rowptr, cnt, dinv, col, n);

    // layer 1
    k_prescale<<<((n + 1) * (F_IN / 4) + B - 1) / B, B, 0, stream>>>(x, dinv, (h4*)xs,
                                                                    (h4*)h2s, n);
    k_gather1<<<(n + 7) / 8, B, 0, stream>>>(xs, rowptr, cnt, col, dinv, axh, n);
    k_mlp_mfma<<<(n + 63) / 64, B, 0, stream>>>(axh, W1T, b1, W2T, dinv, h2s, n);
    k_gather2<<<(n + 7) / 8, B, 0, stream>>>((const _Float16*)h2s, rowptr, cnt, col, dinv,
                                             b2, out, n);
}

// Round 13
// 177.406 us; speedup vs baseline: 2.3596x; 1.0181x over previous
//
#include <hip/hip_runtime.h>
#include <hip/hip_fp16.h>

// GCN 2-layer forward, round 13:
//   R12 + build-tail fusion: k_prescale folded into kb_finalize (bucket-local
//   dinv already in registers; coalesced x->xs fp16 conversion per bucket);
//   zero-row padding written from kb_scan's idle threads; gather2 reworked to
//   4 nodes/wave (4 row-loads in flight, 2-level butterfly, uniform epilogue).
//   ax[v]  = dinv[v]*(sum xs[s] + xs[v]),  xs = fp16(dinv.*x)
//   h2s    = fp16(dinv .* (relu(ax@W1+b1) @ W2))   [MFMA]
//   out[v] = dinv[v]*(sum h2s[s] + h2s[v]) + b2

#define F_IN 64
#define HDIM 128
#define CDIM 32
#define BK 256          // nodes per bucket (== kb_finalize blockDim)
#define SC_CHUNK 4096   // edges per kb_scatter workgroup
#define HIST_BLOCKS 256

struct h4 { __half2 a, b; };  // 8-byte packed 4x fp16

typedef _Float16 half8 __attribute__((ext_vector_type(8)));
typedef float f32x4 __attribute__((ext_vector_type(4)));

__device__ __forceinline__ __half2 hshfl_xor(__half2 h, int d) {
    union { __half2 h2; int i; } u;
    u.h2 = h;
    u.i = __shfl_xor(u.i, d);
    return u.h2;
}

// ---------- bucket histogram (LDS only) + weight transpose/convert ----------
__global__ void kb_hist(const int* __restrict__ dst, int e, int nbk,
                        int* __restrict__ bucketCnt,
                        const float* __restrict__ W1, const float* __restrict__ W2,
                        _Float16* __restrict__ W1T, _Float16* __restrict__ W2T) {
    int tid = threadIdx.x;
    if (blockIdx.x == HIST_BLOCKS) {  // weight conversion block
        for (int i = tid; i < F_IN * HDIM + HDIM * CDIM; i += blockDim.x) {
            if (i < F_IN * HDIM) {
                int k = i >> 7, c = i & 127;
                W1T[c * F_IN + k] = (_Float16)W1[i];
            } else {
                int j = i - F_IN * HDIM;
                int k = j >> 5, c = j & 31;
                W2T[c * HDIM + k] = (_Float16)W2[j];
            }
        }
        return;
    }
    __shared__ int lh[512];
    for (int i = tid; i < nbk; i += blockDim.x) lh[i] = 0;
    __syncthreads();
    for (int i = blockIdx.x * blockDim.x + tid; i < e; i += HIST_BLOCKS * blockDim.x)
        atomicAdd(&lh[dst[i] >> 8], 1);
    __syncthreads();
    for (int i = tid; i < nbk; i += blockDim.x)
        if (lh[i]) atomicAdd(&bucketCnt[i], lh[i]);
}

// exclusive scan of bucketCnt -> bucketBase (+total at [nbk]); cursor copy;
// idle threads write the zero rows xs[n] / h2s[n]
__global__ void kb_scan(const int* __restrict__ bucketCnt, int* __restrict__ bucketBase,
                        int* __restrict__ bucketCursor, int nbk,
                        h4* __restrict__ xs, h4* __restrict__ h2s4, int n) {
    __shared__ int sh[512];
    int tid = threadIdx.x;
    // zero-row padding (independent of scan)
    if (tid >= 504) {
        h4 z; z.a = __float2half2_rn(0.f); z.b = z.a;
        int t = tid - 504;                       // 0..7
        xs[(size_t)n * 16 + t * 2]     = z;      // xs row n: 16 h4
        xs[(size_t)n * 16 + t * 2 + 1] = z;
        h2s4[(size_t)n * 8 + t] = z;             // h2s row n: 8 h4
    }
    int v = (tid < nbk) ? bucketCnt[tid] : 0;
    sh[tid] = v;
    __syncthreads();
    for (int off = 1; off < 512; off <<= 1) {
        int t = (tid >= off) ? sh[tid - off] : 0;
        __syncthreads();
        sh[tid] += t;
        __syncthreads();
    }
    if (tid < nbk) {
        bucketBase[tid] = sh[tid] - v;
        bucketCursor[tid] = sh[tid] - v;
    }
    if (tid == nbk) bucketBase[tid] = sh[511];  // total = e
}

// per-wg LDS histogram -> contiguous run reservation -> packed staging writes
__global__ void kb_scatter(const int* __restrict__ src, const int* __restrict__ dst, int e,
                           int nbk, int* __restrict__ bucketCursor,
                           unsigned* __restrict__ staging) {
    __shared__ int lh[512];
    __shared__ int lbase[512];
    int tid = threadIdx.x;
    int c0 = blockIdx.x * SC_CHUNK;
    int c1 = min(c0 + SC_CHUNK, e);
    for (int i = tid; i < nbk; i += blockDim.x) lh[i] = 0;
    __syncthreads();
    for (int i = c0 + tid; i < c1; i += blockDim.x)
        atomicAdd(&lh[dst[i] >> 8], 1);
    __syncthreads();
    for (int i = tid; i < nbk; i += blockDim.x) {
        int c = lh[i];
        lbase[i] = c ? atomicAdd(&bucketCursor[i], c) : 0;
        lh[i] = 0;  // becomes local cursor
    }
    __syncthreads();
    for (int i = c0 + tid; i < c1; i += blockDim.x) {
        int d = dst[i];
        int b = d >> 8;
        int r = atomicAdd(&lh[b], 1);
        staging[lbase[b] + r] = ((unsigned)(d & (BK - 1)) << 24) | (unsigned)src[i];
    }
}

// fused: degree count + in-bucket scan -> rowptr/cnt/dinv + counting sort
//        + bucket-local prescale x -> xs (fp16, dinv-scaled)
__global__ void kb_finalize(const unsigned* __restrict__ staging,
                            const int* __restrict__ bucketBase,
                            int* __restrict__ rowptr, int* __restrict__ cnt,
                            float* __restrict__ dinv, int* __restrict__ col,
                            const float* __restrict__ x, h4* __restrict__ xs, int n) {
    __shared__ int lc[BK];
    __shared__ int lscan[BK];
    __shared__ float dinvS[BK];
    int b = blockIdx.x;
    int tid = threadIdx.x;
    lc[tid] = 0;
    __syncthreads();
    int beg = bucketBase[b], end = bucketBase[b + 1];
    for (int i = beg + tid; i < end; i += blockDim.x)
        atomicAdd(&lc[staging[i] >> 24], 1);
    __syncthreads();
    int deg = lc[tid];
    lscan[tid] = deg;
    __syncthreads();
    for (int off = 1; off < BK; off <<= 1) {
        int t = (tid >= off) ? lscan[tid - off] : 0;
        __syncthreads();
        lscan[tid] += t;
        __syncthreads();
    }
    int rp = beg + lscan[tid] - deg;   // exclusive in-bucket prefix + bucket base
    int v = b * BK + tid;
    float dv = rsqrtf((float)(deg + 1));
    if (v < n) {
        rowptr[v] = rp;
        cnt[v] = deg;
        dinv[v] = dv;
    }
    dinvS[tid] = dv;
    lc[tid] = rp;  // becomes cursor
    __syncthreads();
    // counting sort into col
    for (int i = beg + tid; i < end; i += blockDim.x) {
        unsigned sd = staging[i];
        int pos = atomicAdd(&lc[sd >> 24], 1);
        col[pos] = (int)(sd & 0xFFFFFFu);
    }
    // bucket-local prescale: xs[v] = fp16(dinv[v] * x[v])  (coalesced)
    int v0 = b * BK;
    int rows = min(BK, n - v0);
    for (int t = tid; t < rows * 16; t += blockDim.x) {
        int row = t >> 4, q = t & 15;
        float s = dinvS[row];
        float4 val = ((const float4*)x)[(size_t)(v0 + row) * 16 + q];
        h4 o;
        o.a = __floats2half2_rn(val.x * s, val.y * s);
        o.b = __floats2half2_rn(val.z * s, val.w * s);
        xs[(size_t)(v0 + row) * 16 + q] = o;
    }
}

// ---------- gather 1: wave = 2 nodes, 8-lane groups x 16B rows, 2-deep unroll ----
__global__ void k_gather1(const _Float16* __restrict__ xs, const int* __restrict__ rowptr,
                          const int* __restrict__ cnt, const int* __restrict__ col,
                          const float* __restrict__ dinv, _Float16* __restrict__ axh, int n) {
    int tid = threadIdx.x;
    int w = tid >> 6, lane = tid & 63;
    int vA = blockIdx.x * 8 + w * 2;
    if (vA >= n) return;  // wave-uniform
    int vB = vA + 1;
    int g = lane >> 3, l = lane & 7;
    int begA = rowptr[vA], degA = cnt[vA];
    int begB = 0, degB = 0;
    if (vB < n) { begB = rowptr[vB]; degB = cnt[vB]; }
    int dmax = max(degA, degB);

    __half2 aA0 = __float2half2_rn(0.f), aA1 = aA0, aA2 = aA0, aA3 = aA0;
    __half2 aB0 = aA0, aB1 = aA0, aB2 = aA0, aB3 = aA0;

    for (int j = g; j < dmax; j += 16) {
        int jb = j + 8;
        int sA0 = (j  < degA) ? col[begA + j]  : n;
        int sA1 = (jb < degA) ? col[begA + jb] : n;
        int sB0 = (j  < degB) ? col[begB + j]  : n;
        int sB1 = (jb < degB) ? col[begB + jb] : n;
        float4 rA0 = ((const float4*)(xs + (size_t)sA0 * F_IN))[l];
        float4 rA1 = ((const float4*)(xs + (size_t)sA1 * F_IN))[l];
        float4 rB0 = ((const float4*)(xs + (size_t)sB0 * F_IN))[l];
        float4 rB1 = ((const float4*)(xs + (size_t)sB1 * F_IN))[l];
        aA0 = __hadd2(aA0, *(__half2*)&rA0.x); aA1 = __hadd2(aA1, *(__half2*)&rA0.y);
        aA2 = __hadd2(aA2, *(__half2*)&rA0.z); aA3 = __hadd2(aA3, *(__half2*)&rA0.w);
        aA0 = __hadd2(aA0, *(__half2*)&rA1.x); aA1 = __hadd2(aA1, *(__half2*)&rA1.y);
        aA2 = __hadd2(aA2, *(__half2*)&rA1.z); aA3 = __hadd2(aA3, *(__half2*)&rA1.w);
        aB0 = __hadd2(aB0, *(__half2*)&rB0.x); aB1 = __hadd2(aB1, *(__half2*)&rB0.y);
        aB2 = __hadd2(aB2, *(__half2*)&rB0.z); aB3 = __hadd2(aB3, *(__half2*)&rB0.w);
        aB0 = __hadd2(aB0, *(__half2*)&rB1.x); aB1 = __hadd2(aB1, *(__half2*)&rB1.y);
        aB2 = __hadd2(aB2, *(__half2*)&rB1.z); aB3 = __hadd2(aB3, *(__half2*)&rB1.w);
    }

    // packed butterfly across the 8 groups (xor 8, 16, 32)
#pragma unroll
    for (int d = 8; d <= 32; d <<= 1) {
        aA0 = __hadd2(aA0, hshfl_xor(aA0, d)); aA1 = __hadd2(aA1, hshfl_xor(aA1, d));
        aA2 = __hadd2(aA2, hshfl_xor(aA2, d)); aA3 = __hadd2(aA3, hshfl_xor(aA3, d));
        aB0 = __hadd2(aB0, hshfl_xor(aB0, d)); aB1 = __hadd2(aB1, hshfl_xor(aB1, d));
        aB2 = __hadd2(aB2, hshfl_xor(aB2, d)); aB3 = __hadd2(aB3, hshfl_xor(aB3, d));
    }

    if (g == 0) {  // epilogue node A
        float dv = dinv[vA];
        float4 sr = ((const float4*)(xs + (size_t)vA * F_IN))[l];
        float2 f0 = __half22float2(aA0), f1 = __half22float2(aA1);
        float2 f2 = __half22float2(aA2), f3 = __half22float2(aA3);
        float2 s0 = __half22float2(*(__half2*)&sr.x), s1 = __half22float2(*(__half2*)&sr.y);
        float2 s2 = __half22float2(*(__half2*)&sr.z), s3 = __half22float2(*(__half2*)&sr.w);
        __half2 o0 = __floats2half2_rn(dv * (f0.x + s0.x), dv * (f0.y + s0.y));
        __half2 o1 = __floats2half2_rn(dv * (f1.x + s1.x), dv * (f1.y + s1.y));
        __half2 o2 = __floats2half2_rn(dv * (f2.x + s2.x), dv * (f2.y + s2.y));
        __half2 o3 = __floats2half2_rn(dv * (f3.x + s3.x), dv * (f3.y + s3.y));
        float4 o;
        o.x = *(float*)&o0; o.y = *(float*)&o1; o.z = *(float*)&o2; o.w = *(float*)&o3;
        ((float4*)(axh + (size_t)vA * F_IN))[l] = o;
    } else if (g == 1 && vB < n) {  // epilogue node B
        float dv = dinv[vB];
        float4 sr = ((const float4*)(xs + (size_t)vB * F_IN))[l];
        float2 f0 = __half22float2(aB0), f1 = __half22float2(aB1);
        float2 f2 = __half22float2(aB2), f3 = __half22float2(aB3);
        float2 s0 = __half22float2(*(__half2*)&sr.x), s1 = __half22float2(*(__half2*)&sr.y);
        float2 s2 = __half22float2(*(__half2*)&sr.z), s3 = __half22float2(*(__half2*)&sr.w);
        __half2 o0 = __floats2half2_rn(dv * (f0.x + s0.x), dv * (f0.y + s0.y));
        __half2 o1 = __floats2half2_rn(dv * (f1.x + s1.x), dv * (f1.y + s1.y));
        __half2 o2 = __floats2half2_rn(dv * (f2.x + s2.x), dv * (f2.y + s2.y));
        __half2 o3 = __floats2half2_rn(dv * (f3.x + s3.x), dv * (f3.y + s3.y));
        float4 o;
        o.x = *(float*)&o0; o.y = *(float*)&o1; o.z = *(float*)&o2; o.w = *(float*)&o3;
        ((float4*)(axh + (size_t)vB * F_IN))[l] = o;
    }
}

// ---------- MFMA MLP: h2s = fp16(dinv .* (relu(axh@W1+b1) @ W2)) ----------
__global__ __launch_bounds__(256) void k_mlp_mfma(
    const _Float16* __restrict__ axh,   // [n][64]
    const _Float16* __restrict__ W1T,   // [128][64]
    const float* __restrict__ b1,
    const _Float16* __restrict__ W2T,   // [32][128]
    const float* __restrict__ dinv,
    __half* __restrict__ h2s, int n) {
    __shared__ float hbuf[64 * 132];
    int tid = threadIdx.x;
    int w = tid >> 6, lane = tid & 63;
    int lo = lane & 15, hi = lane >> 4;
    int m0 = blockIdx.x * 64 + w * 16;

    int arow = m0 + lo; if (arow >= n) arow = n - 1;  // clamp; garbage rows unused
    const half8* aptr = (const half8*)(axh + (size_t)arow * F_IN);
    half8 a0 = aptr[hi];      // k = hi*8
    half8 a1 = aptr[4 + hi];  // k = 32 + hi*8

    float b1v[8];
    f32x4 acc[8];
#pragma unroll
    for (int j = 0; j < 8; ++j) {
        b1v[j] = b1[j * 16 + lo];
        const half8* bptr = (const half8*)(W1T + (size_t)(j * 16 + lo) * F_IN);
        half8 bf0 = bptr[hi];
        half8 bf1 = bptr[4 + hi];
        f32x4 c = {0.f, 0.f, 0.f, 0.f};
        c = __builtin_amdgcn_mfma_f32_16x16x32_f16(a0, bf0, c, 0, 0, 0);
        c = __builtin_amdgcn_mfma_f32_16x16x32_f16(a1, bf1, c, 0, 0, 0);
        acc[j] = c;
    }

#pragma unroll
    for (int j = 0; j < 8; ++j) {
#pragma unroll
        for (int r = 0; r < 4; ++r) {
            int R = w * 16 + hi * 4 + r;
            float hv = acc[j][r] + b1v[j];
            hbuf[R * 132 + j * 16 + lo] = hv > 0.f ? hv : 0.f;
        }
    }

    f32x4 acc2[2] = {{0.f, 0.f, 0.f, 0.f}, {0.f, 0.f, 0.f, 0.f}};
#pragma unroll
    for (int ks = 0; ks < 4; ++ks) {
        const float* hp = &hbuf[(w * 16 + lo) * 132 + ks * 32 + hi * 8];
        half8 a;
#pragma unroll
        for (int r = 0; r < 8; ++r) a[r] = (_Float16)hp[r];
#pragma unroll
        for (int t = 0; t < 2; ++t) {
            const half8* b2p = (const half8*)(W2T + (size_t)(t * 16 + lo) * HDIM);
            acc2[t] = __builtin_amdgcn_mfma_f32_16x16x32_f16(a, b2p[ks * 4 + hi], acc2[t], 0, 0, 0);
        }
    }

#pragma unroll
    for (int r = 0; r < 4; ++r) {
        int R = m0 + hi * 4 + r;
        if (R < n) {
            float dv = dinv[R];
            h2s[(size_t)R * CDIM + lo]      = __float2half(dv * acc2[0][r]);
            h2s[(size_t)R * CDIM + 16 + lo] = __float2half(dv * acc2[1][r]);
        }
    }
}

// ---------- gather 2: wave = 4 nodes (16-lane slots), 4-lane groups x 16B rows ----
__global__ void k_gather2(const _Float16* __restrict__ h2s, const int* __restrict__ rowptr,
                          const int* __restrict__ cnt, const int* __restrict__ col,
                          const float* __restrict__ dinv, const float* __restrict__ b2,
                          float* __restrict__ out, int n) {
    int tid = threadIdx.x;
    int w = tid >> 6, lane = tid & 63;
    int v0w = blockIdx.x * 16 + w * 4;   // first node of this wave
    if (v0w >= n) return;                // wave-uniform
    int slot = lane >> 4;
    int v = v0w + slot;
    bool valid = v < n;
    int g = (lane >> 2) & 3, l = lane & 3;
    int beg = valid ? rowptr[v] : 0;
    int deg = valid ? cnt[v] : 0;

    __half2 a0 = __float2half2_rn(0.f), a1 = a0, a2 = a0, a3 = a0;
    for (int j = g; j < deg; j += 4) {
        int s = col[beg + j];
        float4 r = ((const float4*)(h2s + (size_t)s * CDIM))[l];
        a0 = __hadd2(a0, *(__half2*)&r.x); a1 = __hadd2(a1, *(__half2*)&r.y);
        a2 = __hadd2(a2, *(__half2*)&r.z); a3 = __hadd2(a3, *(__half2*)&r.w);
    }

    // packed butterfly across the 4 groups within the slot (xor 4, 8)
#pragma unroll
    for (int d = 4; d <= 8; d <<= 1) {
        a0 = __hadd2(a0, hshfl_xor(a0, d)); a1 = __hadd2(a1, hshfl_xor(a1, d));
        a2 = __hadd2(a2, hshfl_xor(a2, d)); a3 = __hadd2(a3, hshfl_xor(a3, d));
    }

    if (g == 0 && valid) {
        float dv = dinv[v];
        float4 sr = ((const float4*)(h2s + (size_t)v * CDIM))[l];
        float2 f0 = __half22float2(a0), f1 = __half22float2(a1);
        float2 f2 = __half22float2(a2), f3 = __half22float2(a3);
        float2 s0 = __half22float2(*(__half2*)&sr.x), s1 = __half22float2(*(__half2*)&sr.y);
        float2 s2 = __half22float2(*(__half2*)&sr.z), s3 = __half22float2(*(__half2*)&sr.w);
        const float4* bbp = (const float4*)(b2 + l * 8);
        float4 ba = bbp[0], bb = bbp[1];
        float4 o0, o1;
        o0.x = dv * (f0.x + s0.x) + ba.x;
        o0.y = dv * (f0.y + s0.y) + ba.y;
        o0.z = dv * (f1.x + s1.x) + ba.z;
        o0.w = dv * (f1.y + s1.y) + ba.w;
        o1.x = dv * (f2.x + s2.x) + bb.x;
        o1.y = dv * (f2.y + s2.y) + bb.y;
        o1.z = dv * (f3.x + s3.x) + bb.z;
        o1.w = dv * (f3.y + s3.y) + bb.w;
        float4* op = (float4*)(out + (size_t)v * CDIM + l * 8);
        op[0] = o0;
        op[1] = o1;
    }
}

extern "C" void kernel_launch(void* const* d_in, const int* in_sizes, int n_in,
                              void* d_out, int out_size, void* d_ws, size_t ws_size,
                              hipStream_t stream) {
    const float* x  = (const float*)d_in[0];
    const int*   ei = (const int*)d_in[1];
    const float* W1 = (const float*)d_in[2];
    const float* b1 = (const float*)d_in[3];
    const float* W2 = (const float*)d_in[4];
    const float* b2 = (const float*)d_in[5];
    float* out = (float*)d_out;

    int n = in_sizes[0] / F_IN;
    int e = in_sizes[1] / 2;
    const int* srcIdx = ei;
    const int* dstIdx = ei + e;

    int nbk = (n + BK - 1) / BK;  // 391 for n=100K (needs <= 511)

    // workspace layout (4B words) -- fp16 buffers padded with a zero row at [n]:
    //   cnt[n] | bucketCnt[512] | bucketBase[520] | bucketCursor[512] |
    //   rowptr[n] | col[e] | dinv[n] | xs(fp16 [n+1][64]) | axh(fp16 [n][64]) |
    //   h2s(fp16 [n+1][32]) | W1T | W2T ; staging(uint e) overlays axh
    int* cnt          = (int*)d_ws;
    int* bucketCnt    = cnt + n;
    int* bucketBase   = bucketCnt + 512;
    int* bucketCursor = bucketBase + 520;
    int* rowptr       = bucketCursor + 512;
    int* col          = rowptr + n;
    float* dinv       = (float*)(col + e);
    _Float16* xs      = (_Float16*)(dinv + n);                     // [n+1][64]
    _Float16* axh     = xs + (size_t)(n + 1) * F_IN;               // [n][64]
    __half* h2s       = (__half*)(axh + (size_t)n * F_IN);         // [n+1][32]
    _Float16* W1T     = (_Float16*)(h2s + (size_t)(n + 1) * CDIM); // [128][64]
    _Float16* W2T     = W1T + HDIM * F_IN;                         // [32][128]
    unsigned* staging = (unsigned*)axh;

    const int B = 256;

    hipMemsetAsync(bucketCnt, 0, 512 * sizeof(int), stream);

    // binned edge sort + fused degree/rowptr/dinv/col/prescale build (+ weight conv)
    kb_hist<<<HIST_BLOCKS + 1, B, 0, stream>>>(dstIdx, e, nbk, bucketCnt, W1, W2, W1T, W2T);
    kb_scan<<<1, 512, 0, stream>>>(bucketCnt, bucketBase, bucketCursor, nbk,
                                   (h4*)xs, (h4*)h2s, n);
    kb_scatter<<<(e + SC_CHUNK - 1) / SC_CHUNK, B, 0, stream>>>(srcIdx, dstIdx, e, nbk,
                                                                bucketCursor, staging);
    kb_finalize<<<nbk, BK, 0, stream>>>(staging, bucketBase, rowptr, cnt, dinv, col,
                                        x, (h4*)xs, n);

    // layer 1 + transform + layer 2
    k_gather1<<<(n + 7) / 8, B, 0, stream>>>(xs, rowptr, cnt, col, dinv, axh, n);
    k_mlp_mfma<<<(n + 63) / 64, B, 0, stream>>>(axh, W1T, b1, W2T, dinv, h2s, n);
    k_gather2<<<(n + 15) / 16, B, 0, stream>>>((const _Float16*)h2s, rowptr, cnt, col, dinv,
                                               b2, out, n);
}

// Round 14
// 155.585 us; speedup vs baseline: 2.6905x; 1.1402x over previous
//
#include <hip/hip_runtime.h>
#include <hip/hip_fp16.h>

// GCN 2-layer forward, round 14:
//   R13 + (a) fixed-capacity buckets (CAP=6144 >> mean 4090, 32-sigma margin):
//   staging/col bucket-padded at b*CAP -> kb_hist/kb_scan deleted; scatter
//   caches dst chunk in LDS; (b) gather1+MLP fused per-wave (axs/hbuf16 in
//   wave-private LDS, no barriers) -> axh round-trip deleted; (c) gather2 with
//   2-deep load pipeline.
//   ax[v]  = dinv[v]*(sum xs[s] + xs[v]),  xs = fp16(dinv.*x)
//   h2s    = fp16(dinv .* (relu(ax@W1+b1) @ W2))   [MFMA]
//   out[v] = dinv[v]*(sum h2s[s] + h2s[v]) + b2

#define F_IN 64
#define HDIM 128
#define CDIM 32
#define BK 256          // nodes per bucket (== kb_finalize blockDim)
#define BCAP 6144       // edge capacity per bucket (mean 4090 @ n=100K,E=1.6M)
#define SC_CHUNK 2048   // edges per kb_scatter workgroup

struct h4 { __half2 a, b; };  // 8-byte packed 4x fp16

typedef _Float16 half8 __attribute__((ext_vector_type(8)));
typedef float f32x4 __attribute__((ext_vector_type(4)));

__device__ __forceinline__ __half2 hshfl_xor(__half2 h, int d) {
    union { __half2 h2; int i; } u;
    u.h2 = h;
    u.i = __shfl_xor(u.i, d);
    return u.h2;
}

// ---------- scatter: LDS hist -> cursor reservation -> packed staging ----------
// extra block (blockIdx == nchunks): weight conversion + zero-row padding
__global__ void kb_scatter(const int* __restrict__ src, const int* __restrict__ dst,
                           int e, int nbk, int nchunks, int* __restrict__ bucketCursor,
                           unsigned* __restrict__ staging,
                           const float* __restrict__ W1, const float* __restrict__ W2,
                           _Float16* __restrict__ W1T, _Float16* __restrict__ W2T,
                           h4* __restrict__ xs, h4* __restrict__ h2s4, int n) {
    int tid = threadIdx.x;
    if (blockIdx.x == nchunks) {  // aux block
        for (int i = tid; i < F_IN * HDIM + HDIM * CDIM; i += blockDim.x) {
            if (i < F_IN * HDIM) {
                int k = i >> 7, c = i & 127;
                W1T[c * F_IN + k] = (_Float16)W1[i];
            } else {
                int j = i - F_IN * HDIM;
                int k = j >> 5, c = j & 31;
                W2T[c * HDIM + k] = (_Float16)W2[j];
            }
        }
        h4 z; z.a = __float2half2_rn(0.f); z.b = z.a;
        if (tid < 16) xs[(size_t)n * 16 + tid] = z;          // zero row xs[n]
        else if (tid < 24) h2s4[(size_t)n * 8 + (tid - 16)] = z;  // zero row h2s[n]
        return;
    }
    __shared__ int lh[512];
    __shared__ int lbase[512];
    __shared__ int dstS[SC_CHUNK];
    int c0 = blockIdx.x * SC_CHUNK;
    int m = min(SC_CHUNK, e - c0);
    for (int i = tid; i < nbk; i += blockDim.x) lh[i] = 0;
    __syncthreads();
    for (int i = tid; i < m; i += blockDim.x) {
        int d = dst[c0 + i];
        dstS[i] = d;
        atomicAdd(&lh[d >> 8], 1);
    }
    __syncthreads();
    for (int i = tid; i < nbk; i += blockDim.x) {
        int c = lh[i];
        lbase[i] = c ? atomicAdd(&bucketCursor[i], c) : 0;
        lh[i] = 0;  // becomes local cursor
    }
    __syncthreads();
    for (int i = tid; i < m; i += blockDim.x) {
        int d = dstS[i];
        int b = d >> 8;
        int r = atomicAdd(&lh[b], 1);
        staging[(size_t)b * BCAP + lbase[b] + r] =
            ((unsigned)(d & (BK - 1)) << 24) | (unsigned)src[c0 + i];
    }
}

// fused: degree count + in-bucket scan -> rowptr/cnt/dinv + counting sort
//        + bucket-local prescale x -> xs (fp16, dinv-scaled)
__global__ void kb_finalize(const unsigned* __restrict__ staging,
                            const int* __restrict__ bucketCursor,
                            int* __restrict__ rowptr, int* __restrict__ cnt,
                            float* __restrict__ dinv, int* __restrict__ col,
                            const float* __restrict__ x, h4* __restrict__ xs, int n) {
    __shared__ int lc[BK];
    __shared__ int lscan[BK];
    __shared__ float dinvS[BK];
    int b = blockIdx.x;
    int tid = threadIdx.x;
    lc[tid] = 0;
    __syncthreads();
    int beg = b * BCAP;
    int end = beg + bucketCursor[b];
    for (int i = beg + tid; i < end; i += blockDim.x)
        atomicAdd(&lc[staging[i] >> 24], 1);
    __syncthreads();
    int deg = lc[tid];
    lscan[tid] = deg;
    __syncthreads();
    for (int off = 1; off < BK; off <<= 1) {
        int t = (tid >= off) ? lscan[tid - off] : 0;
        __syncthreads();
        lscan[tid] += t;
        __syncthreads();
    }
    int rp = beg + lscan[tid] - deg;   // bucket-padded CSR offset
    int v = b * BK + tid;
    float dv = rsqrtf((float)(deg + 1));
    if (v < n) {
        rowptr[v] = rp;
        cnt[v] = deg;
        dinv[v] = dv;
    }
    dinvS[tid] = dv;
    lc[tid] = rp;  // becomes cursor
    __syncthreads();
    for (int i = beg + tid; i < end; i += blockDim.x) {
        unsigned sd = staging[i];
        int pos = atomicAdd(&lc[sd >> 24], 1);
        col[pos] = (int)(sd & 0xFFFFFFu);
    }
    // bucket-local prescale: xs[v] = fp16(dinv[v] * x[v])  (coalesced)
    int v0 = b * BK;
    int rows = min(BK, n - v0);
    for (int t = tid; t < rows * 16; t += blockDim.x) {
        int row = t >> 4, q = t & 15;
        float s = dinvS[row];
        float4 val = ((const float4*)x)[(size_t)(v0 + row) * 16 + q];
        h4 o;
        o.a = __floats2half2_rn(val.x * s, val.y * s);
        o.b = __floats2half2_rn(val.z * s, val.w * s);
        xs[(size_t)(v0 + row) * 16 + q] = o;
    }
}

// ---------- fused gather1 + MFMA MLP ----------
// block = 256 = 4 waves; wave owns 16 nodes: gathers them in 8 two-node steps
// into wave-private LDS axs[16][72] (fp16, 2-way-free banks), then
// layer1 MFMA -> hbuf16 (fp16, wave-private rows) -> layer2 MFMA -> h2s.
// No __syncthreads: all LDS regions are wave-private.
__global__ __launch_bounds__(256) void k_fused(
    const _Float16* __restrict__ xs, const int* __restrict__ rowptr,
    const int* __restrict__ cnt, const int* __restrict__ col,
    const float* __restrict__ dinv, const _Float16* __restrict__ W1T,
    const float* __restrict__ b1, const _Float16* __restrict__ W2T,
    __half* __restrict__ h2s, int n) {
    __shared__ _Float16 axs[4][16][72];     // [wave][row][64+8 pad]
    __shared__ _Float16 hbuf[4][16][136];   // [wave][row][128+8 pad]
    int tid = threadIdx.x;
    int w = tid >> 6, lane = tid & 63;
    int m0 = blockIdx.x * 64 + w * 16;
    if (m0 >= n) return;  // wave-uniform; no barriers in this kernel
    int g = lane >> 3, l = lane & 7;
    int lo = lane & 15, hi = lane >> 4;

    // ---- gather phase: 8 pairs ----
    for (int p = 0; p < 8; ++p) {
        int vA = m0 + 2 * p, vB = vA + 1;
        int begA = 0, degA = 0, begB = 0, degB = 0;
        if (vA < n) { begA = rowptr[vA]; degA = cnt[vA]; }
        if (vB < n) { begB = rowptr[vB]; degB = cnt[vB]; }
        int dmax = max(degA, degB);

        __half2 aA0 = __float2half2_rn(0.f), aA1 = aA0, aA2 = aA0, aA3 = aA0;
        __half2 aB0 = aA0, aB1 = aA0, aB2 = aA0, aB3 = aA0;

        for (int j = g; j < dmax; j += 16) {
            int jb = j + 8;
            int sA0 = (j  < degA) ? col[begA + j]  : n;
            int sA1 = (jb < degA) ? col[begA + jb] : n;
            int sB0 = (j  < degB) ? col[begB + j]  : n;
            int sB1 = (jb < degB) ? col[begB + jb] : n;
            float4 rA0 = ((const float4*)(xs + (size_t)sA0 * F_IN))[l];
            float4 rA1 = ((const float4*)(xs + (size_t)sA1 * F_IN))[l];
            float4 rB0 = ((const float4*)(xs + (size_t)sB0 * F_IN))[l];
            float4 rB1 = ((const float4*)(xs + (size_t)sB1 * F_IN))[l];
            aA0 = __hadd2(aA0, *(__half2*)&rA0.x); aA1 = __hadd2(aA1, *(__half2*)&rA0.y);
            aA2 = __hadd2(aA2, *(__half2*)&rA0.z); aA3 = __hadd2(aA3, *(__half2*)&rA0.w);
            aA0 = __hadd2(aA0, *(__half2*)&rA1.x); aA1 = __hadd2(aA1, *(__half2*)&rA1.y);
            aA2 = __hadd2(aA2, *(__half2*)&rA1.z); aA3 = __hadd2(aA3, *(__half2*)&rA1.w);
            aB0 = __hadd2(aB0, *(__half2*)&rB0.x); aB1 = __hadd2(aB1, *(__half2*)&rB0.y);
            aB2 = __hadd2(aB2, *(__half2*)&rB0.z); aB3 = __hadd2(aB3, *(__half2*)&rB0.w);
            aB0 = __hadd2(aB0, *(__half2*)&rB1.x); aB1 = __hadd2(aB1, *(__half2*)&rB1.y);
            aB2 = __hadd2(aB2, *(__half2*)&rB1.z); aB3 = __hadd2(aB3, *(__half2*)&rB1.w);
        }

#pragma unroll
        for (int d = 8; d <= 32; d <<= 1) {
            aA0 = __hadd2(aA0, hshfl_xor(aA0, d)); aA1 = __hadd2(aA1, hshfl_xor(aA1, d));
            aA2 = __hadd2(aA2, hshfl_xor(aA2, d)); aA3 = __hadd2(aA3, hshfl_xor(aA3, d));
            aB0 = __hadd2(aB0, hshfl_xor(aB0, d)); aB1 = __hadd2(aB1, hshfl_xor(aB1, d));
            aB2 = __hadd2(aB2, hshfl_xor(aB2, d)); aB3 = __hadd2(aB3, hshfl_xor(aB3, d));
        }

        if (g == 0 && vA < n) {  // row 2p of this wave's tile
            float dv = dinv[vA];
            float4 sr = ((const float4*)(xs + (size_t)vA * F_IN))[l];
            float2 f0 = __half22float2(aA0), f1 = __half22float2(aA1);
            float2 f2 = __half22float2(aA2), f3 = __half22float2(aA3);
            float2 s0 = __half22float2(*(__half2*)&sr.x), s1 = __half22float2(*(__half2*)&sr.y);
            float2 s2 = __half22float2(*(__half2*)&sr.z), s3 = __half22float2(*(__half2*)&sr.w);
            __half2 o0 = __floats2half2_rn(dv * (f0.x + s0.x), dv * (f0.y + s0.y));
            __half2 o1 = __floats2half2_rn(dv * (f1.x + s1.x), dv * (f1.y + s1.y));
            __half2 o2 = __floats2half2_rn(dv * (f2.x + s2.x), dv * (f2.y + s2.y));
            __half2 o3 = __floats2half2_rn(dv * (f3.x + s3.x), dv * (f3.y + s3.y));
            float4 o;
            o.x = *(float*)&o0; o.y = *(float*)&o1; o.z = *(float*)&o2; o.w = *(float*)&o3;
            *(float4*)&axs[w][2 * p][l * 8] = o;
        } else if (g == 1 && vB < n) {  // row 2p+1
            float dv = dinv[vB];
            float4 sr = ((const float4*)(xs + (size_t)vB * F_IN))[l];
            float2 f0 = __half22float2(aB0), f1 = __half22float2(aB1);
            float2 f2 = __half22float2(aB2), f3 = __half22float2(aB3);
            float2 s0 = __half22float2(*(__half2*)&sr.x), s1 = __half22float2(*(__half2*)&sr.y);
            float2 s2 = __half22float2(*(__half2*)&sr.z), s3 = __half22float2(*(__half2*)&sr.w);
            __half2 o0 = __floats2half2_rn(dv * (f0.x + s0.x), dv * (f0.y + s0.y));
            __half2 o1 = __floats2half2_rn(dv * (f1.x + s1.x), dv * (f1.y + s1.y));
            __half2 o2 = __floats2half2_rn(dv * (f2.x + s2.x), dv * (f2.y + s2.y));
            __half2 o3 = __floats2half2_rn(dv * (f3.x + s3.x), dv * (f3.y + s3.y));
            float4 o;
            o.x = *(float*)&o0; o.y = *(float*)&o1; o.z = *(float*)&o2; o.w = *(float*)&o3;
            *(float4*)&axs[w][2 * p + 1][l * 8] = o;
        }
    }

    // ---- layer 1 MFMA: A from axs (wave-private LDS) ----
    half8 a0 = *(half8*)&axs[w][lo][hi * 8];
    half8 a1 = *(half8*)&axs[w][lo][32 + hi * 8];

    float b1v[8];
    f32x4 acc[8];
#pragma unroll
    for (int j = 0; j < 8; ++j) {
        b1v[j] = b1[j * 16 + lo];
        const half8* bptr = (const half8*)(W1T + (size_t)(j * 16 + lo) * F_IN);
        half8 bf0 = bptr[hi];
        half8 bf1 = bptr[4 + hi];
        f32x4 c = {0.f, 0.f, 0.f, 0.f};
        c = __builtin_amdgcn_mfma_f32_16x16x32_f16(a0, bf0, c, 0, 0, 0);
        c = __builtin_amdgcn_mfma_f32_16x16x32_f16(a1, bf1, c, 0, 0, 0);
        acc[j] = c;
    }

    // epilogue 1: bias + relu -> hbuf16 (wave-private rows)
#pragma unroll
    for (int j = 0; j < 8; ++j) {
#pragma unroll
        for (int r = 0; r < 4; ++r) {
            float hv = acc[j][r] + b1v[j];
            hbuf[w][hi * 4 + r][j * 16 + lo] = (_Float16)(hv > 0.f ? hv : 0.f);
        }
    }

    // ---- layer 2 MFMA: A from hbuf16 ----
    f32x4 acc2[2] = {{0.f, 0.f, 0.f, 0.f}, {0.f, 0.f, 0.f, 0.f}};
#pragma unroll
    for (int ks = 0; ks < 4; ++ks) {
        half8 a = *(half8*)&hbuf[w][lo][ks * 32 + hi * 8];
#pragma unroll
        for (int t = 0; t < 2; ++t) {
            const half8* b2p = (const half8*)(W2T + (size_t)(t * 16 + lo) * HDIM);
            acc2[t] = __builtin_amdgcn_mfma_f32_16x16x32_f16(a, b2p[ks * 4 + hi], acc2[t], 0, 0, 0);
        }
    }

#pragma unroll
    for (int r = 0; r < 4; ++r) {
        int R = m0 + hi * 4 + r;
        if (R < n) {
            float dv = dinv[R];
            h2s[(size_t)R * CDIM + lo]      = __float2half(dv * acc2[0][r]);
            h2s[(size_t)R * CDIM + 16 + lo] = __float2half(dv * acc2[1][r]);
        }
    }
}

// ---------- gather 2: wave = 4 nodes (16-lane slots), 4-lane groups, 2-deep ----
__global__ void k_gather2(const _Float16* __restrict__ h2s, const int* __restrict__ rowptr,
                          const int* __restrict__ cnt, const int* __restrict__ col,
                          const float* __restrict__ dinv, const float* __restrict__ b2,
                          float* __restrict__ out, int n) {
    int tid = threadIdx.x;
    int w = tid >> 6, lane = tid & 63;
    int v0w = blockIdx.x * 16 + w * 4;   // first node of this wave
    if (v0w >= n) return;                // wave-uniform
    int slot = lane >> 4;
    int v = v0w + slot;
    bool valid = v < n;
    int g = (lane >> 2) & 3, l = lane & 3;
    int beg = valid ? rowptr[v] : 0;
    int deg = valid ? cnt[v] : 0;

    __half2 a0 = __float2half2_rn(0.f), a1 = a0, a2 = a0, a3 = a0;
    __half2 c0 = a0, c1 = a0, c2 = a0, c3 = a0;
    for (int j = g; j < deg; j += 8) {
        int s0 = col[beg + j];
        int j2 = j + 4;
        int s1 = (j2 < deg) ? col[beg + j2] : n;
        float4 r0 = ((const float4*)(h2s + (size_t)s0 * CDIM))[l];
        float4 r1 = ((const float4*)(h2s + (size_t)s1 * CDIM))[l];
        a0 = __hadd2(a0, *(__half2*)&r0.x); a1 = __hadd2(a1, *(__half2*)&r0.y);
        a2 = __hadd2(a2, *(__half2*)&r0.z); a3 = __hadd2(a3, *(__half2*)&r0.w);
        c0 = __hadd2(c0, *(__half2*)&r1.x); c1 = __hadd2(c1, *(__half2*)&r1.y);
        c2 = __hadd2(c2, *(__half2*)&r1.z); c3 = __hadd2(c3, *(__half2*)&r1.w);
    }
    a0 = __hadd2(a0, c0); a1 = __hadd2(a1, c1);
    a2 = __hadd2(a2, c2); a3 = __hadd2(a3, c3);

    // packed butterfly across the 4 groups within the slot (xor 4, 8)
#pragma unroll
    for (int d = 4; d <= 8; d <<= 1) {
        a0 = __hadd2(a0, hshfl_xor(a0, d)); a1 = __hadd2(a1, hshfl_xor(a1, d));
        a2 = __hadd2(a2, hshfl_xor(a2, d)); a3 = __hadd2(a3, hshfl_xor(a3, d));
    }

    if (g == 0 && valid) {
        float dv = dinv[v];
        float4 sr = ((const float4*)(h2s + (size_t)v * CDIM))[l];
        float2 f0 = __half22float2(a0), f1 = __half22float2(a1);
        float2 f2 = __half22float2(a2), f3 = __half22float2(a3);
        float2 s0 = __half22float2(*(__half2*)&sr.x), s1 = __half22float2(*(__half2*)&sr.y);
        float2 s2 = __half22float2(*(__half2*)&sr.z), s3 = __half22float2(*(__half2*)&sr.w);
        const float4* bbp = (const float4*)(b2 + l * 8);
        float4 ba = bbp[0], bb = bbp[1];
        float4 o0, o1;
        o0.x = dv * (f0.x + s0.x) + ba.x;
        o0.y = dv * (f0.y + s0.y) + ba.y;
        o0.z = dv * (f1.x + s1.x) + ba.z;
        o0.w = dv * (f1.y + s1.y) + ba.w;
        o1.x = dv * (f2.x + s2.x) + bb.x;
        o1.y = dv * (f2.y + s2.y) + bb.y;
        o1.z = dv * (f3.x + s3.x) + bb.z;
        o1.w = dv * (f3.y + s3.y) + bb.w;
        float4* op = (float4*)(out + (size_t)v * CDIM + l * 8);
        op[0] = o0;
        op[1] = o1;
    }
}

extern "C" void kernel_launch(void* const* d_in, const int* in_sizes, int n_in,
                              void* d_out, int out_size, void* d_ws, size_t ws_size,
                              hipStream_t stream) {
    const float* x  = (const float*)d_in[0];
    const int*   ei = (const int*)d_in[1];
    const float* W1 = (const float*)d_in[2];
    const float* b1 = (const float*)d_in[3];
    const float* W2 = (const float*)d_in[4];
    const float* b2 = (const float*)d_in[5];
    float* out = (float*)d_out;

    int n = in_sizes[0] / F_IN;
    int e = in_sizes[1] / 2;
    const int* srcIdx = ei;
    const int* dstIdx = ei + e;

    int nbk = (n + BK - 1) / BK;  // 391 for n=100K (needs <= 511)
    int nchunks = (e + SC_CHUNK - 1) / SC_CHUNK;

    // workspace layout (4B words):
    //   cnt[n] | bucketCursor[512] | rowptr[n] | col[nbk*BCAP] | dinv[n] |
    //   xs(fp16 [n+1][64]) | h2s(fp16 [n+1][32]) | W1T | W2T | staging[nbk*BCAP]
    int* cnt          = (int*)d_ws;
    int* bucketCursor = cnt + n;
    int* rowptr       = bucketCursor + 512;
    int* col          = rowptr + n;
    float* dinv       = (float*)(col + (size_t)nbk * BCAP);
    _Float16* xs      = (_Float16*)(dinv + n);                     // [n+1][64]
    __half* h2s       = (__half*)(xs + (size_t)(n + 1) * F_IN);    // [n+1][32]
    _Float16* W1T     = (_Float16*)(h2s + (size_t)(n + 1) * CDIM); // [128][64]
    _Float16* W2T     = W1T + HDIM * F_IN;                         // [32][128]
    unsigned* staging = (unsigned*)(W2T + CDIM * HDIM);            // nbk*BCAP

    const int B = 256;

    hipMemsetAsync(bucketCursor, 0, 512 * sizeof(int), stream);

    // build: scatter (fixed-capacity buckets, + wconv/zero-row aux block) -> finalize
    kb_scatter<<<nchunks + 1, B, 0, stream>>>(srcIdx, dstIdx, e, nbk, nchunks,
                                              bucketCursor, staging, W1, W2, W1T, W2T,
                                              (h4*)xs, (h4*)h2s, n);
    kb_finalize<<<nbk, BK, 0, stream>>>(staging, bucketCursor, rowptr, cnt, dinv, col,
                                        x, (h4*)xs, n);

    // fused layer1 gather + MLP (MFMA) ; then layer2 gather
    k_fused<<<(n + 63) / 64, B, 0, stream>>>(xs, rowptr, cnt, col, dinv, W1T, b1, W2T,
                                             h2s, n);
    k_gather2<<<(n + 15) / 16, B, 0, stream>>>((const _Float16*)h2s, rowptr, cnt, col,
                                               dinv, b2, out, n);
}

// Round 15
// 141.293 us; speedup vs baseline: 2.9626x; 1.1012x over previous
//
#include <hip/hip_runtime.h>
#include <hip/hip_fp16.h>

// GCN 2-layer forward, round 15:
//   R14 + k_fused fixes: (a) axs/hbuf overlaid in one wave-private LDS arena
//   (26.6KB -> 17.5KB => 8 blocks/CU); (b) gather processes node QUADS with
//   2-deep loads (8 row-loads in flight per lane, 2x R14).
//   ax[v]  = dinv[v]*(sum xs[s] + xs[v]),  xs = fp16(dinv.*x)
//   h2s    = fp16(dinv .* (relu(ax@W1+b1) @ W2))   [MFMA]
//   out[v] = dinv[v]*(sum h2s[s] + h2s[v]) + b2

#define F_IN 64
#define HDIM 128
#define CDIM 32
#define BK 256          // nodes per bucket (== kb_finalize blockDim)
#define BCAP 6144       // edge capacity per bucket (mean 4090 @ n=100K,E=1.6M)
#define SC_CHUNK 2048   // edges per kb_scatter workgroup

struct h4 { __half2 a, b; };  // 8-byte packed 4x fp16

typedef _Float16 half8 __attribute__((ext_vector_type(8)));
typedef float f32x4 __attribute__((ext_vector_type(4)));

__device__ __forceinline__ __half2 hshfl_xor(__half2 h, int d) {
    union { __half2 h2; int i; } u;
    u.h2 = h;
    u.i = __shfl_xor(u.i, d);
    return u.h2;
}

// ---------- scatter: LDS hist -> cursor reservation -> packed staging ----------
// extra block (blockIdx == nchunks): weight conversion + zero-row padding
__global__ void kb_scatter(const int* __restrict__ src, const int* __restrict__ dst,
                           int e, int nbk, int nchunks, int* __restrict__ bucketCursor,
                           unsigned* __restrict__ staging,
                           const float* __restrict__ W1, const float* __restrict__ W2,
                           _Float16* __restrict__ W1T, _Float16* __restrict__ W2T,
                           h4* __restrict__ xs, h4* __restrict__ h2s4, int n) {
    int tid = threadIdx.x;
    if (blockIdx.x == nchunks) {  // aux block
        for (int i = tid; i < F_IN * HDIM + HDIM * CDIM; i += blockDim.x) {
            if (i < F_IN * HDIM) {
                int k = i >> 7, c = i & 127;
                W1T[c * F_IN + k] = (_Float16)W1[i];
            } else {
                int j = i - F_IN * HDIM;
                int k = j >> 5, c = j & 31;
                W2T[c * HDIM + k] = (_Float16)W2[j];
            }
        }
        h4 z; z.a = __float2half2_rn(0.f); z.b = z.a;
        if (tid < 16) xs[(size_t)n * 16 + tid] = z;               // zero row xs[n]
        else if (tid < 24) h2s4[(size_t)n * 8 + (tid - 16)] = z;  // zero row h2s[n]
        return;
    }
    __shared__ int lh[512];
    __shared__ int lbase[512];
    __shared__ int dstS[SC_CHUNK];
    int c0 = blockIdx.x * SC_CHUNK;
    int m = min(SC_CHUNK, e - c0);
    for (int i = tid; i < nbk; i += blockDim.x) lh[i] = 0;
    __syncthreads();
    for (int i = tid; i < m; i += blockDim.x) {
        int d = dst[c0 + i];
        dstS[i] = d;
        atomicAdd(&lh[d >> 8], 1);
    }
    __syncthreads();
    for (int i = tid; i < nbk; i += blockDim.x) {
        int c = lh[i];
        lbase[i] = c ? atomicAdd(&bucketCursor[i], c) : 0;
        lh[i] = 0;  // becomes local cursor
    }
    __syncthreads();
    for (int i = tid; i < m; i += blockDim.x) {
        int d = dstS[i];
        int b = d >> 8;
        int r = atomicAdd(&lh[b], 1);
        staging[(size_t)b * BCAP + lbase[b] + r] =
            ((unsigned)(d & (BK - 1)) << 24) | (unsigned)src[c0 + i];
    }
}

// fused: degree count + in-bucket scan -> rowptr/cnt/dinv + counting sort
//        + bucket-local prescale x -> xs (fp16, dinv-scaled)
__global__ void kb_finalize(const unsigned* __restrict__ staging,
                            const int* __restrict__ bucketCursor,
                            int* __restrict__ rowptr, int* __restrict__ cnt,
                            float* __restrict__ dinv, int* __restrict__ col,
                            const float* __restrict__ x, h4* __restrict__ xs, int n) {
    __shared__ int lc[BK];
    __shared__ int lscan[BK];
    __shared__ float dinvS[BK];
    int b = blockIdx.x;
    int tid = threadIdx.x;
    lc[tid] = 0;
    __syncthreads();
    int beg = b * BCAP;
    int end = beg + bucketCursor[b];
    for (int i = beg + tid; i < end; i += blockDim.x)
        atomicAdd(&lc[staging[i] >> 24], 1);
    __syncthreads();
    int deg = lc[tid];
    lscan[tid] = deg;
    __syncthreads();
    for (int off = 1; off < BK; off <<= 1) {
        int t = (tid >= off) ? lscan[tid - off] : 0;
        __syncthreads();
        lscan[tid] += t;
        __syncthreads();
    }
    int rp = beg + lscan[tid] - deg;   // bucket-padded CSR offset
    int v = b * BK + tid;
    float dv = rsqrtf((float)(deg + 1));
    if (v < n) {
        rowptr[v] = rp;
        cnt[v] = deg;
        dinv[v] = dv;
    }
    dinvS[tid] = dv;
    lc[tid] = rp;  // becomes cursor
    __syncthreads();
    for (int i = beg + tid; i < end; i += blockDim.x) {
        unsigned sd = staging[i];
        int pos = atomicAdd(&lc[sd >> 24], 1);
        col[pos] = (int)(sd & 0xFFFFFFu);
    }
    // bucket-local prescale: xs[v] = fp16(dinv[v] * x[v])  (coalesced)
    int v0 = b * BK;
    int rows = min(BK, n - v0);
    for (int t = tid; t < rows * 16; t += blockDim.x) {
        int row = t >> 4, q = t & 15;
        float s = dinvS[row];
        float4 val = ((const float4*)x)[(size_t)(v0 + row) * 16 + q];
        h4 o;
        o.a = __floats2half2_rn(val.x * s, val.y * s);
        o.b = __floats2half2_rn(val.z * s, val.w * s);
        xs[(size_t)(v0 + row) * 16 + q] = o;
    }
}

// ---------- fused gather1 + MFMA MLP ----------
// block = 256 = 4 waves; wave owns 16 nodes: gathers in 4 QUAD steps
// (4 nodes x 2-deep = 8 row-loads in flight/lane) into a wave-private LDS
// arena; axs (row stride 72) is consumed into registers before hbuf
// (row stride 136) overwrites the same arena. No __syncthreads.
__global__ __launch_bounds__(256) void k_fused(
    const _Float16* __restrict__ xs, const int* __restrict__ rowptr,
    const int* __restrict__ cnt, const int* __restrict__ col,
    const float* __restrict__ dinv, const _Float16* __restrict__ W1T,
    const float* __restrict__ b1, const _Float16* __restrict__ W2T,
    __half* __restrict__ h2s, int n) {
    __shared__ _Float16 smem[4][16 * 136 + 8];  // per-wave arena
    int tid = threadIdx.x;
    int w = tid >> 6, lane = tid & 63;
    int m0 = blockIdx.x * 64 + w * 16;
    if (m0 >= n) return;  // wave-uniform; no barriers in this kernel
    int g = lane >> 3, l = lane & 7;
    int lo = lane & 15, hi = lane >> 4;
    _Float16* sm = smem[w];

    // ---- gather phase: 4 quads ----
    for (int p = 0; p < 4; ++p) {
        int v0 = m0 + 4 * p;
        int beg0 = 0, deg0 = 0, beg1 = 0, deg1 = 0;
        int beg2 = 0, deg2 = 0, beg3 = 0, deg3 = 0;
        if (v0 < n)     { beg0 = rowptr[v0];     deg0 = cnt[v0]; }
        if (v0 + 1 < n) { beg1 = rowptr[v0 + 1]; deg1 = cnt[v0 + 1]; }
        if (v0 + 2 < n) { beg2 = rowptr[v0 + 2]; deg2 = cnt[v0 + 2]; }
        if (v0 + 3 < n) { beg3 = rowptr[v0 + 3]; deg3 = cnt[v0 + 3]; }
        int dmax = max(max(deg0, deg1), max(deg2, deg3));

        __half2 z = __float2half2_rn(0.f);
        __half2 a00 = z, a01 = z, a02 = z, a03 = z;
        __half2 a10 = z, a11 = z, a12 = z, a13 = z;
        __half2 a20 = z, a21 = z, a22 = z, a23 = z;
        __half2 a30 = z, a31 = z, a32 = z, a33 = z;

        for (int j = g; j < dmax; j += 16) {
            int jb = j + 8;
            int s00 = (j  < deg0) ? col[beg0 + j]  : n;
            int s01 = (jb < deg0) ? col[beg0 + jb] : n;
            int s10 = (j  < deg1) ? col[beg1 + j]  : n;
            int s11 = (jb < deg1) ? col[beg1 + jb] : n;
            int s20 = (j  < deg2) ? col[beg2 + j]  : n;
            int s21 = (jb < deg2) ? col[beg2 + jb] : n;
            int s30 = (j  < deg3) ? col[beg3 + j]  : n;
            int s31 = (jb < deg3) ? col[beg3 + jb] : n;
            float4 r00 = ((const float4*)(xs + (size_t)s00 * F_IN))[l];
            float4 r01 = ((const float4*)(xs + (size_t)s01 * F_IN))[l];
            float4 r10 = ((const float4*)(xs + (size_t)s10 * F_IN))[l];
            float4 r11 = ((const float4*)(xs + (size_t)s11 * F_IN))[l];
            float4 r20 = ((const float4*)(xs + (size_t)s20 * F_IN))[l];
            float4 r21 = ((const float4*)(xs + (size_t)s21 * F_IN))[l];
            float4 r30 = ((const float4*)(xs + (size_t)s30 * F_IN))[l];
            float4 r31 = ((const float4*)(xs + (size_t)s31 * F_IN))[l];
            a00 = __hadd2(a00, *(__half2*)&r00.x); a01 = __hadd2(a01, *(__half2*)&r00.y);
            a02 = __hadd2(a02, *(__half2*)&r00.z); a03 = __hadd2(a03, *(__half2*)&r00.w);
            a00 = __hadd2(a00, *(__half2*)&r01.x); a01 = __hadd2(a01, *(__half2*)&r01.y);
            a02 = __hadd2(a02, *(__half2*)&r01.z); a03 = __hadd2(a03, *(__half2*)&r01.w);
            a10 = __hadd2(a10, *(__half2*)&r10.x); a11 = __hadd2(a11, *(__half2*)&r10.y);
            a12 = __hadd2(a12, *(__half2*)&r10.z); a13 = __hadd2(a13, *(__half2*)&r10.w);
            a10 = __hadd2(a10, *(__half2*)&r11.x); a11 = __hadd2(a11, *(__half2*)&r11.y);
            a12 = __hadd2(a12, *(__half2*)&r11.z); a13 = __hadd2(a13, *(__half2*)&r11.w);
            a20 = __hadd2(a20, *(__half2*)&r20.x); a21 = __hadd2(a21, *(__half2*)&r20.y);
            a22 = __hadd2(a22, *(__half2*)&r20.z); a23 = __hadd2(a23, *(__half2*)&r20.w);
            a20 = __hadd2(a20, *(__half2*)&r21.x); a21 = __hadd2(a21, *(__half2*)&r21.y);
            a22 = __hadd2(a22, *(__half2*)&r21.z); a23 = __hadd2(a23, *(__half2*)&r21.w);
            a30 = __hadd2(a30, *(__half2*)&r30.x); a31 = __hadd2(a31, *(__half2*)&r30.y);
            a32 = __hadd2(a32, *(__half2*)&r30.z); a33 = __hadd2(a33, *(__half2*)&r30.w);
            a30 = __hadd2(a30, *(__half2*)&r31.x); a31 = __hadd2(a31, *(__half2*)&r31.y);
            a32 = __hadd2(a32, *(__half2*)&r31.z); a33 = __hadd2(a33, *(__half2*)&r31.w);
        }

        // packed butterfly across the 8 groups (xor 8, 16, 32)
#pragma unroll
        for (int d = 8; d <= 32; d <<= 1) {
            a00 = __hadd2(a00, hshfl_xor(a00, d)); a01 = __hadd2(a01, hshfl_xor(a01, d));
            a02 = __hadd2(a02, hshfl_xor(a02, d)); a03 = __hadd2(a03, hshfl_xor(a03, d));
            a10 = __hadd2(a10, hshfl_xor(a10, d)); a11 = __hadd2(a11, hshfl_xor(a11, d));
            a12 = __hadd2(a12, hshfl_xor(a12, d)); a13 = __hadd2(a13, hshfl_xor(a13, d));
            a20 = __hadd2(a20, hshfl_xor(a20, d)); a21 = __hadd2(a21, hshfl_xor(a21, d));
            a22 = __hadd2(a22, hshfl_xor(a22, d)); a23 = __hadd2(a23, hshfl_xor(a23, d));
            a30 = __hadd2(a30, hshfl_xor(a30, d)); a31 = __hadd2(a31, hshfl_xor(a31, d));
            a32 = __hadd2(a32, hshfl_xor(a32, d)); a33 = __hadd2(a33, hshfl_xor(a33, d));
        }

        // selection (register moves only) + shared epilogue
        if (g < 4) {
            int v = v0 + g;
            if (v < n) {
                __half2 A0, A1, A2, A3;
                if (g == 0)      { A0 = a00; A1 = a01; A2 = a02; A3 = a03; }
                else if (g == 1) { A0 = a10; A1 = a11; A2 = a12; A3 = a13; }
                else if (g == 2) { A0 = a20; A1 = a21; A2 = a22; A3 = a23; }
                else             { A0 = a30; A1 = a31; A2 = a32; A3 = a33; }
                float dv = dinv[v];
                float4 sr = ((const float4*)(xs + (size_t)v * F_IN))[l];
                float2 f0 = __half22float2(A0), f1 = __half22float2(A1);
                float2 f2 = __half22float2(A2), f3 = __half22float2(A3);
                float2 s0 = __half22float2(*(__half2*)&sr.x);
                float2 s1 = __half22float2(*(__half2*)&sr.y);
                float2 s2 = __half22float2(*(__half2*)&sr.z);
                float2 s3 = __half22float2(*(__half2*)&sr.w);
                __half2 o0 = __floats2half2_rn(dv * (f0.x + s0.x), dv * (f0.y + s0.y));
                __half2 o1 = __floats2half2_rn(dv * (f1.x + s1.x), dv * (f1.y + s1.y));
                __half2 o2 = __floats2half2_rn(dv * (f2.x + s2.x), dv * (f2.y + s2.y));
                __half2 o3 = __floats2half2_rn(dv * (f3.x + s3.x), dv * (f3.y + s3.y));
                float4 o;
                o.x = *(float*)&o0; o.y = *(float*)&o1; o.z = *(float*)&o2; o.w = *(float*)&o3;
                *(float4*)&sm[(4 * p + g) * 72 + l * 8] = o;   // axs row
            }
        }
    }

    // ---- layer 1 MFMA: A from axs (arena, stride 72) ----
    half8 a0 = *(half8*)&sm[lo * 72 + hi * 8];
    half8 a1 = *(half8*)&sm[lo * 72 + 32 + hi * 8];

    float b1v[8];
    f32x4 acc[8];
#pragma unroll
    for (int j = 0; j < 8; ++j) {
        b1v[j] = b1[j * 16 + lo];
        const half8* bptr = (const half8*)(W1T + (size_t)(j * 16 + lo) * F_IN);
        half8 bf0 = bptr[hi];
        half8 bf1 = bptr[4 + hi];
        f32x4 c = {0.f, 0.f, 0.f, 0.f};
        c = __builtin_amdgcn_mfma_f32_16x16x32_f16(a0, bf0, c, 0, 0, 0);
        c = __builtin_amdgcn_mfma_f32_16x16x32_f16(a1, bf1, c, 0, 0, 0);
        acc[j] = c;
    }

    // epilogue 1: bias + relu -> hbuf (arena, stride 136; axs regs already consumed)
#pragma unroll
    for (int j = 0; j < 8; ++j) {
#pragma unroll
        for (int r = 0; r < 4; ++r) {
            float hv = acc[j][r] + b1v[j];
            sm[(hi * 4 + r) * 136 + j * 16 + lo] = (_Float16)(hv > 0.f ? hv : 0.f);
        }
    }

    // ---- layer 2 MFMA: A from hbuf ----
    f32x4 acc2[2] = {{0.f, 0.f, 0.f, 0.f}, {0.f, 0.f, 0.f, 0.f}};
#pragma unroll
    for (int ks = 0; ks < 4; ++ks) {
        half8 a = *(half8*)&sm[lo * 136 + ks * 32 + hi * 8];
#pragma unroll
        for (int t = 0; t < 2; ++t) {
            const half8* b2p = (const half8*)(W2T + (size_t)(t * 16 + lo) * HDIM);
            acc2[t] = __builtin_amdgcn_mfma_f32_16x16x32_f16(a, b2p[ks * 4 + hi], acc2[t], 0, 0, 0);
        }
    }

#pragma unroll
    for (int r = 0; r < 4; ++r) {
        int R = m0 + hi * 4 + r;
        if (R < n) {
            float dv = dinv[R];
            h2s[(size_t)R * CDIM + lo]      = __float2half(dv * acc2[0][r]);
            h2s[(size_t)R * CDIM + 16 + lo] = __float2half(dv * acc2[1][r]);
        }
    }
}

// ---------- gather 2: wave = 4 nodes (16-lane slots), 4-lane groups, 2-deep ----
__global__ void k_gather2(const _Float16* __restrict__ h2s, const int* __restrict__ rowptr,
                          const int* __restrict__ cnt, const int* __restrict__ col,
                          const float* __restrict__ dinv, const float* __restrict__ b2,
                          float* __restrict__ out, int n) {
    int tid = threadIdx.x;
    int w = tid >> 6, lane = tid & 63;
    int v0w = blockIdx.x * 16 + w * 4;   // first node of this wave
    if (v0w >= n) return;                // wave-uniform
    int slot = lane >> 4;
    int v = v0w + slot;
    bool valid = v < n;
    int g = (lane >> 2) & 3, l = lane & 3;
    int beg = valid ? rowptr[v] : 0;
    int deg = valid ? cnt[v] : 0;

    __half2 a0 = __float2half2_rn(0.f), a1 = a0, a2 = a0, a3 = a0;
    __half2 c0 = a0, c1 = a0, c2 = a0, c3 = a0;
    for (int j = g; j < deg; j += 8) {
        int s0 = col[beg + j];
        int j2 = j + 4;
        int s1 = (j2 < deg) ? col[beg + j2] : n;
        float4 r0 = ((const float4*)(h2s + (size_t)s0 * CDIM))[l];
        float4 r1 = ((const float4*)(h2s + (size_t)s1 * CDIM))[l];
        a0 = __hadd2(a0, *(__half2*)&r0.x); a1 = __hadd2(a1, *(__half2*)&r0.y);
        a2 = __hadd2(a2, *(__half2*)&r0.z); a3 = __hadd2(a3, *(__half2*)&r0.w);
        c0 = __hadd2(c0, *(__half2*)&r1.x); c1 = __hadd2(c1, *(__half2*)&r1.y);
        c2 = __hadd2(c2, *(__half2*)&r1.z); c3 = __hadd2(c3, *(__half2*)&r1.w);
    }
    a0 = __hadd2(a0, c0); a1 = __hadd2(a1, c1);
    a2 = __hadd2(a2, c2); a3 = __hadd2(a3, c3);

    // packed butterfly across the 4 groups within the slot (xor 4, 8)
#pragma unroll
    for (int d = 4; d <= 8; d <<= 1) {
        a0 = __hadd2(a0, hshfl_xor(a0, d)); a1 = __hadd2(a1, hshfl_xor(a1, d));
        a2 = __hadd2(a2, hshfl_xor(a2, d)); a3 = __hadd2(a3, hshfl_xor(a3, d));
    }

    if (g == 0 && valid) {
        float dv = dinv[v];
        float4 sr = ((const float4*)(h2s + (size_t)v * CDIM))[l];
        float2 f0 = __half22float2(a0), f1 = __half22float2(a1);
        float2 f2 = __half22float2(a2), f3 = __half22float2(a3);
        float2 s0 = __half22float2(*(__half2*)&sr.x), s1 = __half22float2(*(__half2*)&sr.y);
        float2 s2 = __half22float2(*(__half2*)&sr.z), s3 = __half22float2(*(__half2*)&sr.w);
        const float4* bbp = (const float4*)(b2 + l * 8);
        float4 ba = bbp[0], bb = bbp[1];
        float4 o0, o1;
        o0.x = dv * (f0.x + s0.x) + ba.x;
        o0.y = dv * (f0.y + s0.y) + ba.y;
        o0.z = dv * (f1.x + s1.x) + ba.z;
        o0.w = dv * (f1.y + s1.y) + ba.w;
        o1.x = dv * (f2.x + s2.x) + bb.x;
        o1.y = dv * (f2.y + s2.y) + bb.y;
        o1.z = dv * (f3.x + s3.x) + bb.z;
        o1.w = dv * (f3.y + s3.y) + bb.w;
        float4* op = (float4*)(out + (size_t)v * CDIM + l * 8);
        op[0] = o0;
        op[1] = o1;
    }
}

extern "C" void kernel_launch(void* const* d_in, const int* in_sizes, int n_in,
                              void* d_out, int out_size, void* d_ws, size_t ws_size,
                              hipStream_t stream) {
    const float* x  = (const float*)d_in[0];
    const int*   ei = (const int*)d_in[1];
    const float* W1 = (const float*)d_in[2];
    const float* b1 = (const float*)d_in[3];
    const float* W2 = (const float*)d_in[4];
    const float* b2 = (const float*)d_in[5];
    float* out = (float*)d_out;

    int n = in_sizes[0] / F_IN;
    int e = in_sizes[1] / 2;
    const int* srcIdx = ei;
    const int* dstIdx = ei + e;

    int nbk = (n + BK - 1) / BK;  // 391 for n=100K (needs <= 511)
    int nchunks = (e + SC_CHUNK - 1) / SC_CHUNK;

    // workspace layout (4B words):
    //   cnt[n] | bucketCursor[512] | rowptr[n] | col[nbk*BCAP] | dinv[n] |
    //   xs(fp16 [n+1][64]) | h2s(fp16 [n+1][32]) | W1T | W2T | staging[nbk*BCAP]
    int* cnt          = (int*)d_ws;
    int* bucketCursor = cnt + n;
    int* rowptr       = bucketCursor + 512;
    int* col          = rowptr + n;
    float* dinv       = (float*)(col + (size_t)nbk * BCAP);
    _Float16* xs      = (_Float16*)(dinv + n);                     // [n+1][64]
    __half* h2s       = (__half*)(xs + (size_t)(n + 1) * F_IN);    // [n+1][32]
    _Float16* W1T     = (_Float16*)(h2s + (size_t)(n + 1) * CDIM); // [128][64]
    _Float16* W2T     = W1T + HDIM * F_IN;                         // [32][128]
    unsigned* staging = (unsigned*)(W2T + CDIM * HDIM);            // nbk*BCAP

    const int B = 256;

    hipMemsetAsync(bucketCursor, 0, 512 * sizeof(int), stream);

    // build: scatter (fixed-capacity buckets, + wconv/zero-row aux block) -> finalize
    kb_scatter<<<nchunks + 1, B, 0, stream>>>(srcIdx, dstIdx, e, nbk, nchunks,
                                              bucketCursor, staging, W1, W2, W1T, W2T,
                                              (h4*)xs, (h4*)h2s, n);
    kb_finalize<<<nbk, BK, 0, stream>>>(staging, bucketCursor, rowptr, cnt, dinv, col,
                                        x, (h4*)xs, n);

    // fused layer1 gather + MLP (MFMA) ; then layer2 gather
    k_fused<<<(n + 63) / 64, B, 0, stream>>>(xs, rowptr, cnt, col, dinv, W1T, b1, W2T,
                                             h2s, n);
    k_gather2<<<(n + 15) / 16, B, 0, stream>>>((const _Float16*)h2s, rowptr, cnt, col,
                                               dinv, b2, out, n);
}

// Round 16
// 127.435 us; speedup vs baseline: 3.2848x; 1.1088x over previous
//
#include <hip/hip_runtime.h>
#include <hip/hip_fp16.h>

// GCN 2-layer forward, round 16:
//   R15 + (a) kb_finalize single-pass (bucket staging copied to LDS during the
//   count; sort reads LDS -> one less 6.4MB global pass); (b) SC_CHUNK 4096
//   (42B staging runs, fewer partial-line writes); (c) gather2 4-deep loads.
//   ax[v]  = dinv[v]*(sum xs[s] + xs[v]),  xs = fp16(dinv.*x)
//   h2s    = fp16(dinv .* (relu(ax@W1+b1) @ W2))   [MFMA]
//   out[v] = dinv[v]*(sum h2s[s] + h2s[v]) + b2

#define F_IN 64
#define HDIM 128
#define CDIM 32
#define BK 256          // nodes per bucket (== kb_finalize blockDim)
#define BCAP 6144       // edge capacity per bucket (mean 4090 @ n=100K,E=1.6M)
#define SC_CHUNK 4096   // edges per kb_scatter workgroup

struct h4 { __half2 a, b; };  // 8-byte packed 4x fp16

typedef _Float16 half8 __attribute__((ext_vector_type(8)));
typedef float f32x4 __attribute__((ext_vector_type(4)));

__device__ __forceinline__ __half2 hshfl_xor(__half2 h, int d) {
    union { __half2 h2; int i; } u;
    u.h2 = h;
    u.i = __shfl_xor(u.i, d);
    return u.h2;
}

// ---------- scatter: LDS hist -> cursor reservation -> packed staging ----------
// extra block (blockIdx == nchunks): weight conversion + zero-row padding
__global__ void kb_scatter(const int* __restrict__ src, const int* __restrict__ dst,
                           int e, int nbk, int nchunks, int* __restrict__ bucketCursor,
                           unsigned* __restrict__ staging,
                           const float* __restrict__ W1, const float* __restrict__ W2,
                           _Float16* __restrict__ W1T, _Float16* __restrict__ W2T,
                           h4* __restrict__ xs, h4* __restrict__ h2s4, int n) {
    int tid = threadIdx.x;
    if (blockIdx.x == nchunks) {  // aux block
        for (int i = tid; i < F_IN * HDIM + HDIM * CDIM; i += blockDim.x) {
            if (i < F_IN * HDIM) {
                int k = i >> 7, c = i & 127;
                W1T[c * F_IN + k] = (_Float16)W1[i];
            } else {
                int j = i - F_IN * HDIM;
                int k = j >> 5, c = j & 31;
                W2T[c * HDIM + k] = (_Float16)W2[j];
            }
        }
        h4 z; z.a = __float2half2_rn(0.f); z.b = z.a;
        if (tid < 16) xs[(size_t)n * 16 + tid] = z;               // zero row xs[n]
        else if (tid < 24) h2s4[(size_t)n * 8 + (tid - 16)] = z;  // zero row h2s[n]
        return;
    }
    __shared__ int lh[512];
    __shared__ int lbase[512];
    __shared__ int dstS[SC_CHUNK];
    int c0 = blockIdx.x * SC_CHUNK;
    int m = min(SC_CHUNK, e - c0);
    for (int i = tid; i < nbk; i += blockDim.x) lh[i] = 0;
    __syncthreads();
    for (int i = tid; i < m; i += blockDim.x) {
        int d = dst[c0 + i];
        dstS[i] = d;
        atomicAdd(&lh[d >> 8], 1);
    }
    __syncthreads();
    for (int i = tid; i < nbk; i += blockDim.x) {
        int c = lh[i];
        lbase[i] = c ? atomicAdd(&bucketCursor[i], c) : 0;
        lh[i] = 0;  // becomes local cursor
    }
    __syncthreads();
    for (int i = tid; i < m; i += blockDim.x) {
        int d = dstS[i];
        int b = d >> 8;
        int r = atomicAdd(&lh[b], 1);
        staging[(size_t)b * BCAP + lbase[b] + r] =
            ((unsigned)(d & (BK - 1)) << 24) | (unsigned)src[c0 + i];
    }
}

// fused single-pass: staging copied to LDS during degree count, in-bucket scan
// -> rowptr/cnt/dinv, counting sort from LDS, bucket-local prescale x -> xs
__global__ __launch_bounds__(256) void kb_finalize(
    const unsigned* __restrict__ staging, const int* __restrict__ bucketCursor,
    int* __restrict__ rowptr, int* __restrict__ cnt, float* __restrict__ dinv,
    int* __restrict__ col, const float* __restrict__ x, h4* __restrict__ xs, int n) {
    __shared__ unsigned eS[BCAP];   // 24KB bucket edge cache
    __shared__ int lc[BK];
    __shared__ int lscan[BK];
    __shared__ float dinvS[BK];
    int b = blockIdx.x;
    int tid = threadIdx.x;
    lc[tid] = 0;
    __syncthreads();
    int beg = b * BCAP;
    int ne = bucketCursor[b];
    for (int i = tid; i < ne; i += blockDim.x) {
        unsigned sd = staging[beg + i];
        eS[i] = sd;
        atomicAdd(&lc[sd >> 24], 1);
    }
    __syncthreads();
    int deg = lc[tid];
    lscan[tid] = deg;
    __syncthreads();
    for (int off = 1; off < BK; off <<= 1) {
        int t = (tid >= off) ? lscan[tid - off] : 0;
        __syncthreads();
        lscan[tid] += t;
        __syncthreads();
    }
    int rp = beg + lscan[tid] - deg;   // bucket-padded CSR offset
    int v = b * BK + tid;
    float dv = rsqrtf((float)(deg + 1));
    if (v < n) {
        rowptr[v] = rp;
        cnt[v] = deg;
        dinv[v] = dv;
    }
    dinvS[tid] = dv;
    lc[tid] = rp;  // becomes cursor
    __syncthreads();
    for (int i = tid; i < ne; i += blockDim.x) {
        unsigned sd = eS[i];
        int pos = atomicAdd(&lc[sd >> 24], 1);
        col[pos] = (int)(sd & 0xFFFFFFu);
    }
    // bucket-local prescale: xs[v] = fp16(dinv[v] * x[v])  (coalesced)
    int v0 = b * BK;
    int rows = min(BK, n - v0);
    for (int t = tid; t < rows * 16; t += blockDim.x) {
        int row = t >> 4, q = t & 15;
        float s = dinvS[row];
        float4 val = ((const float4*)x)[(size_t)(v0 + row) * 16 + q];
        h4 o;
        o.a = __floats2half2_rn(val.x * s, val.y * s);
        o.b = __floats2half2_rn(val.z * s, val.w * s);
        xs[(size_t)(v0 + row) * 16 + q] = o;
    }
}

// ---------- fused gather1 + MFMA MLP ----------
// block = 256 = 4 waves; wave owns 16 nodes: gathers in 4 QUAD steps
// (4 nodes x 2-deep = 8 row-loads in flight/lane) into a wave-private LDS
// arena; axs (stride 72) consumed to registers before hbuf (stride 136)
// overwrites the arena. No __syncthreads.
__global__ __launch_bounds__(256) void k_fused(
    const _Float16* __restrict__ xs, const int* __restrict__ rowptr,
    const int* __restrict__ cnt, const int* __restrict__ col,
    const float* __restrict__ dinv, const _Float16* __restrict__ W1T,
    const float* __restrict__ b1, const _Float16* __restrict__ W2T,
    __half* __restrict__ h2s, int n) {
    __shared__ _Float16 smem[4][16 * 136 + 8];  // per-wave arena
    int tid = threadIdx.x;
    int w = tid >> 6, lane = tid & 63;
    int m0 = blockIdx.x * 64 + w * 16;
    if (m0 >= n) return;  // wave-uniform; no barriers in this kernel
    int g = lane >> 3, l = lane & 7;
    int lo = lane & 15, hi = lane >> 4;
    _Float16* sm = smem[w];

    // ---- gather phase: 4 quads ----
    for (int p = 0; p < 4; ++p) {
        int v0 = m0 + 4 * p;
        int beg0 = 0, deg0 = 0, beg1 = 0, deg1 = 0;
        int beg2 = 0, deg2 = 0, beg3 = 0, deg3 = 0;
        if (v0 < n)     { beg0 = rowptr[v0];     deg0 = cnt[v0]; }
        if (v0 + 1 < n) { beg1 = rowptr[v0 + 1]; deg1 = cnt[v0 + 1]; }
        if (v0 + 2 < n) { beg2 = rowptr[v0 + 2]; deg2 = cnt[v0 + 2]; }
        if (v0 + 3 < n) { beg3 = rowptr[v0 + 3]; deg3 = cnt[v0 + 3]; }
        int dmax = max(max(deg0, deg1), max(deg2, deg3));

        __half2 z = __float2half2_rn(0.f);
        __half2 a00 = z, a01 = z, a02 = z, a03 = z;
        __half2 a10 = z, a11 = z, a12 = z, a13 = z;
        __half2 a20 = z, a21 = z, a22 = z, a23 = z;
        __half2 a30 = z, a31 = z, a32 = z, a33 = z;

        for (int j = g; j < dmax; j += 16) {
            int jb = j + 8;
            int s00 = (j  < deg0) ? col[beg0 + j]  : n;
            int s01 = (jb < deg0) ? col[beg0 + jb] : n;
            int s10 = (j  < deg1) ? col[beg1 + j]  : n;
            int s11 = (jb < deg1) ? col[beg1 + jb] : n;
            int s20 = (j  < deg2) ? col[beg2 + j]  : n;
            int s21 = (jb < deg2) ? col[beg2 + jb] : n;
            int s30 = (j  < deg3) ? col[beg3 + j]  : n;
            int s31 = (jb < deg3) ? col[beg3 + jb] : n;
            float4 r00 = ((const float4*)(xs + (size_t)s00 * F_IN))[l];
            float4 r01 = ((const float4*)(xs + (size_t)s01 * F_IN))[l];
            float4 r10 = ((const float4*)(xs + (size_t)s10 * F_IN))[l];
            float4 r11 = ((const float4*)(xs + (size_t)s11 * F_IN))[l];
            float4 r20 = ((const float4*)(xs + (size_t)s20 * F_IN))[l];
            float4 r21 = ((const float4*)(xs + (size_t)s21 * F_IN))[l];
            float4 r30 = ((const float4*)(xs + (size_t)s30 * F_IN))[l];
            float4 r31 = ((const float4*)(xs + (size_t)s31 * F_IN))[l];
            a00 = __hadd2(a00, *(__half2*)&r00.x); a01 = __hadd2(a01, *(__half2*)&r00.y);
            a02 = __hadd2(a02, *(__half2*)&r00.z); a03 = __hadd2(a03, *(__half2*)&r00.w);
            a00 = __hadd2(a00, *(__half2*)&r01.x); a01 = __hadd2(a01, *(__half2*)&r01.y);
            a02 = __hadd2(a02, *(__half2*)&r01.z); a03 = __hadd2(a03, *(__half2*)&r01.w);
            a10 = __hadd2(a10, *(__half2*)&r10.x); a11 = __hadd2(a11, *(__half2*)&r10.y);
            a12 = __hadd2(a12, *(__half2*)&r10.z); a13 = __hadd2(a13, *(__half2*)&r10.w);
            a10 = __hadd2(a10, *(__half2*)&r11.x); a11 = __hadd2(a11, *(__half2*)&r11.y);
            a12 = __hadd2(a12, *(__half2*)&r11.z); a13 = __hadd2(a13, *(__half2*)&r11.w);
            a20 = __hadd2(a20, *(__half2*)&r20.x); a21 = __hadd2(a21, *(__half2*)&r20.y);
            a22 = __hadd2(a22, *(__half2*)&r20.z); a23 = __hadd2(a23, *(__half2*)&r20.w);
            a20 = __hadd2(a20, *(__half2*)&r21.x); a21 = __hadd2(a21, *(__half2*)&r21.y);
            a22 = __hadd2(a22, *(__half2*)&r21.z); a23 = __hadd2(a23, *(__half2*)&r21.w);
            a30 = __hadd2(a30, *(__half2*)&r30.x); a31 = __hadd2(a31, *(__half2*)&r30.y);
            a32 = __hadd2(a32, *(__half2*)&r30.z); a33 = __hadd2(a33, *(__half2*)&r30.w);
            a30 = __hadd2(a30, *(__half2*)&r31.x); a31 = __hadd2(a31, *(__half2*)&r31.y);
            a32 = __hadd2(a32, *(__half2*)&r31.z); a33 = __hadd2(a33, *(__half2*)&r31.w);
        }

        // packed butterfly across the 8 groups (xor 8, 16, 32)
#pragma unroll
        for (int d = 8; d <= 32; d <<= 1) {
            a00 = __hadd2(a00, hshfl_xor(a00, d)); a01 = __hadd2(a01, hshfl_xor(a01, d));
            a02 = __hadd2(a02, hshfl_xor(a02, d)); a03 = __hadd2(a03, hshfl_xor(a03, d));
            a10 = __hadd2(a10, hshfl_xor(a10, d)); a11 = __hadd2(a11, hshfl_xor(a11, d));
            a12 = __hadd2(a12, hshfl_xor(a12, d)); a13 = __hadd2(a13, hshfl_xor(a13, d));
            a20 = __hadd2(a20, hshfl_xor(a20, d)); a21 = __hadd2(a21, hshfl_xor(a21, d));
            a22 = __hadd2(a22, hshfl_xor(a22, d)); a23 = __hadd2(a23, hshfl_xor(a23, d));
            a30 = __hadd2(a30, hshfl_xor(a30, d)); a31 = __hadd2(a31, hshfl_xor(a31, d));
            a32 = __hadd2(a32, hshfl_xor(a32, d)); a33 = __hadd2(a33, hshfl_xor(a33, d));
        }

        // selection (register moves only) + shared epilogue
        if (g < 4) {
            int v = v0 + g;
            if (v < n) {
                __half2 A0, A1, A2, A3;
                if (g == 0)      { A0 = a00; A1 = a01; A2 = a02; A3 = a03; }
                else if (g == 1) { A0 = a10; A1 = a11; A2 = a12; A3 = a13; }
                else if (g == 2) { A0 = a20; A1 = a21; A2 = a22; A3 = a23; }
                else             { A0 = a30; A1 = a31; A2 = a32; A3 = a33; }
                float dv = dinv[v];
                float4 sr = ((const float4*)(xs + (size_t)v * F_IN))[l];
                float2 f0 = __half22float2(A0), f1 = __half22float2(A1);
                float2 f2 = __half22float2(A2), f3 = __half22float2(A3);
                float2 s0 = __half22float2(*(__half2*)&sr.x);
                float2 s1 = __half22float2(*(__half2*)&sr.y);
                float2 s2 = __half22float2(*(__half2*)&sr.z);
                float2 s3 = __half22float2(*(__half2*)&sr.w);
                __half2 o0 = __floats2half2_rn(dv * (f0.x + s0.x), dv * (f0.y + s0.y));
                __half2 o1 = __floats2half2_rn(dv * (f1.x + s1.x), dv * (f1.y + s1.y));
                __half2 o2 = __floats2half2_rn(dv * (f2.x + s2.x), dv * (f2.y + s2.y));
                __half2 o3 = __floats2half2_rn(dv * (f3.x + s3.x), dv * (f3.y + s3.y));
                float4 o;
                o.x = *(float*)&o0; o.y = *(float*)&o1; o.z = *(float*)&o2; o.w = *(float*)&o3;
                *(float4*)&sm[(4 * p + g) * 72 + l * 8] = o;   // axs row
            }
        }
    }

    // ---- layer 1 MFMA: A from axs (arena, stride 72) ----
    half8 a0 = *(half8*)&sm[lo * 72 + hi * 8];
    half8 a1 = *(half8*)&sm[lo * 72 + 32 + hi * 8];

    float b1v[8];
    f32x4 acc[8];
#pragma unroll
    for (int j = 0; j < 8; ++j) {
        b1v[j] = b1[j * 16 + lo];
        const half8* bptr = (const half8*)(W1T + (size_t)(j * 16 + lo) * F_IN);
        half8 bf0 = bptr[hi];
        half8 bf1 = bptr[4 + hi];
        f32x4 c = {0.f, 0.f, 0.f, 0.f};
        c = __builtin_amdgcn_mfma_f32_16x16x32_f16(a0, bf0, c, 0, 0, 0);
        c = __builtin_amdgcn_mfma_f32_16x16x32_f16(a1, bf1, c, 0, 0, 0);
        acc[j] = c;
    }

    // epilogue 1: bias + relu -> hbuf (arena, stride 136)
#pragma unroll
    for (int j = 0; j < 8; ++j) {
#pragma unroll
        for (int r = 0; r < 4; ++r) {
            float hv = acc[j][r] + b1v[j];
            sm[(hi * 4 + r) * 136 + j * 16 + lo] = (_Float16)(hv > 0.f ? hv : 0.f);
        }
    }

    // ---- layer 2 MFMA: A from hbuf ----
    f32x4 acc2[2] = {{0.f, 0.f, 0.f, 0.f}, {0.f, 0.f, 0.f, 0.f}};
#pragma unroll
    for (int ks = 0; ks < 4; ++ks) {
        half8 a = *(half8*)&sm[lo * 136 + ks * 32 + hi * 8];
#pragma unroll
        for (int t = 0; t < 2; ++t) {
            const half8* b2p = (const half8*)(W2T + (size_t)(t * 16 + lo) * HDIM);
            acc2[t] = __builtin_amdgcn_mfma_f32_16x16x32_f16(a, b2p[ks * 4 + hi], acc2[t], 0, 0, 0);
        }
    }

#pragma unroll
    for (int r = 0; r < 4; ++r) {
        int R = m0 + hi * 4 + r;
        if (R < n) {
            float dv = dinv[R];
            h2s[(size_t)R * CDIM + lo]      = __float2half(dv * acc2[0][r]);
            h2s[(size_t)R * CDIM + 16 + lo] = __float2half(dv * acc2[1][r]);
        }
    }
}

// ---------- gather 2: wave = 4 nodes (16-lane slots), 4-lane groups, 4-deep ----
__global__ void k_gather2(const _Float16* __restrict__ h2s, const int* __restrict__ rowptr,
                          const int* __restrict__ cnt, const int* __restrict__ col,
                          const float* __restrict__ dinv, const float* __restrict__ b2,
                          float* __restrict__ out, int n) {
    int tid = threadIdx.x;
    int w = tid >> 6, lane = tid & 63;
    int v0w = blockIdx.x * 16 + w * 4;   // first node of this wave
    if (v0w >= n) return;                // wave-uniform
    int slot = lane >> 4;
    int v = v0w + slot;
    bool valid = v < n;
    int g = (lane >> 2) & 3, l = lane & 3;
    int beg = valid ? rowptr[v] : 0;
    int deg = valid ? cnt[v] : 0;

    __half2 zz = __float2half2_rn(0.f);
    __half2 a0 = zz, a1 = zz, a2 = zz, a3 = zz;
    __half2 c0 = zz, c1 = zz, c2 = zz, c3 = zz;
    __half2 d0 = zz, d1 = zz, d2 = zz, d3 = zz;
    __half2 e0 = zz, e1 = zz, e2 = zz, e3 = zz;
    for (int j = g; j < deg; j += 16) {
        int s0 = col[beg + j];
        int s1 = (j + 4  < deg) ? col[beg + j + 4]  : n;
        int s2 = (j + 8  < deg) ? col[beg + j + 8]  : n;
        int s3 = (j + 12 < deg) ? col[beg + j + 12] : n;
        float4 r0 = ((const float4*)(h2s + (size_t)s0 * CDIM))[l];
        float4 r1 = ((const float4*)(h2s + (size_t)s1 * CDIM))[l];
        float4 r2 = ((const float4*)(h2s + (size_t)s2 * CDIM))[l];
        float4 r3 = ((const float4*)(h2s + (size_t)s3 * CDIM))[l];
        a0 = __hadd2(a0, *(__half2*)&r0.x); a1 = __hadd2(a1, *(__half2*)&r0.y);
        a2 = __hadd2(a2, *(__half2*)&r0.z); a3 = __hadd2(a3, *(__half2*)&r0.w);
        c0 = __hadd2(c0, *(__half2*)&r1.x); c1 = __hadd2(c1, *(__half2*)&r1.y);
        c2 = __hadd2(c2, *(__half2*)&r1.z); c3 = __hadd2(c3, *(__half2*)&r1.w);
        d0 = __hadd2(d0, *(__half2*)&r2.x); d1 = __hadd2(d1, *(__half2*)&r2.y);
        d2 = __hadd2(d2, *(__half2*)&r2.z); d3 = __hadd2(d3, *(__half2*)&r2.w);
        e0 = __hadd2(e0, *(__half2*)&r3.x); e1 = __hadd2(e1, *(__half2*)&r3.y);
        e2 = __hadd2(e2, *(__half2*)&r3.z); e3 = __hadd2(e3, *(__half2*)&r3.w);
    }
    a0 = __hadd2(__hadd2(a0, c0), __hadd2(d0, e0));
    a1 = __hadd2(__hadd2(a1, c1), __hadd2(d1, e1));
    a2 = __hadd2(__hadd2(a2, c2), __hadd2(d2, e2));
    a3 = __hadd2(__hadd2(a3, c3), __hadd2(d3, e3));

    // packed butterfly across the 4 groups within the slot (xor 4, 8)
#pragma unroll
    for (int d = 4; d <= 8; d <<= 1) {
        a0 = __hadd2(a0, hshfl_xor(a0, d)); a1 = __hadd2(a1, hshfl_xor(a1, d));
        a2 = __hadd2(a2, hshfl_xor(a2, d)); a3 = __hadd2(a3, hshfl_xor(a3, d));
    }

    if (g == 0 && valid) {
        float dv = dinv[v];
        float4 sr = ((const float4*)(h2s + (size_t)v * CDIM))[l];
        float2 f0 = __half22float2(a0), f1 = __half22float2(a1);
        float2 f2 = __half22float2(a2), f3 = __half22float2(a3);
        float2 s0 = __half22float2(*(__half2*)&sr.x), s1 = __half22float2(*(__half2*)&sr.y);
        float2 s2 = __half22float2(*(__half2*)&sr.z), s3 = __half22float2(*(__half2*)&sr.w);
        const float4* bbp = (const float4*)(b2 + l * 8);
        float4 ba = bbp[0], bb = bbp[1];
        float4 o0, o1;
        o0.x = dv * (f0.x + s0.x) + ba.x;
        o0.y = dv * (f0.y + s0.y) + ba.y;
        o0.z = dv * (f1.x + s1.x) + ba.z;
        o0.w = dv * (f1.y + s1.y) + ba.w;
        o1.x = dv * (f2.x + s2.x) + bb.x;
        o1.y = dv * (f2.y + s2.y) + bb.y;
        o1.z = dv * (f3.x + s3.x) + bb.z;
        o1.w = dv * (f3.y + s3.y) + bb.w;
        float4* op = (float4*)(out + (size_t)v * CDIM + l * 8);
        op[0] = o0;
        op[1] = o1;
    }
}

extern "C" void kernel_launch(void* const* d_in, const int* in_sizes, int n_in,
                              void* d_out, int out_size, void* d_ws, size_t ws_size,
                              hipStream_t stream) {
    const float* x  = (const float*)d_in[0];
    const int*   ei = (const int*)d_in[1];
    const float* W1 = (const float*)d_in[2];
    const float* b1 = (const float*)d_in[3];
    const float* W2 = (const float*)d_in[4];
    const float* b2 = (const float*)d_in[5];
    float* out = (float*)d_out;

    int n = in_sizes[0] / F_IN;
    int e = in_sizes[1] / 2;
    const int* srcIdx = ei;
    const int* dstIdx = ei + e;

    int nbk = (n + BK - 1) / BK;  // 391 for n=100K (needs <= 511)
    int nchunks = (e + SC_CHUNK - 1) / SC_CHUNK;

    // workspace layout (4B words):
    //   cnt[n] | bucketCursor[512] | rowptr[n] | col[nbk*BCAP] | dinv[n] |
    //   xs(fp16 [n+1][64]) | h2s(fp16 [n+1][32]) | W1T | W2T | staging[nbk*BCAP]
    int* cnt          = (int*)d_ws;
    int* bucketCursor = cnt + n;
    int* rowptr       = bucketCursor + 512;
    int* col          = rowptr + n;
    float* dinv       = (float*)(col + (size_t)nbk * BCAP);
    _Float16* xs      = (_Float16*)(dinv + n);                     // [n+1][64]
    __half* h2s       = (__half*)(xs + (size_t)(n + 1) * F_IN);    // [n+1][32]
    _Float16* W1T     = (_Float16*)(h2s + (size_t)(n + 1) * CDIM); // [128][64]
    _Float16* W2T     = W1T + HDIM * F_IN;                         // [32][128]
    unsigned* staging = (unsigned*)(W2T + CDIM * HDIM);            // nbk*BCAP

    const int B = 256;

    hipMemsetAsync(bucketCursor, 0, 512 * sizeof(int), stream);

    // build: scatter (fixed-capacity buckets, + wconv/zero-row aux block) -> finalize
    kb_scatter<<<nchunks + 1, B, 0, stream>>>(srcIdx, dstIdx, e, nbk, nchunks,
                                              bucketCursor, staging, W1, W2, W1T, W2T,
                                              (h4*)xs, (h4*)h2s, n);
    kb_finalize<<<nbk, BK, 0, stream>>>(staging, bucketCursor, rowptr, cnt, dinv, col,
                                        x, (h4*)xs, n);

    // fused layer1 gather + MLP (MFMA) ; then layer2 gather
    k_fused<<<(n + 63) / 64, B, 0, stream>>>(xs, rowptr, cnt, col, dinv, W1T, b1, W2T,
                                             h2s, n);
    k_gather2<<<(n + 15) / 16, B, 0, stream>>>((const _Float16*)h2s, rowptr, cnt, col,
                                               dinv, b2, out, n);
}